// Round 4
// baseline (872.462 us; speedup 1.0000x reference)
//
#include <hip/hip_runtime.h>
#include <math.h>

// GAT 3-layer inference on MI355X.
// Strategy: device-built CSR (by dst) once per call; per-layer:
//   z = h@W (LDS-tiled f32 GEMM), el/er per-node reductions,
//   e per-edge leaky_relu, then one-wave-per-node softmax+aggregate
//   (no float atomics anywhere).

#define NEG_BIG (-1e38f)

static inline int cdiv(int a, int b) { return (a + b - 1) / b; }

// ---------------- CSR build ----------------

__global__ void count_deg_kernel(const int* __restrict__ dst, int* __restrict__ deg, int E) {
    int i = blockIdx.x * blockDim.x + threadIdx.x;
    if (i < E) atomicAdd(&deg[dst[i]], 1);
}

// single-block exclusive scan over N (~50000) elements
__global__ void scan_kernel(const int* __restrict__ deg, int* __restrict__ rowptr, int n) {
    __shared__ int sums[1024];
    int t = threadIdx.x;
    int chunk = (n + 1023) >> 10;
    int s0 = t * chunk;
    int s1 = min(s0 + chunk, n);
    if (s1 < s0) s1 = s0;
    int tot = 0;
    for (int i = s0; i < s1; ++i) tot += deg[i];
    sums[t] = tot;
    __syncthreads();
    for (int off = 1; off < 1024; off <<= 1) {
        int val = (t >= off) ? sums[t - off] : 0;
        __syncthreads();
        sums[t] += val;
        __syncthreads();
    }
    int excl = sums[t] - tot;
    for (int i = s0; i < s1; ++i) { rowptr[i] = excl; excl += deg[i]; }
    if (t == 1023) rowptr[n] = sums[1023];
}

__global__ void fill_csr_kernel(const int* __restrict__ dst, const int* __restrict__ rowptr,
                                int* __restrict__ cursor, int* __restrict__ eidx, int E) {
    int i = blockIdx.x * blockDim.x + threadIdx.x;
    if (i < E) {
        int d = dst[i];
        int pos = atomicAdd(&cursor[d], 1);
        eidx[rowptr[d] + pos] = i;
    }
}

// ---------------- layer 1 projection (Fin=2) ----------------

__global__ void z1_kernel(const float* __restrict__ feat, const float* __restrict__ W1,
                          float* __restrict__ z, int N) {
    int t = blockIdx.x * blockDim.x + threadIdx.x;
    int n = t >> 7;
    if (n >= N) return;
    int j = t & 127;
    float f0 = feat[(size_t)n * 2];
    float f1 = feat[(size_t)n * 2 + 1];
    z[t] = fmaf(f0, W1[j], f1 * W1[128 + j]);
}

// ---------------- GEMM: A[N,128] @ W[128,HDout] -> Z[N,HDout] ----------------
// 64x64 tile per block, 256 threads, 4x4 micro-tile, K=128 staged in LDS.

__global__ __launch_bounds__(256) void gemm_tile_kernel(
        const float* __restrict__ A, const float* __restrict__ W,
        float* __restrict__ Z, int N, int HDout) {
    __shared__ __align__(16) float hs[64][129];  // +1 pad: kills bank conflicts on hs[r][k]
    __shared__ __align__(16) float ws[128][64];
    int n0 = blockIdx.x * 64;
    int c0 = blockIdx.y * 64;
    int t = threadIdx.x;
    for (int idx = t; idx < 64 * 128; idx += 256) {
        int r = idx >> 7, k = idx & 127;
        int n = n0 + r;
        hs[r][k] = (n < N) ? A[(size_t)n * 128 + k] : 0.f;
    }
    for (int idx = t; idx < 128 * 64; idx += 256) {
        int k = idx >> 6, c = idx & 63;
        ws[k][c] = W[(size_t)k * HDout + c0 + c];
    }
    __syncthreads();
    int tr = t >> 4, tc = t & 15;
    float acc[4][4] = {};
    #pragma unroll 4
    for (int k = 0; k < 128; ++k) {
        float a0 = hs[tr * 4 + 0][k];
        float a1 = hs[tr * 4 + 1][k];
        float a2 = hs[tr * 4 + 2][k];
        float a3 = hs[tr * 4 + 3][k];
        float4 wv = *(const float4*)&ws[k][tc * 4];
        acc[0][0] = fmaf(a0, wv.x, acc[0][0]); acc[0][1] = fmaf(a0, wv.y, acc[0][1]);
        acc[0][2] = fmaf(a0, wv.z, acc[0][2]); acc[0][3] = fmaf(a0, wv.w, acc[0][3]);
        acc[1][0] = fmaf(a1, wv.x, acc[1][0]); acc[1][1] = fmaf(a1, wv.y, acc[1][1]);
        acc[1][2] = fmaf(a1, wv.z, acc[1][2]); acc[1][3] = fmaf(a1, wv.w, acc[1][3]);
        acc[2][0] = fmaf(a2, wv.x, acc[2][0]); acc[2][1] = fmaf(a2, wv.y, acc[2][1]);
        acc[2][2] = fmaf(a2, wv.z, acc[2][2]); acc[2][3] = fmaf(a2, wv.w, acc[2][3]);
        acc[3][0] = fmaf(a3, wv.x, acc[3][0]); acc[3][1] = fmaf(a3, wv.y, acc[3][1]);
        acc[3][2] = fmaf(a3, wv.z, acc[3][2]); acc[3][3] = fmaf(a3, wv.w, acc[3][3]);
    }
    #pragma unroll
    for (int i = 0; i < 4; ++i) {
        int n = n0 + tr * 4 + i;
        if (n < N) {
            float4 o = make_float4(acc[i][0], acc[i][1], acc[i][2], acc[i][3]);
            *(float4*)&Z[(size_t)n * HDout + c0 + tc * 4] = o;
        }
    }
}

// ---------------- el/er: per-node attention logits ----------------
// HD=128, D=32: lane owns channels l and l+64; 32-lane-group reduce.

__global__ void elr128_kernel(const float* __restrict__ z, const float* __restrict__ al,
                              const float* __restrict__ ar, float* __restrict__ el,
                              float* __restrict__ er, int N) {
    int l = threadIdx.x & 63;
    int v = blockIdx.x * 4 + (threadIdx.x >> 6);
    if (v >= N) return;
    const float* zr = z + (size_t)v * 128;
    float z0 = zr[l], z1 = zr[l + 64];
    float pl0 = z0 * al[l], pl1 = z1 * al[l + 64];
    float pr0 = z0 * ar[l], pr1 = z1 * ar[l + 64];
    #pragma unroll
    for (int off = 1; off < 32; off <<= 1) {
        pl0 += __shfl_xor(pl0, off);
        pl1 += __shfl_xor(pl1, off);
        pr0 += __shfl_xor(pr0, off);
        pr1 += __shfl_xor(pr1, off);
    }
    if ((l & 31) == 0) {
        int g = l >> 5;  // 0 or 1
        el[(size_t)v * 4 + g] = pl0;
        el[(size_t)v * 4 + 2 + g] = pl1;
        er[(size_t)v * 4 + g] = pr0;
        er[(size_t)v * 4 + 2 + g] = pr1;
    }
}

// HD=256, D=64: lane owns c = l + 64*j, j=0..3 (head j); full-wave reduce.
__global__ void elr256_kernel(const float* __restrict__ z, const float* __restrict__ al,
                              const float* __restrict__ ar, float* __restrict__ el,
                              float* __restrict__ er, int N) {
    int l = threadIdx.x & 63;
    int v = blockIdx.x * 4 + (threadIdx.x >> 6);
    if (v >= N) return;
    const float* zr = z + (size_t)v * 256;
    float pl[4], pr[4];
    #pragma unroll
    for (int j = 0; j < 4; ++j) {
        int c = l + 64 * j;
        float zc = zr[c];
        pl[j] = zc * al[c];
        pr[j] = zc * ar[c];
    }
    #pragma unroll
    for (int off = 1; off < 64; off <<= 1) {
        #pragma unroll
        for (int j = 0; j < 4; ++j) {
            pl[j] += __shfl_xor(pl[j], off);
            pr[j] += __shfl_xor(pr[j], off);
        }
    }
    if (l == 0) {
        #pragma unroll
        for (int j = 0; j < 4; ++j) {
            el[(size_t)v * 4 + j] = pl[j];
            er[(size_t)v * 4 + j] = pr[j];
        }
    }
}

// ---------------- per-edge logits: e = leaky_relu(el[src]+er[dst], 0.2) ----------------

__global__ void edge_e_kernel(const int* __restrict__ src, const int* __restrict__ dst,
                              const float* __restrict__ el, const float* __restrict__ er,
                              float* __restrict__ e, int E) {
    int t = blockIdx.x * blockDim.x + threadIdx.x;
    if (t >= E * 4) return;
    int i = t >> 2, h = t & 3;
    float x = el[(size_t)src[i] * 4 + h] + er[(size_t)dst[i] * 4 + h];
    e[t] = (x >= 0.f) ? x : 0.2f * x;
}

// ---------------- per-node softmax + aggregate (one wave per node) ----------------
// HD=128: lane owns channels 2l,2l+1 (single head h=l>>4).

template <bool RELU>
__global__ __launch_bounds__(256) void agg128_kernel(
        const float* __restrict__ z, const float* __restrict__ e,
        const int* __restrict__ src, const int* __restrict__ rowptr,
        const int* __restrict__ eidx, const float* __restrict__ bias,
        float* __restrict__ out, int N) {
    int l = threadIdx.x & 63;
    int v = blockIdx.x * 4 + (threadIdx.x >> 6);
    if (v >= N) return;
    int r0 = rowptr[v], r1 = rowptr[v + 1];
    int c0 = l * 2;
    int h = l >> 4;
    float b0 = bias[c0], b1 = bias[c0 + 1];
    float ox, oy;
    if (r1 == r0) {
        ox = b0; oy = b1;  // empty segment: segment_sum = 0, out = bias
    } else {
        float m0 = NEG_BIG, m1 = NEG_BIG, m2 = NEG_BIG, m3 = NEG_BIG;
        for (int i = r0 + l; i < r1; i += 64) {
            int eid = eidx[i];
            float4 ev = *(const float4*)(e + (size_t)eid * 4);
            m0 = fmaxf(m0, ev.x); m1 = fmaxf(m1, ev.y);
            m2 = fmaxf(m2, ev.z); m3 = fmaxf(m3, ev.w);
        }
        #pragma unroll
        for (int off = 1; off < 64; off <<= 1) {
            m0 = fmaxf(m0, __shfl_xor(m0, off));
            m1 = fmaxf(m1, __shfl_xor(m1, off));
            m2 = fmaxf(m2, __shfl_xor(m2, off));
            m3 = fmaxf(m3, __shfl_xor(m3, off));
        }
        float m = (h == 0) ? m0 : (h == 1) ? m1 : (h == 2) ? m2 : m3;
        float s = 0.f, ax = 0.f, ay = 0.f;
        for (int i = r0; i < r1; ++i) {
            int eid = eidx[i];
            int sv = src[eid];
            float ev = e[(size_t)eid * 4 + h];
            float ex = __expf(ev - m);
            s += ex;
            float2 zz = *(const float2*)(z + (size_t)sv * 128 + c0);
            ax = fmaf(zz.x, ex, ax);
            ay = fmaf(zz.y, ex, ay);
        }
        float inv = 1.f / s;  // s >= 1 (max edge contributes exp(0)=1)
        ox = fmaf(ax, inv, b0);
        oy = fmaf(ay, inv, b1);
    }
    if (RELU) { ox = fmaxf(ox, 0.f); oy = fmaxf(oy, 0.f); }
    *(float2*)(out + (size_t)v * 128 + c0) = make_float2(ox, oy);
}

// HD=256: lane owns channels 4l..4l+3 (single head h=l>>4).
template <bool RELU>
__global__ __launch_bounds__(256) void agg256_kernel(
        const float* __restrict__ z, const float* __restrict__ e,
        const int* __restrict__ src, const int* __restrict__ rowptr,
        const int* __restrict__ eidx, const float* __restrict__ bias,
        float* __restrict__ out, int N) {
    int l = threadIdx.x & 63;
    int v = blockIdx.x * 4 + (threadIdx.x >> 6);
    if (v >= N) return;
    int r0 = rowptr[v], r1 = rowptr[v + 1];
    int c0 = l * 4;
    int h = l >> 4;
    float4 bv = *(const float4*)(bias + c0);
    float4 o;
    if (r1 == r0) {
        o = bv;
    } else {
        float m0 = NEG_BIG, m1 = NEG_BIG, m2 = NEG_BIG, m3 = NEG_BIG;
        for (int i = r0 + l; i < r1; i += 64) {
            int eid = eidx[i];
            float4 ev = *(const float4*)(e + (size_t)eid * 4);
            m0 = fmaxf(m0, ev.x); m1 = fmaxf(m1, ev.y);
            m2 = fmaxf(m2, ev.z); m3 = fmaxf(m3, ev.w);
        }
        #pragma unroll
        for (int off = 1; off < 64; off <<= 1) {
            m0 = fmaxf(m0, __shfl_xor(m0, off));
            m1 = fmaxf(m1, __shfl_xor(m1, off));
            m2 = fmaxf(m2, __shfl_xor(m2, off));
            m3 = fmaxf(m3, __shfl_xor(m3, off));
        }
        float m = (h == 0) ? m0 : (h == 1) ? m1 : (h == 2) ? m2 : m3;
        float s = 0.f, ax = 0.f, ay = 0.f, az = 0.f, aw = 0.f;
        for (int i = r0; i < r1; ++i) {
            int eid = eidx[i];
            int sv = src[eid];
            float ev = e[(size_t)eid * 4 + h];
            float ex = __expf(ev - m);
            s += ex;
            float4 zz = *(const float4*)(z + (size_t)sv * 256 + c0);
            ax = fmaf(zz.x, ex, ax); ay = fmaf(zz.y, ex, ay);
            az = fmaf(zz.z, ex, az); aw = fmaf(zz.w, ex, aw);
        }
        float inv = 1.f / s;
        o.x = fmaf(ax, inv, bv.x); o.y = fmaf(ay, inv, bv.y);
        o.z = fmaf(az, inv, bv.z); o.w = fmaf(aw, inv, bv.w);
    }
    if (RELU) {
        o.x = fmaxf(o.x, 0.f); o.y = fmaxf(o.y, 0.f);
        o.z = fmaxf(o.z, 0.f); o.w = fmaxf(o.w, 0.f);
    }
    *(float4*)(out + (size_t)v * 256 + c0) = o;
}

// ---------------- launch ----------------

extern "C" void kernel_launch(void* const* d_in, const int* in_sizes, int n_in,
                              void* d_out, int out_size, void* d_ws, size_t ws_size,
                              hipStream_t stream) {
    const float* feat = (const float*)d_in[0];
    const int* src = (const int*)d_in[1];
    const int* dst = (const int*)d_in[2];
    const float* W1 = (const float*)d_in[3];
    const float* al1 = (const float*)d_in[4];
    const float* ar1 = (const float*)d_in[5];
    const float* b1 = (const float*)d_in[6];
    const float* W2 = (const float*)d_in[7];
    const float* al2 = (const float*)d_in[8];
    const float* ar2 = (const float*)d_in[9];
    const float* b2 = (const float*)d_in[10];
    const float* W3 = (const float*)d_in[11];
    const float* al3 = (const float*)d_in[12];
    const float* ar3 = (const float*)d_in[13];
    const float* b3 = (const float*)d_in[14];
    const int N = in_sizes[0] / 2;   // feat is [N,2]
    const int E = in_sizes[1];

    // workspace layout (f32 unless noted)
    float* z = (float*)d_ws;                       // [N,256] (layers 1-2 use first [N,128])
    float* hbuf = z + (size_t)N * 256;             // [N,128]
    float* el = hbuf + (size_t)N * 128;            // [N,4]
    float* er = el + (size_t)N * 4;                // [N,4]
    float* e = er + (size_t)N * 4;                 // [E,4] (16B aligned)
    int* deg = (int*)(e + (size_t)E * 4);          // [N]
    int* cursor = deg + N;                         // [N]
    int* rowptr = cursor + N;                      // [N+1]
    int* eidx = rowptr + (N + 1);                  // [E]

    // CSR build (per call; deterministic up to fill order)
    hipMemsetAsync(deg, 0, sizeof(int) * (size_t)(2 * N), stream);  // deg + cursor
    count_deg_kernel<<<cdiv(E, 256), 256, 0, stream>>>(dst, deg, E);
    scan_kernel<<<1, 1024, 0, stream>>>(deg, rowptr, N);
    fill_csr_kernel<<<cdiv(E, 256), 256, 0, stream>>>(dst, rowptr, cursor, eidx, E);

    const int nodeBlocks = cdiv(N, 4);
    const int edgeHBlocks = cdiv(E * 4, 256);

    // ---- layer 1 (2 -> 128, relu) ----
    z1_kernel<<<cdiv(N * 128, 256), 256, 0, stream>>>(feat, W1, z, N);
    elr128_kernel<<<nodeBlocks, 256, 0, stream>>>(z, al1, ar1, el, er, N);
    edge_e_kernel<<<edgeHBlocks, 256, 0, stream>>>(src, dst, el, er, e, E);
    agg128_kernel<true><<<nodeBlocks, 256, 0, stream>>>(z, e, src, rowptr, eidx, b1, hbuf, N);

    // ---- layer 2 (128 -> 128, relu) ----
    gemm_tile_kernel<<<dim3(cdiv(N, 64), 2), 256, 0, stream>>>(hbuf, W2, z, N, 128);
    elr128_kernel<<<nodeBlocks, 256, 0, stream>>>(z, al2, ar2, el, er, N);
    edge_e_kernel<<<edgeHBlocks, 256, 0, stream>>>(src, dst, el, er, e, E);
    agg128_kernel<true><<<nodeBlocks, 256, 0, stream>>>(z, e, src, rowptr, eidx, b2, hbuf, N);

    // ---- layer 3 (128 -> 256, no relu) ----
    gemm_tile_kernel<<<dim3(cdiv(N, 64), 4), 256, 0, stream>>>(hbuf, W3, z, N, 256);
    elr256_kernel<<<nodeBlocks, 256, 0, stream>>>(z, al3, ar3, el, er, N);
    edge_e_kernel<<<edgeHBlocks, 256, 0, stream>>>(src, dst, el, er, e, E);
    agg256_kernel<false><<<nodeBlocks, 256, 0, stream>>>(z, e, src, rowptr, eidx, b3,
                                                         (float*)d_out, N);
}

// Round 5
// 674.489 us; speedup vs baseline: 1.2935x; 1.2935x over previous
//
#include <hip/hip_runtime.h>
#include <math.h>

// GAT 3-layer inference on MI355X.
// R4: latency-bound agg fix — csr stores src values directly (no eidx
// indirection), edge_e fused into agg (e recomputed from el/er inline),
// per-wave batched src prefetch + __shfl broadcast, unroll-4 gather loop.

#define NEG_BIG (-1e38f)

static inline int cdiv(int a, int b) { return (a + b - 1) / b; }

// ---------------- CSR build ----------------

__global__ void count_deg_kernel(const int* __restrict__ dst, int* __restrict__ deg, int E) {
    int i = blockIdx.x * blockDim.x + threadIdx.x;
    if (i < E) atomicAdd(&deg[dst[i]], 1);
}

// single-block exclusive scan over N (~50000) elements
__global__ void scan_kernel(const int* __restrict__ deg, int* __restrict__ rowptr, int n) {
    __shared__ int sums[1024];
    int t = threadIdx.x;
    int chunk = (n + 1023) >> 10;
    int s0 = t * chunk;
    int s1 = min(s0 + chunk, n);
    if (s1 < s0) s1 = s0;
    int tot = 0;
    for (int i = s0; i < s1; ++i) tot += deg[i];
    sums[t] = tot;
    __syncthreads();
    for (int off = 1; off < 1024; off <<= 1) {
        int val = (t >= off) ? sums[t - off] : 0;
        __syncthreads();
        sums[t] += val;
        __syncthreads();
    }
    int excl = sums[t] - tot;
    for (int i = s0; i < s1; ++i) { rowptr[i] = excl; excl += deg[i]; }
    if (t == 1023) rowptr[n] = sums[1023];
}

// store the SRC VALUE in CSR order (kills the eidx->src indirection)
__global__ void fill_csr_kernel(const int* __restrict__ src, const int* __restrict__ dst,
                                const int* __restrict__ rowptr,
                                int* __restrict__ cursor, int* __restrict__ csrc, int E) {
    int i = blockIdx.x * blockDim.x + threadIdx.x;
    if (i < E) {
        int d = dst[i];
        int pos = atomicAdd(&cursor[d], 1);
        csrc[rowptr[d] + pos] = src[i];
    }
}

// ---------------- layer 1 projection (Fin=2) ----------------

__global__ void z1_kernel(const float* __restrict__ feat, const float* __restrict__ W1,
                          float* __restrict__ z, int N) {
    int t = blockIdx.x * blockDim.x + threadIdx.x;
    int n = t >> 7;
    if (n >= N) return;
    int j = t & 127;
    float f0 = feat[(size_t)n * 2];
    float f1 = feat[(size_t)n * 2 + 1];
    z[t] = fmaf(f0, W1[j], f1 * W1[128 + j]);
}

// ---------------- GEMM: A[N,128] @ W[128,HDout] -> Z[N,HDout] ----------------

__global__ __launch_bounds__(256) void gemm_tile_kernel(
        const float* __restrict__ A, const float* __restrict__ W,
        float* __restrict__ Z, int N, int HDout) {
    __shared__ __align__(16) float hs[64][129];
    __shared__ __align__(16) float ws[128][64];
    int n0 = blockIdx.x * 64;
    int c0 = blockIdx.y * 64;
    int t = threadIdx.x;
    for (int idx = t; idx < 64 * 128; idx += 256) {
        int r = idx >> 7, k = idx & 127;
        int n = n0 + r;
        hs[r][k] = (n < N) ? A[(size_t)n * 128 + k] : 0.f;
    }
    for (int idx = t; idx < 128 * 64; idx += 256) {
        int k = idx >> 6, c = idx & 63;
        ws[k][c] = W[(size_t)k * HDout + c0 + c];
    }
    __syncthreads();
    int tr = t >> 4, tc = t & 15;
    float acc[4][4] = {};
    #pragma unroll 4
    for (int k = 0; k < 128; ++k) {
        float a0 = hs[tr * 4 + 0][k];
        float a1 = hs[tr * 4 + 1][k];
        float a2 = hs[tr * 4 + 2][k];
        float a3 = hs[tr * 4 + 3][k];
        float4 wv = *(const float4*)&ws[k][tc * 4];
        acc[0][0] = fmaf(a0, wv.x, acc[0][0]); acc[0][1] = fmaf(a0, wv.y, acc[0][1]);
        acc[0][2] = fmaf(a0, wv.z, acc[0][2]); acc[0][3] = fmaf(a0, wv.w, acc[0][3]);
        acc[1][0] = fmaf(a1, wv.x, acc[1][0]); acc[1][1] = fmaf(a1, wv.y, acc[1][1]);
        acc[1][2] = fmaf(a1, wv.z, acc[1][2]); acc[1][3] = fmaf(a1, wv.w, acc[1][3]);
        acc[2][0] = fmaf(a2, wv.x, acc[2][0]); acc[2][1] = fmaf(a2, wv.y, acc[2][1]);
        acc[2][2] = fmaf(a2, wv.z, acc[2][2]); acc[2][3] = fmaf(a2, wv.w, acc[2][3]);
        acc[3][0] = fmaf(a3, wv.x, acc[3][0]); acc[3][1] = fmaf(a3, wv.y, acc[3][1]);
        acc[3][2] = fmaf(a3, wv.z, acc[3][2]); acc[3][3] = fmaf(a3, wv.w, acc[3][3]);
    }
    #pragma unroll
    for (int i = 0; i < 4; ++i) {
        int n = n0 + tr * 4 + i;
        if (n < N) {
            float4 o = make_float4(acc[i][0], acc[i][1], acc[i][2], acc[i][3]);
            *(float4*)&Z[(size_t)n * HDout + c0 + tc * 4] = o;
        }
    }
}

// ---------------- el/er: per-node attention logits ----------------

__global__ void elr128_kernel(const float* __restrict__ z, const float* __restrict__ al,
                              const float* __restrict__ ar, float* __restrict__ el,
                              float* __restrict__ er, int N) {
    int l = threadIdx.x & 63;
    int v = blockIdx.x * 4 + (threadIdx.x >> 6);
    if (v >= N) return;
    const float* zr = z + (size_t)v * 128;
    float z0 = zr[l], z1 = zr[l + 64];
    float pl0 = z0 * al[l], pl1 = z1 * al[l + 64];
    float pr0 = z0 * ar[l], pr1 = z1 * ar[l + 64];
    #pragma unroll
    for (int off = 1; off < 32; off <<= 1) {
        pl0 += __shfl_xor(pl0, off);
        pl1 += __shfl_xor(pl1, off);
        pr0 += __shfl_xor(pr0, off);
        pr1 += __shfl_xor(pr1, off);
    }
    if ((l & 31) == 0) {
        int g = l >> 5;  // 0 or 1
        el[(size_t)v * 4 + g] = pl0;
        el[(size_t)v * 4 + 2 + g] = pl1;
        er[(size_t)v * 4 + g] = pr0;
        er[(size_t)v * 4 + 2 + g] = pr1;
    }
}

__global__ void elr256_kernel(const float* __restrict__ z, const float* __restrict__ al,
                              const float* __restrict__ ar, float* __restrict__ el,
                              float* __restrict__ er, int N) {
    int l = threadIdx.x & 63;
    int v = blockIdx.x * 4 + (threadIdx.x >> 6);
    if (v >= N) return;
    const float* zr = z + (size_t)v * 256;
    float pl[4], pr[4];
    #pragma unroll
    for (int j = 0; j < 4; ++j) {
        int c = l + 64 * j;
        float zc = zr[c];
        pl[j] = zc * al[c];
        pr[j] = zc * ar[c];
    }
    #pragma unroll
    for (int off = 1; off < 64; off <<= 1) {
        #pragma unroll
        for (int j = 0; j < 4; ++j) {
            pl[j] += __shfl_xor(pl[j], off);
            pr[j] += __shfl_xor(pr[j], off);
        }
    }
    if (l == 0) {
        #pragma unroll
        for (int j = 0; j < 4; ++j) {
            el[(size_t)v * 4 + j] = pl[j];
            er[(size_t)v * 4 + j] = pr[j];
        }
    }
}

// ---------------- fused edge-softmax + aggregate (one wave per node) ----------------
// CPL = channels per lane (HD/64). Lane owns channels [l*CPL, l*CPL+CPL),
// which all belong to head h = l>>4. e = leaky_relu(el[src]+er[dst]) is
// recomputed inline (el is an L2-hot 800KB array). Pass 1 prefetches up to
// 64 src ids per wave (strided) and computes per-head maxes; pass 2
// broadcasts src ids via __shfl (readlane) so each edge iteration issues
// two INDEPENDENT loads (el scalar + z vector) with no pointer chase.

template <bool RELU, int CPL>
__global__ __launch_bounds__(256) void agg_kernel(
        const float* __restrict__ z, const float* __restrict__ el,
        const float* __restrict__ er, const int* __restrict__ rowptr,
        const int* __restrict__ csrc, const float* __restrict__ bias,
        float* __restrict__ out, int N) {
    const int HD = CPL * 64;
    int l = threadIdx.x & 63;
    int v = blockIdx.x * 4 + (threadIdx.x >> 6);
    if (v >= N) return;
    int r0 = rowptr[v], r1 = rowptr[v + 1];
    int c0 = l * CPL;
    int h = l >> 4;
    float b[CPL];
    #pragma unroll
    for (int c = 0; c < CPL; ++c) b[c] = bias[c0 + c];
    float o[CPL];

    if (r0 == r1) {
        #pragma unroll
        for (int c = 0; c < CPL; ++c) o[c] = b[c];
    } else {
        float4 er4 = *(const float4*)(er + (size_t)v * 4);
        float er_h = (h == 0) ? er4.x : (h == 1) ? er4.y : (h == 2) ? er4.z : er4.w;

        // ---- pass 1: per-head max of leaky_relu(el[src]+er[v]) ----
        float m0 = NEG_BIG, m1 = NEG_BIG, m2 = NEG_BIG, m3 = NEG_BIG;
        int sv0 = 0;  // first-chunk prefetch, reused in pass 2
        {
            int i = r0 + l;
            if (i < r1) {
                sv0 = csrc[i];
                float4 ev = *(const float4*)(el + (size_t)sv0 * 4);
                float x;
                x = ev.x + er4.x; m0 = (x >= 0.f) ? x : 0.2f * x;
                x = ev.y + er4.y; m1 = (x >= 0.f) ? x : 0.2f * x;
                x = ev.z + er4.z; m2 = (x >= 0.f) ? x : 0.2f * x;
                x = ev.w + er4.w; m3 = (x >= 0.f) ? x : 0.2f * x;
            }
        }
        for (int base = r0 + 64; base < r1; base += 64) {
            int i = base + l;
            if (i < r1) {
                int sv = csrc[i];
                float4 ev = *(const float4*)(el + (size_t)sv * 4);
                float x;
                x = ev.x + er4.x; m0 = fmaxf(m0, (x >= 0.f) ? x : 0.2f * x);
                x = ev.y + er4.y; m1 = fmaxf(m1, (x >= 0.f) ? x : 0.2f * x);
                x = ev.z + er4.z; m2 = fmaxf(m2, (x >= 0.f) ? x : 0.2f * x);
                x = ev.w + er4.w; m3 = fmaxf(m3, (x >= 0.f) ? x : 0.2f * x);
            }
        }
        #pragma unroll
        for (int off = 1; off < 64; off <<= 1) {
            m0 = fmaxf(m0, __shfl_xor(m0, off));
            m1 = fmaxf(m1, __shfl_xor(m1, off));
            m2 = fmaxf(m2, __shfl_xor(m2, off));
            m3 = fmaxf(m3, __shfl_xor(m3, off));
        }
        float m = (h == 0) ? m0 : (h == 1) ? m1 : (h == 2) ? m2 : m3;

        // ---- pass 2: sum exp + weighted z gather ----
        float s = 0.f;
        float acc[CPL];
        #pragma unroll
        for (int c = 0; c < CPL; ++c) acc[c] = 0.f;

        for (int base = r0; base < r1; base += 64) {
            int cnt = min(64, r1 - base);
            int svl = (base == r0) ? sv0
                                   : ((base + l < r1) ? csrc[base + l] : 0);
            #pragma unroll 4
            for (int k = 0; k < cnt; ++k) {
                int sv = __shfl(svl, k);
                float ev = el[(size_t)sv * 4 + h] + er_h;
                ev = (ev >= 0.f) ? ev : 0.2f * ev;
                float ex = __expf(ev - m);
                s += ex;
                const float* zr = z + (size_t)sv * HD + c0;
                if constexpr (CPL == 4) {
                    float4 zz = *(const float4*)zr;
                    acc[0] = fmaf(zz.x, ex, acc[0]);
                    acc[1] = fmaf(zz.y, ex, acc[1]);
                    acc[2] = fmaf(zz.z, ex, acc[2]);
                    acc[3] = fmaf(zz.w, ex, acc[3]);
                } else {
                    float2 zz = *(const float2*)zr;
                    acc[0] = fmaf(zz.x, ex, acc[0]);
                    acc[1] = fmaf(zz.y, ex, acc[1]);
                }
            }
        }
        float inv = 1.f / s;  // s >= 1 (max edge contributes exp(0)=1)
        #pragma unroll
        for (int c = 0; c < CPL; ++c) o[c] = fmaf(acc[c], inv, b[c]);
    }
    if (RELU) {
        #pragma unroll
        for (int c = 0; c < CPL; ++c) o[c] = fmaxf(o[c], 0.f);
    }
    float* op = out + (size_t)v * HD + c0;
    if constexpr (CPL == 4) {
        *(float4*)op = make_float4(o[0], o[1], o[2], o[3]);
    } else {
        *(float2*)op = make_float2(o[0], o[1]);
    }
}

// ---------------- launch ----------------

extern "C" void kernel_launch(void* const* d_in, const int* in_sizes, int n_in,
                              void* d_out, int out_size, void* d_ws, size_t ws_size,
                              hipStream_t stream) {
    const float* feat = (const float*)d_in[0];
    const int* src = (const int*)d_in[1];
    const int* dst = (const int*)d_in[2];
    const float* W1 = (const float*)d_in[3];
    const float* al1 = (const float*)d_in[4];
    const float* ar1 = (const float*)d_in[5];
    const float* b1 = (const float*)d_in[6];
    const float* W2 = (const float*)d_in[7];
    const float* al2 = (const float*)d_in[8];
    const float* ar2 = (const float*)d_in[9];
    const float* b2 = (const float*)d_in[10];
    const float* W3 = (const float*)d_in[11];
    const float* al3 = (const float*)d_in[12];
    const float* ar3 = (const float*)d_in[13];
    const float* b3 = (const float*)d_in[14];
    const int N = in_sizes[0] / 2;   // feat is [N,2]
    const int E = in_sizes[1];

    // workspace layout
    float* z = (float*)d_ws;                       // [N,256]
    float* hbuf = z + (size_t)N * 256;             // [N,128]
    float* el = hbuf + (size_t)N * 128;            // [N,4]
    float* er = el + (size_t)N * 4;                // [N,4]
    int* csrc = (int*)(er + (size_t)N * 4);        // [E] src values in CSR order
    int* deg = csrc + E;                           // [N]
    int* cursor = deg + N;                         // [N]
    int* rowptr = cursor + N;                      // [N+1]

    // CSR build (per call)
    hipMemsetAsync(deg, 0, sizeof(int) * (size_t)(2 * N), stream);  // deg + cursor
    count_deg_kernel<<<cdiv(E, 256), 256, 0, stream>>>(dst, deg, E);
    scan_kernel<<<1, 1024, 0, stream>>>(deg, rowptr, N);
    fill_csr_kernel<<<cdiv(E, 256), 256, 0, stream>>>(src, dst, rowptr, cursor, csrc, E);

    const int nodeBlocks = cdiv(N, 4);

    // ---- layer 1 (2 -> 128, relu) ----
    z1_kernel<<<cdiv(N * 128, 256), 256, 0, stream>>>(feat, W1, z, N);
    elr128_kernel<<<nodeBlocks, 256, 0, stream>>>(z, al1, ar1, el, er, N);
    agg_kernel<true, 2><<<nodeBlocks, 256, 0, stream>>>(z, el, er, rowptr, csrc, b1, hbuf, N);

    // ---- layer 2 (128 -> 128, relu) ----
    gemm_tile_kernel<<<dim3(cdiv(N, 64), 2), 256, 0, stream>>>(hbuf, W2, z, N, 128);
    elr128_kernel<<<nodeBlocks, 256, 0, stream>>>(z, al2, ar2, el, er, N);
    agg_kernel<true, 2><<<nodeBlocks, 256, 0, stream>>>(z, el, er, rowptr, csrc, b2, hbuf, N);

    // ---- layer 3 (128 -> 256, no relu) ----
    gemm_tile_kernel<<<dim3(cdiv(N, 64), 4), 256, 0, stream>>>(hbuf, W3, z, N, 256);
    elr256_kernel<<<nodeBlocks, 256, 0, stream>>>(z, al3, ar3, el, er, N);
    agg_kernel<false, 4><<<nodeBlocks, 256, 0, stream>>>(z, el, er, rowptr, csrc, b3,
                                                         (float*)d_out, N);
}

// Round 6
// 666.816 us; speedup vs baseline: 1.3084x; 1.0115x over previous
//
#include <hip/hip_runtime.h>
#include <math.h>

// GAT 3-layer inference on MI355X.
// R5: agg pass-2 restructure — per-edge exp computed once (lane-vectorized,
// all 4 heads) and staged in padded LDS; softmax denom via wave reduction;
// inner gather loop is pure {2 broadcast ds_read + z float4 load + fma},
// unroll-8 for 8 gathers in flight per wave.

#define NEG_BIG (-1e38f)

static inline int cdiv(int a, int b) { return (a + b - 1) / b; }

__device__ __forceinline__ float lrelu(float x) { return (x >= 0.f) ? x : 0.2f * x; }

// ---------------- CSR build ----------------

__global__ void count_deg_kernel(const int* __restrict__ dst, int* __restrict__ deg, int E) {
    int i = blockIdx.x * blockDim.x + threadIdx.x;
    if (i < E) atomicAdd(&deg[dst[i]], 1);
}

// single-block exclusive scan over N (~50000) elements
__global__ void scan_kernel(const int* __restrict__ deg, int* __restrict__ rowptr, int n) {
    __shared__ int sums[1024];
    int t = threadIdx.x;
    int chunk = (n + 1023) >> 10;
    int s0 = t * chunk;
    int s1 = min(s0 + chunk, n);
    if (s1 < s0) s1 = s0;
    int tot = 0;
    for (int i = s0; i < s1; ++i) tot += deg[i];
    sums[t] = tot;
    __syncthreads();
    for (int off = 1; off < 1024; off <<= 1) {
        int val = (t >= off) ? sums[t - off] : 0;
        __syncthreads();
        sums[t] += val;
        __syncthreads();
    }
    int excl = sums[t] - tot;
    for (int i = s0; i < s1; ++i) { rowptr[i] = excl; excl += deg[i]; }
    if (t == 1023) rowptr[n] = sums[1023];
}

// store the SRC VALUE in CSR order (no eidx indirection)
__global__ void fill_csr_kernel(const int* __restrict__ src, const int* __restrict__ dst,
                                const int* __restrict__ rowptr,
                                int* __restrict__ cursor, int* __restrict__ csrc, int E) {
    int i = blockIdx.x * blockDim.x + threadIdx.x;
    if (i < E) {
        int d = dst[i];
        int pos = atomicAdd(&cursor[d], 1);
        csrc[rowptr[d] + pos] = src[i];
    }
}

// ---------------- layer 1 projection (Fin=2) ----------------

__global__ void z1_kernel(const float* __restrict__ feat, const float* __restrict__ W1,
                          float* __restrict__ z, int N) {
    int t = blockIdx.x * blockDim.x + threadIdx.x;
    int n = t >> 7;
    if (n >= N) return;
    int j = t & 127;
    float f0 = feat[(size_t)n * 2];
    float f1 = feat[(size_t)n * 2 + 1];
    z[t] = fmaf(f0, W1[j], f1 * W1[128 + j]);
}

// ---------------- GEMM: A[N,128] @ W[128,HDout] -> Z[N,HDout] ----------------

__global__ __launch_bounds__(256) void gemm_tile_kernel(
        const float* __restrict__ A, const float* __restrict__ W,
        float* __restrict__ Z, int N, int HDout) {
    __shared__ __align__(16) float hs[64][129];
    __shared__ __align__(16) float ws[128][64];
    int n0 = blockIdx.x * 64;
    int c0 = blockIdx.y * 64;
    int t = threadIdx.x;
    for (int idx = t; idx < 64 * 128; idx += 256) {
        int r = idx >> 7, k = idx & 127;
        int n = n0 + r;
        hs[r][k] = (n < N) ? A[(size_t)n * 128 + k] : 0.f;
    }
    for (int idx = t; idx < 128 * 64; idx += 256) {
        int k = idx >> 6, c = idx & 63;
        ws[k][c] = W[(size_t)k * HDout + c0 + c];
    }
    __syncthreads();
    int tr = t >> 4, tc = t & 15;
    float acc[4][4] = {};
    #pragma unroll 4
    for (int k = 0; k < 128; ++k) {
        float a0 = hs[tr * 4 + 0][k];
        float a1 = hs[tr * 4 + 1][k];
        float a2 = hs[tr * 4 + 2][k];
        float a3 = hs[tr * 4 + 3][k];
        float4 wv = *(const float4*)&ws[k][tc * 4];
        acc[0][0] = fmaf(a0, wv.x, acc[0][0]); acc[0][1] = fmaf(a0, wv.y, acc[0][1]);
        acc[0][2] = fmaf(a0, wv.z, acc[0][2]); acc[0][3] = fmaf(a0, wv.w, acc[0][3]);
        acc[1][0] = fmaf(a1, wv.x, acc[1][0]); acc[1][1] = fmaf(a1, wv.y, acc[1][1]);
        acc[1][2] = fmaf(a1, wv.z, acc[1][2]); acc[1][3] = fmaf(a1, wv.w, acc[1][3]);
        acc[2][0] = fmaf(a2, wv.x, acc[2][0]); acc[2][1] = fmaf(a2, wv.y, acc[2][1]);
        acc[2][2] = fmaf(a2, wv.z, acc[2][2]); acc[2][3] = fmaf(a2, wv.w, acc[2][3]);
        acc[3][0] = fmaf(a3, wv.x, acc[3][0]); acc[3][1] = fmaf(a3, wv.y, acc[3][1]);
        acc[3][2] = fmaf(a3, wv.z, acc[3][2]); acc[3][3] = fmaf(a3, wv.w, acc[3][3]);
    }
    #pragma unroll
    for (int i = 0; i < 4; ++i) {
        int n = n0 + tr * 4 + i;
        if (n < N) {
            float4 o = make_float4(acc[i][0], acc[i][1], acc[i][2], acc[i][3]);
            *(float4*)&Z[(size_t)n * HDout + c0 + tc * 4] = o;
        }
    }
}

// ---------------- el/er: per-node attention logits ----------------

__global__ void elr128_kernel(const float* __restrict__ z, const float* __restrict__ al,
                              const float* __restrict__ ar, float* __restrict__ el,
                              float* __restrict__ er, int N) {
    int l = threadIdx.x & 63;
    int v = blockIdx.x * 4 + (threadIdx.x >> 6);
    if (v >= N) return;
    const float* zr = z + (size_t)v * 128;
    float z0 = zr[l], z1 = zr[l + 64];
    float pl0 = z0 * al[l], pl1 = z1 * al[l + 64];
    float pr0 = z0 * ar[l], pr1 = z1 * ar[l + 64];
    #pragma unroll
    for (int off = 1; off < 32; off <<= 1) {
        pl0 += __shfl_xor(pl0, off);
        pl1 += __shfl_xor(pl1, off);
        pr0 += __shfl_xor(pr0, off);
        pr1 += __shfl_xor(pr1, off);
    }
    if ((l & 31) == 0) {
        int g = l >> 5;  // 0 or 1
        el[(size_t)v * 4 + g] = pl0;
        el[(size_t)v * 4 + 2 + g] = pl1;
        er[(size_t)v * 4 + g] = pr0;
        er[(size_t)v * 4 + 2 + g] = pr1;
    }
}

__global__ void elr256_kernel(const float* __restrict__ z, const float* __restrict__ al,
                              const float* __restrict__ ar, float* __restrict__ el,
                              float* __restrict__ er, int N) {
    int l = threadIdx.x & 63;
    int v = blockIdx.x * 4 + (threadIdx.x >> 6);
    if (v >= N) return;
    const float* zr = z + (size_t)v * 256;
    float pl[4], pr[4];
    #pragma unroll
    for (int j = 0; j < 4; ++j) {
        int c = l + 64 * j;
        float zc = zr[c];
        pl[j] = zc * al[c];
        pr[j] = zc * ar[c];
    }
    #pragma unroll
    for (int off = 1; off < 64; off <<= 1) {
        #pragma unroll
        for (int j = 0; j < 4; ++j) {
            pl[j] += __shfl_xor(pl[j], off);
            pr[j] += __shfl_xor(pr[j], off);
        }
    }
    if (l == 0) {
        #pragma unroll
        for (int j = 0; j < 4; ++j) {
            el[(size_t)v * 4 + j] = pl[j];
            er[(size_t)v * 4 + j] = pr[j];
        }
    }
}

// ---------------- fused edge-softmax + aggregate (one wave per node) ----------------
// CPL = channels per lane (HD/64). Lane owns channels [l*CPL, l*CPL+CPL),
// all in head h = l>>4.
// Pass 1: per 64-edge chunk, lane l loads csrc/el for edge base+l and keeps
//   all-4-head lrelu'd logits; per-head max via wave reduce. Chunk-0 values
//   stay in registers for pass 2.
// Pass 2: lane computes exp(e-m) for all 4 heads of ITS edge (4 exps/edge
//   total), stages {sv, ex[h]} in LDS (padded, bank-clean); softmax denom
//   accumulated per-lane and wave-reduced at the end. The k-loop is then a
//   pure gather: 2 broadcast ds_reads + one z vector load + CPL fma,
//   unroll-8 so 8 independent z gathers are in flight per wave.

template <bool RELU, int CPL>
__global__ __launch_bounds__(256) void agg_kernel(
        const float* __restrict__ z, const float* __restrict__ el,
        const float* __restrict__ er, const int* __restrict__ rowptr,
        const int* __restrict__ csrc, const float* __restrict__ bias,
        float* __restrict__ out, int N) {
    const int HD = CPL * 64;
    __shared__ float exs[4][4][65];  // [wave][head][edge] pad 65: 4 distinct banks on read
    __shared__ int svs[4][64];
    int l = threadIdx.x & 63;
    int w = threadIdx.x >> 6;
    int v = blockIdx.x * 4 + w;
    if (v >= N) return;
    int r0 = rowptr[v], r1 = rowptr[v + 1];
    int c0 = l * CPL;
    int h = l >> 4;
    float b[CPL];
    #pragma unroll
    for (int c = 0; c < CPL; ++c) b[c] = bias[c0 + c];
    float o[CPL];

    if (r0 == r1) {
        #pragma unroll
        for (int c = 0; c < CPL; ++c) o[c] = b[c];  // empty segment: out = bias
    } else {
        float4 er4 = *(const float4*)(er + (size_t)v * 4);

        // ---- pass 1: per-head max; keep chunk-0 logits in registers ----
        float m0 = NEG_BIG, m1 = NEG_BIG, m2 = NEG_BIG, m3 = NEG_BIG;
        int sv0 = 0;
        float4 e40 = make_float4(NEG_BIG, NEG_BIG, NEG_BIG, NEG_BIG);
        for (int base = r0; base < r1; base += 64) {
            int i = base + l;
            float ex_ = NEG_BIG, ey_ = NEG_BIG, ez_ = NEG_BIG, ew_ = NEG_BIG;
            int sv = 0;
            if (i < r1) {
                sv = csrc[i];
                float4 ev = *(const float4*)(el + (size_t)sv * 4);
                ex_ = lrelu(ev.x + er4.x);
                ey_ = lrelu(ev.y + er4.y);
                ez_ = lrelu(ev.z + er4.z);
                ew_ = lrelu(ev.w + er4.w);
            }
            if (base == r0) { sv0 = sv; e40 = make_float4(ex_, ey_, ez_, ew_); }
            m0 = fmaxf(m0, ex_); m1 = fmaxf(m1, ey_);
            m2 = fmaxf(m2, ez_); m3 = fmaxf(m3, ew_);
        }
        #pragma unroll
        for (int off = 1; off < 64; off <<= 1) {
            m0 = fmaxf(m0, __shfl_xor(m0, off));
            m1 = fmaxf(m1, __shfl_xor(m1, off));
            m2 = fmaxf(m2, __shfl_xor(m2, off));
            m3 = fmaxf(m3, __shfl_xor(m3, off));
        }

        // ---- pass 2: stage {sv, ex} per chunk, pure-gather inner loop ----
        float s0 = 0.f, s1 = 0.f, s2 = 0.f, s3 = 0.f;  // per-lane denom partials
        float acc[CPL];
        #pragma unroll
        for (int c = 0; c < CPL; ++c) acc[c] = 0.f;

        for (int base = r0; base < r1; base += 64) {
            int i = base + l;
            int sv; float4 e4;
            if (base == r0) {
                sv = sv0; e4 = e40;  // reused from pass 1 (covers deg<=64 fully)
            } else if (i < r1) {
                sv = csrc[i];
                float4 ev = *(const float4*)(el + (size_t)sv * 4);
                e4 = make_float4(lrelu(ev.x + er4.x), lrelu(ev.y + er4.y),
                                 lrelu(ev.z + er4.z), lrelu(ev.w + er4.w));
            } else {
                sv = 0; e4 = make_float4(NEG_BIG, NEG_BIG, NEG_BIG, NEG_BIG);
            }
            bool valid = (i < r1);
            float exv0 = valid ? __expf(e4.x - m0) : 0.f;
            float exv1 = valid ? __expf(e4.y - m1) : 0.f;
            float exv2 = valid ? __expf(e4.z - m2) : 0.f;
            float exv3 = valid ? __expf(e4.w - m3) : 0.f;
            s0 += exv0; s1 += exv1; s2 += exv2; s3 += exv3;
            svs[w][l] = sv;
            exs[w][0][l] = exv0; exs[w][1][l] = exv1;
            exs[w][2][l] = exv2; exs[w][3][l] = exv3;
            // same-wave producer/consumer: hardware lgkmcnt ordering suffices
            int cnt = min(64, r1 - base);
            #pragma unroll 8
            for (int k = 0; k < cnt; ++k) {
                int sv_k = svs[w][k];          // broadcast ds_read
                float exk = exs[w][h][k];      // broadcast ds_read (4 banks)
                const float* zr = z + (size_t)sv_k * HD + c0;
                if constexpr (CPL == 4) {
                    float4 zz = *(const float4*)zr;
                    acc[0] = fmaf(zz.x, exk, acc[0]);
                    acc[1] = fmaf(zz.y, exk, acc[1]);
                    acc[2] = fmaf(zz.z, exk, acc[2]);
                    acc[3] = fmaf(zz.w, exk, acc[3]);
                } else {
                    float2 zz = *(const float2*)zr;
                    acc[0] = fmaf(zz.x, exk, acc[0]);
                    acc[1] = fmaf(zz.y, exk, acc[1]);
                }
            }
        }
        // wave-reduce denominators, pick this lane's head
        #pragma unroll
        for (int off = 1; off < 64; off <<= 1) {
            s0 += __shfl_xor(s0, off);
            s1 += __shfl_xor(s1, off);
            s2 += __shfl_xor(s2, off);
            s3 += __shfl_xor(s3, off);
        }
        float s = (h == 0) ? s0 : (h == 1) ? s1 : (h == 2) ? s2 : s3;
        float inv = 1.f / s;  // s >= 1 (max edge contributes exp(0)=1)
        #pragma unroll
        for (int c = 0; c < CPL; ++c) o[c] = fmaf(acc[c], inv, b[c]);
    }
    if (RELU) {
        #pragma unroll
        for (int c = 0; c < CPL; ++c) o[c] = fmaxf(o[c], 0.f);
    }
    float* op = out + (size_t)v * HD + c0;
    if constexpr (CPL == 4) {
        *(float4*)op = make_float4(o[0], o[1], o[2], o[3]);
    } else {
        *(float2*)op = make_float2(o[0], o[1]);
    }
}

// ---------------- launch ----------------

extern "C" void kernel_launch(void* const* d_in, const int* in_sizes, int n_in,
                              void* d_out, int out_size, void* d_ws, size_t ws_size,
                              hipStream_t stream) {
    const float* feat = (const float*)d_in[0];
    const int* src = (const int*)d_in[1];
    const int* dst = (const int*)d_in[2];
    const float* W1 = (const float*)d_in[3];
    const float* al1 = (const float*)d_in[4];
    const float* ar1 = (const float*)d_in[5];
    const float* b1 = (const float*)d_in[6];
    const float* W2 = (const float*)d_in[7];
    const float* al2 = (const float*)d_in[8];
    const float* ar2 = (const float*)d_in[9];
    const float* b2 = (const float*)d_in[10];
    const float* W3 = (const float*)d_in[11];
    const float* al3 = (const float*)d_in[12];
    const float* ar3 = (const float*)d_in[13];
    const float* b3 = (const float*)d_in[14];
    const int N = in_sizes[0] / 2;   // feat is [N,2]
    const int E = in_sizes[1];

    // workspace layout
    float* z = (float*)d_ws;                       // [N,256]
    float* hbuf = z + (size_t)N * 256;             // [N,128]
    float* el = hbuf + (size_t)N * 128;            // [N,4]
    float* er = el + (size_t)N * 4;                // [N,4]
    int* csrc = (int*)(er + (size_t)N * 4);        // [E] src values in CSR order
    int* deg = csrc + E;                           // [N]
    int* cursor = deg + N;                         // [N]
    int* rowptr = cursor + N;                      // [N+1]

    // CSR build (per call)
    hipMemsetAsync(deg, 0, sizeof(int) * (size_t)(2 * N), stream);  // deg + cursor
    count_deg_kernel<<<cdiv(E, 256), 256, 0, stream>>>(dst, deg, E);
    scan_kernel<<<1, 1024, 0, stream>>>(deg, rowptr, N);
    fill_csr_kernel<<<cdiv(E, 256), 256, 0, stream>>>(src, dst, rowptr, cursor, csrc, E);

    const int nodeBlocks = cdiv(N, 4);

    // ---- layer 1 (2 -> 128, relu) ----
    z1_kernel<<<cdiv(N * 128, 256), 256, 0, stream>>>(feat, W1, z, N);
    elr128_kernel<<<nodeBlocks, 256, 0, stream>>>(z, al1, ar1, el, er, N);
    agg_kernel<true, 2><<<nodeBlocks, 256, 0, stream>>>(z, el, er, rowptr, csrc, b1, hbuf, N);

    // ---- layer 2 (128 -> 128, relu) ----
    gemm_tile_kernel<<<dim3(cdiv(N, 64), 2), 256, 0, stream>>>(hbuf, W2, z, N, 128);
    elr128_kernel<<<nodeBlocks, 256, 0, stream>>>(z, al2, ar2, el, er, N);
    agg_kernel<true, 2><<<nodeBlocks, 256, 0, stream>>>(z, el, er, rowptr, csrc, b2, hbuf, N);

    // ---- layer 3 (128 -> 256, no relu) ----
    gemm_tile_kernel<<<dim3(cdiv(N, 64), 4), 256, 0, stream>>>(hbuf, W3, z, N, 256);
    elr256_kernel<<<nodeBlocks, 256, 0, stream>>>(z, al3, ar3, el, er, N);
    agg_kernel<false, 4><<<nodeBlocks, 256, 0, stream>>>(z, el, er, rowptr, csrc, b3,
                                                         (float*)d_out, N);
}

// Round 7
// 567.128 us; speedup vs baseline: 1.5384x; 1.1758x over previous
//
#include <hip/hip_runtime.h>
#include <math.h>

// GAT 3-layer inference on MI355X.
// R6: GEMM restructure — 128x64 tile, 8x4 micro-tile, K chunked at 64,
// A staged TRANSPOSED in LDS (pad 132 -> b128-aligned, bank-spread) so the
// inner loop is 3x ds_read_b128 per 32 FMA; LDS 49KB -> 3 blocks/CU.

#define NEG_BIG (-1e38f)

static inline int cdiv(int a, int b) { return (a + b - 1) / b; }

__device__ __forceinline__ float lrelu(float x) { return (x >= 0.f) ? x : 0.2f * x; }

// ---------------- CSR build ----------------

__global__ void count_deg_kernel(const int* __restrict__ dst, int* __restrict__ deg, int E) {
    int i = blockIdx.x * blockDim.x + threadIdx.x;
    if (i < E) atomicAdd(&deg[dst[i]], 1);
}

// single-block exclusive scan over N (~50000) elements
__global__ void scan_kernel(const int* __restrict__ deg, int* __restrict__ rowptr, int n) {
    __shared__ int sums[1024];
    int t = threadIdx.x;
    int chunk = (n + 1023) >> 10;
    int s0 = t * chunk;
    int s1 = min(s0 + chunk, n);
    if (s1 < s0) s1 = s0;
    int tot = 0;
    for (int i = s0; i < s1; ++i) tot += deg[i];
    sums[t] = tot;
    __syncthreads();
    for (int off = 1; off < 1024; off <<= 1) {
        int val = (t >= off) ? sums[t - off] : 0;
        __syncthreads();
        sums[t] += val;
        __syncthreads();
    }
    int excl = sums[t] - tot;
    for (int i = s0; i < s1; ++i) { rowptr[i] = excl; excl += deg[i]; }
    if (t == 1023) rowptr[n] = sums[1023];
}

// store the SRC VALUE in CSR order (no eidx indirection)
__global__ void fill_csr_kernel(const int* __restrict__ src, const int* __restrict__ dst,
                                const int* __restrict__ rowptr,
                                int* __restrict__ cursor, int* __restrict__ csrc, int E) {
    int i = blockIdx.x * blockDim.x + threadIdx.x;
    if (i < E) {
        int d = dst[i];
        int pos = atomicAdd(&cursor[d], 1);
        csrc[rowptr[d] + pos] = src[i];
    }
}

// ---------------- layer 1 projection (Fin=2) ----------------

__global__ void z1_kernel(const float* __restrict__ feat, const float* __restrict__ W1,
                          float* __restrict__ z, int N) {
    int t = blockIdx.x * blockDim.x + threadIdx.x;
    int n = t >> 7;
    if (n >= N) return;
    int j = t & 127;
    float f0 = feat[(size_t)n * 2];
    float f1 = feat[(size_t)n * 2 + 1];
    z[t] = fmaf(f0, W1[j], f1 * W1[128 + j]);
}

// ---------------- GEMM: A[N,128] @ W[128,HDout] -> Z[N,HDout] ----------------
// Tile 128 rows x 64 cols, 256 threads, 8x4 micro-tile, K chunked at 64.
// AT[k][r] transposed A-chunk: pad 132 (528B rows = 16B aligned; bank stride
// 132 mod 32 = 4 spreads k across banks). Inner loop: 2 b128 (A rows,
// broadcast, conflict-free) + 1 b128 (W, 2-way) per 32 FMA.

__global__ __launch_bounds__(256) void gemm_tile_kernel(
        const float* __restrict__ A, const float* __restrict__ W,
        float* __restrict__ Z, int N, int HDout) {
    __shared__ __align__(16) float AT[64][132];
    __shared__ __align__(16) float WS[64][64];
    int n0 = blockIdx.x * 128;
    int c0 = blockIdx.y * 64;
    int t = threadIdx.x;
    int tr = t >> 4;   // 0..15: rows tr*8 .. tr*8+7
    int tc = t & 15;   // cols tc*4 .. tc*4+3

    float acc[8][4] = {};

    for (int kc = 0; kc < 128; kc += 64) {
        // ---- stage A chunk transposed: lane reads float4 along k ----
        {
            int kk = (t & 15) * 4;      // k within chunk
            int rb = t >> 4;            // row base, += 16 per it
            #pragma unroll
            for (int it = 0; it < 8; ++it) {
                int r = rb + 16 * it;
                int n = n0 + r;
                float4 a = (n < N) ? *(const float4*)&A[(size_t)n * 128 + kc + kk]
                                   : make_float4(0.f, 0.f, 0.f, 0.f);
                AT[kk + 0][r] = a.x;
                AT[kk + 1][r] = a.y;
                AT[kk + 2][r] = a.z;
                AT[kk + 3][r] = a.w;
            }
        }
        // ---- stage W chunk: coalesced float4, conflict-free b128 writes ----
        {
            int cc = (t & 15) * 4;
            int kb = t >> 4;
            #pragma unroll
            for (int it = 0; it < 4; ++it) {
                int k = kb + 16 * it;
                *(float4*)&WS[k][cc] =
                    *(const float4*)&W[(size_t)(kc + k) * HDout + c0 + cc];
            }
        }
        __syncthreads();

        #pragma unroll 4
        for (int k = 0; k < 64; ++k) {
            float4 a0 = *(const float4*)&AT[k][tr * 8];
            float4 a1 = *(const float4*)&AT[k][tr * 8 + 4];
            float4 wv = *(const float4*)&WS[k][tc * 4];
            acc[0][0] = fmaf(a0.x, wv.x, acc[0][0]); acc[0][1] = fmaf(a0.x, wv.y, acc[0][1]);
            acc[0][2] = fmaf(a0.x, wv.z, acc[0][2]); acc[0][3] = fmaf(a0.x, wv.w, acc[0][3]);
            acc[1][0] = fmaf(a0.y, wv.x, acc[1][0]); acc[1][1] = fmaf(a0.y, wv.y, acc[1][1]);
            acc[1][2] = fmaf(a0.y, wv.z, acc[1][2]); acc[1][3] = fmaf(a0.y, wv.w, acc[1][3]);
            acc[2][0] = fmaf(a0.z, wv.x, acc[2][0]); acc[2][1] = fmaf(a0.z, wv.y, acc[2][1]);
            acc[2][2] = fmaf(a0.z, wv.z, acc[2][2]); acc[2][3] = fmaf(a0.z, wv.w, acc[2][3]);
            acc[3][0] = fmaf(a0.w, wv.x, acc[3][0]); acc[3][1] = fmaf(a0.w, wv.y, acc[3][1]);
            acc[3][2] = fmaf(a0.w, wv.z, acc[3][2]); acc[3][3] = fmaf(a0.w, wv.w, acc[3][3]);
            acc[4][0] = fmaf(a1.x, wv.x, acc[4][0]); acc[4][1] = fmaf(a1.x, wv.y, acc[4][1]);
            acc[4][2] = fmaf(a1.x, wv.z, acc[4][2]); acc[4][3] = fmaf(a1.x, wv.w, acc[4][3]);
            acc[5][0] = fmaf(a1.y, wv.x, acc[5][0]); acc[5][1] = fmaf(a1.y, wv.y, acc[5][1]);
            acc[5][2] = fmaf(a1.y, wv.z, acc[5][2]); acc[5][3] = fmaf(a1.y, wv.w, acc[5][3]);
            acc[6][0] = fmaf(a1.z, wv.x, acc[6][0]); acc[6][1] = fmaf(a1.z, wv.y, acc[6][1]);
            acc[6][2] = fmaf(a1.z, wv.z, acc[6][2]); acc[6][3] = fmaf(a1.z, wv.w, acc[6][3]);
            acc[7][0] = fmaf(a1.w, wv.x, acc[7][0]); acc[7][1] = fmaf(a1.w, wv.y, acc[7][1]);
            acc[7][2] = fmaf(a1.w, wv.z, acc[7][2]); acc[7][3] = fmaf(a1.w, wv.w, acc[7][3]);
        }
        __syncthreads();
    }

    #pragma unroll
    for (int i = 0; i < 8; ++i) {
        int n = n0 + tr * 8 + i;
        if (n < N) {
            *(float4*)&Z[(size_t)n * HDout + c0 + tc * 4] =
                make_float4(acc[i][0], acc[i][1], acc[i][2], acc[i][3]);
        }
    }
}

// ---------------- el/er: per-node attention logits ----------------

__global__ void elr128_kernel(const float* __restrict__ z, const float* __restrict__ al,
                              const float* __restrict__ ar, float* __restrict__ el,
                              float* __restrict__ er, int N) {
    int l = threadIdx.x & 63;
    int v = blockIdx.x * 4 + (threadIdx.x >> 6);
    if (v >= N) return;
    const float* zr = z + (size_t)v * 128;
    float z0 = zr[l], z1 = zr[l + 64];
    float pl0 = z0 * al[l], pl1 = z1 * al[l + 64];
    float pr0 = z0 * ar[l], pr1 = z1 * ar[l + 64];
    #pragma unroll
    for (int off = 1; off < 32; off <<= 1) {
        pl0 += __shfl_xor(pl0, off);
        pl1 += __shfl_xor(pl1, off);
        pr0 += __shfl_xor(pr0, off);
        pr1 += __shfl_xor(pr1, off);
    }
    if ((l & 31) == 0) {
        int g = l >> 5;  // 0 or 1
        el[(size_t)v * 4 + g] = pl0;
        el[(size_t)v * 4 + 2 + g] = pl1;
        er[(size_t)v * 4 + g] = pr0;
        er[(size_t)v * 4 + 2 + g] = pr1;
    }
}

__global__ void elr256_kernel(const float* __restrict__ z, const float* __restrict__ al,
                              const float* __restrict__ ar, float* __restrict__ el,
                              float* __restrict__ er, int N) {
    int l = threadIdx.x & 63;
    int v = blockIdx.x * 4 + (threadIdx.x >> 6);
    if (v >= N) return;
    const float* zr = z + (size_t)v * 256;
    float pl[4], pr[4];
    #pragma unroll
    for (int j = 0; j < 4; ++j) {
        int c = l + 64 * j;
        float zc = zr[c];
        pl[j] = zc * al[c];
        pr[j] = zc * ar[c];
    }
    #pragma unroll
    for (int off = 1; off < 64; off <<= 1) {
        #pragma unroll
        for (int j = 0; j < 4; ++j) {
            pl[j] += __shfl_xor(pl[j], off);
            pr[j] += __shfl_xor(pr[j], off);
        }
    }
    if (l == 0) {
        #pragma unroll
        for (int j = 0; j < 4; ++j) {
            el[(size_t)v * 4 + j] = pl[j];
            er[(size_t)v * 4 + j] = pr[j];
        }
    }
}

// ---------------- fused edge-softmax + aggregate (one wave per node) ----------------
// (unchanged from R5 — see that round's comments)

template <bool RELU, int CPL>
__global__ __launch_bounds__(256) void agg_kernel(
        const float* __restrict__ z, const float* __restrict__ el,
        const float* __restrict__ er, const int* __restrict__ rowptr,
        const int* __restrict__ csrc, const float* __restrict__ bias,
        float* __restrict__ out, int N) {
    const int HD = CPL * 64;
    __shared__ float exs[4][4][65];  // [wave][head][edge] pad 65
    __shared__ int svs[4][64];
    int l = threadIdx.x & 63;
    int w = threadIdx.x >> 6;
    int v = blockIdx.x * 4 + w;
    if (v >= N) return;
    int r0 = rowptr[v], r1 = rowptr[v + 1];
    int c0 = l * CPL;
    int h = l >> 4;
    float b[CPL];
    #pragma unroll
    for (int c = 0; c < CPL; ++c) b[c] = bias[c0 + c];
    float o[CPL];

    if (r0 == r1) {
        #pragma unroll
        for (int c = 0; c < CPL; ++c) o[c] = b[c];  // empty segment: out = bias
    } else {
        float4 er4 = *(const float4*)(er + (size_t)v * 4);

        // ---- pass 1: per-head max; keep chunk-0 logits in registers ----
        float m0 = NEG_BIG, m1 = NEG_BIG, m2 = NEG_BIG, m3 = NEG_BIG;
        int sv0 = 0;
        float4 e40 = make_float4(NEG_BIG, NEG_BIG, NEG_BIG, NEG_BIG);
        for (int base = r0; base < r1; base += 64) {
            int i = base + l;
            float ex_ = NEG_BIG, ey_ = NEG_BIG, ez_ = NEG_BIG, ew_ = NEG_BIG;
            int sv = 0;
            if (i < r1) {
                sv = csrc[i];
                float4 ev = *(const float4*)(el + (size_t)sv * 4);
                ex_ = lrelu(ev.x + er4.x);
                ey_ = lrelu(ev.y + er4.y);
                ez_ = lrelu(ev.z + er4.z);
                ew_ = lrelu(ev.w + er4.w);
            }
            if (base == r0) { sv0 = sv; e40 = make_float4(ex_, ey_, ez_, ew_); }
            m0 = fmaxf(m0, ex_); m1 = fmaxf(m1, ey_);
            m2 = fmaxf(m2, ez_); m3 = fmaxf(m3, ew_);
        }
        #pragma unroll
        for (int off = 1; off < 64; off <<= 1) {
            m0 = fmaxf(m0, __shfl_xor(m0, off));
            m1 = fmaxf(m1, __shfl_xor(m1, off));
            m2 = fmaxf(m2, __shfl_xor(m2, off));
            m3 = fmaxf(m3, __shfl_xor(m3, off));
        }

        // ---- pass 2: stage {sv, ex} per chunk, pure-gather inner loop ----
        float s0 = 0.f, s1 = 0.f, s2 = 0.f, s3 = 0.f;
        float acc[CPL];
        #pragma unroll
        for (int c = 0; c < CPL; ++c) acc[c] = 0.f;

        for (int base = r0; base < r1; base += 64) {
            int i = base + l;
            int sv; float4 e4;
            if (base == r0) {
                sv = sv0; e4 = e40;  // reused from pass 1 (covers deg<=64 fully)
            } else if (i < r1) {
                sv = csrc[i];
                float4 ev = *(const float4*)(el + (size_t)sv * 4);
                e4 = make_float4(lrelu(ev.x + er4.x), lrelu(ev.y + er4.y),
                                 lrelu(ev.z + er4.z), lrelu(ev.w + er4.w));
            } else {
                sv = 0; e4 = make_float4(NEG_BIG, NEG_BIG, NEG_BIG, NEG_BIG);
            }
            bool valid = (i < r1);
            float exv0 = valid ? __expf(e4.x - m0) : 0.f;
            float exv1 = valid ? __expf(e4.y - m1) : 0.f;
            float exv2 = valid ? __expf(e4.z - m2) : 0.f;
            float exv3 = valid ? __expf(e4.w - m3) : 0.f;
            s0 += exv0; s1 += exv1; s2 += exv2; s3 += exv3;
            svs[w][l] = sv;
            exs[w][0][l] = exv0; exs[w][1][l] = exv1;
            exs[w][2][l] = exv2; exs[w][3][l] = exv3;
            // same-wave producer/consumer: hardware lgkmcnt ordering suffices
            int cnt = min(64, r1 - base);
            #pragma unroll 8
            for (int k = 0; k < cnt; ++k) {
                int sv_k = svs[w][k];          // broadcast ds_read
                float exk = exs[w][h][k];      // broadcast ds_read
                const float* zr = z + (size_t)sv_k * HD + c0;
                if constexpr (CPL == 4) {
                    float4 zz = *(const float4*)zr;
                    acc[0] = fmaf(zz.x, exk, acc[0]);
                    acc[1] = fmaf(zz.y, exk, acc[1]);
                    acc[2] = fmaf(zz.z, exk, acc[2]);
                    acc[3] = fmaf(zz.w, exk, acc[3]);
                } else {
                    float2 zz = *(const float2*)zr;
                    acc[0] = fmaf(zz.x, exk, acc[0]);
                    acc[1] = fmaf(zz.y, exk, acc[1]);
                }
            }
        }
        // wave-reduce denominators, pick this lane's head
        #pragma unroll
        for (int off = 1; off < 64; off <<= 1) {
            s0 += __shfl_xor(s0, off);
            s1 += __shfl_xor(s1, off);
            s2 += __shfl_xor(s2, off);
            s3 += __shfl_xor(s3, off);
        }
        float s = (h == 0) ? s0 : (h == 1) ? s1 : (h == 2) ? s2 : s3;
        float inv = 1.f / s;  // s >= 1 (max edge contributes exp(0)=1)
        #pragma unroll
        for (int c = 0; c < CPL; ++c) o[c] = fmaf(acc[c], inv, b[c]);
    }
    if (RELU) {
        #pragma unroll
        for (int c = 0; c < CPL; ++c) o[c] = fmaxf(o[c], 0.f);
    }
    float* op = out + (size_t)v * HD + c0;
    if constexpr (CPL == 4) {
        *(float4*)op = make_float4(o[0], o[1], o[2], o[3]);
    } else {
        *(float2*)op = make_float2(o[0], o[1]);
    }
}

// ---------------- launch ----------------

extern "C" void kernel_launch(void* const* d_in, const int* in_sizes, int n_in,
                              void* d_out, int out_size, void* d_ws, size_t ws_size,
                              hipStream_t stream) {
    const float* feat = (const float*)d_in[0];
    const int* src = (const int*)d_in[1];
    const int* dst = (const int*)d_in[2];
    const float* W1 = (const float*)d_in[3];
    const float* al1 = (const float*)d_in[4];
    const float* ar1 = (const float*)d_in[5];
    const float* b1 = (const float*)d_in[6];
    const float* W2 = (const float*)d_in[7];
    const float* al2 = (const float*)d_in[8];
    const float* ar2 = (const float*)d_in[9];
    const float* b2 = (const float*)d_in[10];
    const float* W3 = (const float*)d_in[11];
    const float* al3 = (const float*)d_in[12];
    const float* ar3 = (const float*)d_in[13];
    const float* b3 = (const float*)d_in[14];
    const int N = in_sizes[0] / 2;   // feat is [N,2]
    const int E = in_sizes[1];

    // workspace layout
    float* z = (float*)d_ws;                       // [N,256]
    float* hbuf = z + (size_t)N * 256;             // [N,128]
    float* el = hbuf + (size_t)N * 128;            // [N,4]
    float* er = el + (size_t)N * 4;                // [N,4]
    int* csrc = (int*)(er + (size_t)N * 4);        // [E] src values in CSR order
    int* deg = csrc + E;                           // [N]
    int* cursor = deg + N;                         // [N]
    int* rowptr = cursor + N;                      // [N+1]

    // CSR build (per call)
    hipMemsetAsync(deg, 0, sizeof(int) * (size_t)(2 * N), stream);  // deg + cursor
    count_deg_kernel<<<cdiv(E, 256), 256, 0, stream>>>(dst, deg, E);
    scan_kernel<<<1, 1024, 0, stream>>>(deg, rowptr, N);
    fill_csr_kernel<<<cdiv(E, 256), 256, 0, stream>>>(src, dst, rowptr, cursor, csrc, E);

    const int nodeBlocks = cdiv(N, 4);

    // ---- layer 1 (2 -> 128, relu) ----
    z1_kernel<<<cdiv(N * 128, 256), 256, 0, stream>>>(feat, W1, z, N);
    elr128_kernel<<<nodeBlocks, 256, 0, stream>>>(z, al1, ar1, el, er, N);
    agg_kernel<true, 2><<<nodeBlocks, 256, 0, stream>>>(z, el, er, rowptr, csrc, b1, hbuf, N);

    // ---- layer 2 (128 -> 128, relu) ----
    gemm_tile_kernel<<<dim3(cdiv(N, 128), 2), 256, 0, stream>>>(hbuf, W2, z, N, 128);
    elr128_kernel<<<nodeBlocks, 256, 0, stream>>>(z, al2, ar2, el, er, N);
    agg_kernel<true, 2><<<nodeBlocks, 256, 0, stream>>>(z, el, er, rowptr, csrc, b2, hbuf, N);

    // ---- layer 3 (128 -> 256, no relu) ----
    gemm_tile_kernel<<<dim3(cdiv(N, 128), 4), 256, 0, stream>>>(hbuf, W3, z, N, 256);
    elr256_kernel<<<nodeBlocks, 256, 0, stream>>>(z, al3, ar3, el, er, N);
    agg_kernel<false, 4><<<nodeBlocks, 256, 0, stream>>>(z, el, er, rowptr, csrc, b3,
                                                         (float*)d_out, N);
}

// Round 8
// 559.483 us; speedup vs baseline: 1.5594x; 1.0137x over previous
//
#include <hip/hip_runtime.h>
#include <math.h>

// GAT 3-layer inference on MI355X.
// R7: agg restructure — one 16-lane group per node (HD=128) / 32-lane group
// (HD=256), so a wave processes 4 (2) nodes concurrently: full-width pass-1
// logit loads, 4 (2) independent z-gather streams, 4x (2x) fewer serial
// k-iterations. 8 channels/lane in both configs (2x float4 per edge).

#define NEG_BIG (-1e38f)

static inline int cdiv(int a, int b) { return (a + b - 1) / b; }

__device__ __forceinline__ float lrelu(float x) { return (x >= 0.f) ? x : 0.2f * x; }

// ---------------- CSR build ----------------

__global__ void count_deg_kernel(const int* __restrict__ dst, int* __restrict__ deg, int E) {
    int i = blockIdx.x * blockDim.x + threadIdx.x;
    if (i < E) atomicAdd(&deg[dst[i]], 1);
}

// single-block exclusive scan over N (~50000) elements
__global__ void scan_kernel(const int* __restrict__ deg, int* __restrict__ rowptr, int n) {
    __shared__ int sums[1024];
    int t = threadIdx.x;
    int chunk = (n + 1023) >> 10;
    int s0 = t * chunk;
    int s1 = min(s0 + chunk, n);
    if (s1 < s0) s1 = s0;
    int tot = 0;
    for (int i = s0; i < s1; ++i) tot += deg[i];
    sums[t] = tot;
    __syncthreads();
    for (int off = 1; off < 1024; off <<= 1) {
        int val = (t >= off) ? sums[t - off] : 0;
        __syncthreads();
        sums[t] += val;
        __syncthreads();
    }
    int excl = sums[t] - tot;
    for (int i = s0; i < s1; ++i) { rowptr[i] = excl; excl += deg[i]; }
    if (t == 1023) rowptr[n] = sums[1023];
}

// store the SRC VALUE in CSR order (no eidx indirection)
__global__ void fill_csr_kernel(const int* __restrict__ src, const int* __restrict__ dst,
                                const int* __restrict__ rowptr,
                                int* __restrict__ cursor, int* __restrict__ csrc, int E) {
    int i = blockIdx.x * blockDim.x + threadIdx.x;
    if (i < E) {
        int d = dst[i];
        int pos = atomicAdd(&cursor[d], 1);
        csrc[rowptr[d] + pos] = src[i];
    }
}

// ---------------- layer 1 projection (Fin=2) ----------------

__global__ void z1_kernel(const float* __restrict__ feat, const float* __restrict__ W1,
                          float* __restrict__ z, int N) {
    int t = blockIdx.x * blockDim.x + threadIdx.x;
    int n = t >> 7;
    if (n >= N) return;
    int j = t & 127;
    float f0 = feat[(size_t)n * 2];
    float f1 = feat[(size_t)n * 2 + 1];
    z[t] = fmaf(f0, W1[j], f1 * W1[128 + j]);
}

// ---------------- GEMM: A[N,128] @ W[128,HDout] -> Z[N,HDout] ----------------
// (unchanged from R6: 128x64 tile, 8x4 micro-tile, K chunked at 64,
// A transposed in LDS pad 132, W pad-free; 49KB LDS -> 3 blocks/CU.)

__global__ __launch_bounds__(256) void gemm_tile_kernel(
        const float* __restrict__ A, const float* __restrict__ W,
        float* __restrict__ Z, int N, int HDout) {
    __shared__ __align__(16) float AT[64][132];
    __shared__ __align__(16) float WS[64][64];
    int n0 = blockIdx.x * 128;
    int c0 = blockIdx.y * 64;
    int t = threadIdx.x;
    int tr = t >> 4;
    int tc = t & 15;

    float acc[8][4] = {};

    for (int kc = 0; kc < 128; kc += 64) {
        {
            int kk = (t & 15) * 4;
            int rb = t >> 4;
            #pragma unroll
            for (int it = 0; it < 8; ++it) {
                int r = rb + 16 * it;
                int n = n0 + r;
                float4 a = (n < N) ? *(const float4*)&A[(size_t)n * 128 + kc + kk]
                                   : make_float4(0.f, 0.f, 0.f, 0.f);
                AT[kk + 0][r] = a.x;
                AT[kk + 1][r] = a.y;
                AT[kk + 2][r] = a.z;
                AT[kk + 3][r] = a.w;
            }
        }
        {
            int cc = (t & 15) * 4;
            int kb = t >> 4;
            #pragma unroll
            for (int it = 0; it < 4; ++it) {
                int k = kb + 16 * it;
                *(float4*)&WS[k][cc] =
                    *(const float4*)&W[(size_t)(kc + k) * HDout + c0 + cc];
            }
        }
        __syncthreads();

        #pragma unroll 4
        for (int k = 0; k < 64; ++k) {
            float4 a0 = *(const float4*)&AT[k][tr * 8];
            float4 a1 = *(const float4*)&AT[k][tr * 8 + 4];
            float4 wv = *(const float4*)&WS[k][tc * 4];
            acc[0][0] = fmaf(a0.x, wv.x, acc[0][0]); acc[0][1] = fmaf(a0.x, wv.y, acc[0][1]);
            acc[0][2] = fmaf(a0.x, wv.z, acc[0][2]); acc[0][3] = fmaf(a0.x, wv.w, acc[0][3]);
            acc[1][0] = fmaf(a0.y, wv.x, acc[1][0]); acc[1][1] = fmaf(a0.y, wv.y, acc[1][1]);
            acc[1][2] = fmaf(a0.y, wv.z, acc[1][2]); acc[1][3] = fmaf(a0.y, wv.w, acc[1][3]);
            acc[2][0] = fmaf(a0.z, wv.x, acc[2][0]); acc[2][1] = fmaf(a0.z, wv.y, acc[2][1]);
            acc[2][2] = fmaf(a0.z, wv.z, acc[2][2]); acc[2][3] = fmaf(a0.z, wv.w, acc[2][3]);
            acc[3][0] = fmaf(a0.w, wv.x, acc[3][0]); acc[3][1] = fmaf(a0.w, wv.y, acc[3][1]);
            acc[3][2] = fmaf(a0.w, wv.z, acc[3][2]); acc[3][3] = fmaf(a0.w, wv.w, acc[3][3]);
            acc[4][0] = fmaf(a1.x, wv.x, acc[4][0]); acc[4][1] = fmaf(a1.x, wv.y, acc[4][1]);
            acc[4][2] = fmaf(a1.x, wv.z, acc[4][2]); acc[4][3] = fmaf(a1.x, wv.w, acc[4][3]);
            acc[5][0] = fmaf(a1.y, wv.x, acc[5][0]); acc[5][1] = fmaf(a1.y, wv.y, acc[5][1]);
            acc[5][2] = fmaf(a1.y, wv.z, acc[5][2]); acc[5][3] = fmaf(a1.y, wv.w, acc[5][3]);
            acc[6][0] = fmaf(a1.z, wv.x, acc[6][0]); acc[6][1] = fmaf(a1.z, wv.y, acc[6][1]);
            acc[6][2] = fmaf(a1.z, wv.z, acc[6][2]); acc[6][3] = fmaf(a1.z, wv.w, acc[6][3]);
            acc[7][0] = fmaf(a1.w, wv.x, acc[7][0]); acc[7][1] = fmaf(a1.w, wv.y, acc[7][1]);
            acc[7][2] = fmaf(a1.w, wv.z, acc[7][2]); acc[7][3] = fmaf(a1.w, wv.w, acc[7][3]);
        }
        __syncthreads();
    }

    #pragma unroll
    for (int i = 0; i < 8; ++i) {
        int n = n0 + tr * 8 + i;
        if (n < N) {
            *(float4*)&Z[(size_t)n * HDout + c0 + tc * 4] =
                make_float4(acc[i][0], acc[i][1], acc[i][2], acc[i][3]);
        }
    }
}

// ---------------- el/er: per-node attention logits ----------------

__global__ void elr128_kernel(const float* __restrict__ z, const float* __restrict__ al,
                              const float* __restrict__ ar, float* __restrict__ el,
                              float* __restrict__ er, int N) {
    int l = threadIdx.x & 63;
    int v = blockIdx.x * 4 + (threadIdx.x >> 6);
    if (v >= N) return;
    const float* zr = z + (size_t)v * 128;
    float z0 = zr[l], z1 = zr[l + 64];
    float pl0 = z0 * al[l], pl1 = z1 * al[l + 64];
    float pr0 = z0 * ar[l], pr1 = z1 * ar[l + 64];
    #pragma unroll
    for (int off = 1; off < 32; off <<= 1) {
        pl0 += __shfl_xor(pl0, off);
        pl1 += __shfl_xor(pl1, off);
        pr0 += __shfl_xor(pr0, off);
        pr1 += __shfl_xor(pr1, off);
    }
    if ((l & 31) == 0) {
        int g = l >> 5;  // 0 or 1
        el[(size_t)v * 4 + g] = pl0;
        el[(size_t)v * 4 + 2 + g] = pl1;
        er[(size_t)v * 4 + g] = pr0;
        er[(size_t)v * 4 + 2 + g] = pr1;
    }
}

__global__ void elr256_kernel(const float* __restrict__ z, const float* __restrict__ al,
                              const float* __restrict__ ar, float* __restrict__ el,
                              float* __restrict__ er, int N) {
    int l = threadIdx.x & 63;
    int v = blockIdx.x * 4 + (threadIdx.x >> 6);
    if (v >= N) return;
    const float* zr = z + (size_t)v * 256;
    float pl[4], pr[4];
    #pragma unroll
    for (int j = 0; j < 4; ++j) {
        int c = l + 64 * j;
        float zc = zr[c];
        pl[j] = zc * al[c];
        pr[j] = zc * ar[c];
    }
    #pragma unroll
    for (int off = 1; off < 64; off <<= 1) {
        #pragma unroll
        for (int j = 0; j < 4; ++j) {
            pl[j] += __shfl_xor(pl[j], off);
            pr[j] += __shfl_xor(pr[j], off);
        }
    }
    if (l == 0) {
        #pragma unroll
        for (int j = 0; j < 4; ++j) {
            el[(size_t)v * 4 + j] = pl[j];
            er[(size_t)v * 4 + j] = pr[j];
        }
    }
}

// ---------------- fused edge-softmax + aggregate (one GROUP per node) ----------------
// GRP lanes per node (16 for HD=128, 32 for HD=256); NV = 64/GRP nodes per
// wave run CONCURRENTLY in the same instructions. Each lane owns 8 channels
// c0 = lg*8 (all in head h = lg/(GRP/4)). Pass 1: lane lg loads edge
// base+lg's csrc/el (full 64-lane width across NV nodes), per-head max via
// width-GRP shfl_xor (group-aligned; masks < GRP stay in-group). Pass 2:
// 4 exps/edge computed once, staged in per-group LDS (pad +1 word: stride
// 17/33 -> conflict-free banks); inner k-loop is a pure gather of 2x float4
// per edge, NV independent streams per wave, unroll 4.

template <bool RELU, int GRP, int HD>
__global__ __launch_bounds__(256) void agg_kernel(
        const float* __restrict__ z, const float* __restrict__ el,
        const float* __restrict__ er, const int* __restrict__ rowptr,
        const int* __restrict__ csrc, const float* __restrict__ bias,
        float* __restrict__ out, int N) {
    constexpr int NV = 64 / GRP;    // nodes per wave
    constexpr int CH = HD / GRP;    // channels per lane (= 8)
    constexpr int HGRP = GRP / 4;   // lanes per head
    static_assert(CH == 8, "config assumes 8 channels per lane");
    __shared__ float exs[4][NV][4][GRP + 1];
    __shared__ int   svs[4][NV][GRP + 1];
    const int l = threadIdx.x & 63;
    const int w = threadIdx.x >> 6;
    const int g = l / GRP;          // node slot within wave
    const int lg = l & (GRP - 1);   // lane within group
    const int v = blockIdx.x * (4 * NV) + w * NV + g;
    if (v >= N) return;             // whole group exits together (v group-uniform)
    const int r0 = rowptr[v], r1 = rowptr[v + 1];
    const int c0 = lg * CH;
    const int h = lg / HGRP;
    float4 b0 = *(const float4*)(bias + c0);
    float4 b1 = *(const float4*)(bias + c0 + 4);
    float4 o0, o1;

    if (r0 == r1) {
        o0 = b0; o1 = b1;  // empty segment: segment_sum = 0, out = bias
    } else {
        float4 er4 = *(const float4*)(er + (size_t)v * 4);

        // ---- pass 1: per-head max; keep chunk-0 logits in registers ----
        float m0 = NEG_BIG, m1 = NEG_BIG, m2 = NEG_BIG, m3 = NEG_BIG;
        int sv0 = 0;
        float4 e40 = make_float4(NEG_BIG, NEG_BIG, NEG_BIG, NEG_BIG);
        for (int base = r0; base < r1; base += GRP) {
            int i = base + lg;
            float ex_ = NEG_BIG, ey_ = NEG_BIG, ez_ = NEG_BIG, ew_ = NEG_BIG;
            int sv = 0;
            if (i < r1) {
                sv = csrc[i];
                float4 ev = *(const float4*)(el + (size_t)sv * 4);
                ex_ = lrelu(ev.x + er4.x);
                ey_ = lrelu(ev.y + er4.y);
                ez_ = lrelu(ev.z + er4.z);
                ew_ = lrelu(ev.w + er4.w);
            }
            if (base == r0) { sv0 = sv; e40 = make_float4(ex_, ey_, ez_, ew_); }
            m0 = fmaxf(m0, ex_); m1 = fmaxf(m1, ey_);
            m2 = fmaxf(m2, ez_); m3 = fmaxf(m3, ew_);
        }
        #pragma unroll
        for (int off = 1; off < GRP; off <<= 1) {
            m0 = fmaxf(m0, __shfl_xor(m0, off));
            m1 = fmaxf(m1, __shfl_xor(m1, off));
            m2 = fmaxf(m2, __shfl_xor(m2, off));
            m3 = fmaxf(m3, __shfl_xor(m3, off));
        }

        // ---- pass 2: stage {sv, ex} per chunk, pure-gather inner loop ----
        float s0 = 0.f, s1 = 0.f, s2 = 0.f, s3 = 0.f;
        float4 a0 = make_float4(0.f, 0.f, 0.f, 0.f);
        float4 a1 = make_float4(0.f, 0.f, 0.f, 0.f);

        for (int base = r0; base < r1; base += GRP) {
            int i = base + lg;
            int sv; float4 e4;
            if (base == r0) {
                sv = sv0; e4 = e40;  // reused from pass 1 (covers deg<=GRP fully)
            } else if (i < r1) {
                sv = csrc[i];
                float4 ev = *(const float4*)(el + (size_t)sv * 4);
                e4 = make_float4(lrelu(ev.x + er4.x), lrelu(ev.y + er4.y),
                                 lrelu(ev.z + er4.z), lrelu(ev.w + er4.w));
            } else {
                sv = 0; e4 = make_float4(NEG_BIG, NEG_BIG, NEG_BIG, NEG_BIG);
            }
            bool valid = (i < r1);
            float exv0 = valid ? __expf(e4.x - m0) : 0.f;
            float exv1 = valid ? __expf(e4.y - m1) : 0.f;
            float exv2 = valid ? __expf(e4.z - m2) : 0.f;
            float exv3 = valid ? __expf(e4.w - m3) : 0.f;
            s0 += exv0; s1 += exv1; s2 += exv2; s3 += exv3;
            svs[w][g][lg] = sv;
            exs[w][g][0][lg] = exv0; exs[w][g][1][lg] = exv1;
            exs[w][g][2][lg] = exv2; exs[w][g][3][lg] = exv3;
            // same-wave producer/consumer: compiler-inserted lgkmcnt waits order this
            int cnt = min(GRP, r1 - base);
            #pragma unroll 4
            for (int k = 0; k < cnt; ++k) {
                int svk = svs[w][g][k];        // broadcast ds_read within group
                float exk = exs[w][g][h][k];   // broadcast ds_read (bank-spread)
                const float* zr = z + (size_t)svk * HD + c0;
                float4 za = *(const float4*)zr;
                float4 zb = *(const float4*)(zr + 4);
                a0.x = fmaf(za.x, exk, a0.x); a0.y = fmaf(za.y, exk, a0.y);
                a0.z = fmaf(za.z, exk, a0.z); a0.w = fmaf(za.w, exk, a0.w);
                a1.x = fmaf(zb.x, exk, a1.x); a1.y = fmaf(zb.y, exk, a1.y);
                a1.z = fmaf(zb.z, exk, a1.z); a1.w = fmaf(zb.w, exk, a1.w);
            }
        }
        // group-reduce denominators, pick this lane's head
        #pragma unroll
        for (int off = 1; off < GRP; off <<= 1) {
            s0 += __shfl_xor(s0, off);
            s1 += __shfl_xor(s1, off);
            s2 += __shfl_xor(s2, off);
            s3 += __shfl_xor(s3, off);
        }
        float s = (h == 0) ? s0 : (h == 1) ? s1 : (h == 2) ? s2 : s3;
        float inv = 1.f / s;  // s >= 1 (max edge contributes exp(0)=1)
        o0 = make_float4(fmaf(a0.x, inv, b0.x), fmaf(a0.y, inv, b0.y),
                         fmaf(a0.z, inv, b0.z), fmaf(a0.w, inv, b0.w));
        o1 = make_float4(fmaf(a1.x, inv, b1.x), fmaf(a1.y, inv, b1.y),
                         fmaf(a1.z, inv, b1.z), fmaf(a1.w, inv, b1.w));
    }
    if (RELU) {
        o0.x = fmaxf(o0.x, 0.f); o0.y = fmaxf(o0.y, 0.f);
        o0.z = fmaxf(o0.z, 0.f); o0.w = fmaxf(o0.w, 0.f);
        o1.x = fmaxf(o1.x, 0.f); o1.y = fmaxf(o1.y, 0.f);
        o1.z = fmaxf(o1.z, 0.f); o1.w = fmaxf(o1.w, 0.f);
    }
    float* op = out + (size_t)v * HD + c0;
    *(float4*)op = o0;
    *(float4*)(op + 4) = o1;
}

// ---------------- launch ----------------

extern "C" void kernel_launch(void* const* d_in, const int* in_sizes, int n_in,
                              void* d_out, int out_size, void* d_ws, size_t ws_size,
                              hipStream_t stream) {
    const float* feat = (const float*)d_in[0];
    const int* src = (const int*)d_in[1];
    const int* dst = (const int*)d_in[2];
    const float* W1 = (const float*)d_in[3];
    const float* al1 = (const float*)d_in[4];
    const float* ar1 = (const float*)d_in[5];
    const float* b1 = (const float*)d_in[6];
    const float* W2 = (const float*)d_in[7];
    const float* al2 = (const float*)d_in[8];
    const float* ar2 = (const float*)d_in[9];
    const float* b2 = (const float*)d_in[10];
    const float* W3 = (const float*)d_in[11];
    const float* al3 = (const float*)d_in[12];
    const float* ar3 = (const float*)d_in[13];
    const float* b3 = (const float*)d_in[14];
    const int N = in_sizes[0] / 2;   // feat is [N,2]
    const int E = in_sizes[1];

    // workspace layout
    float* z = (float*)d_ws;                       // [N,256]
    float* hbuf = z + (size_t)N * 256;             // [N,128]
    float* el = hbuf + (size_t)N * 128;            // [N,4]
    float* er = el + (size_t)N * 4;                // [N,4]
    int* csrc = (int*)(er + (size_t)N * 4);        // [E] src values in CSR order
    int* deg = csrc + E;                           // [N]
    int* cursor = deg + N;                         // [N]
    int* rowptr = cursor + N;                      // [N+1]

    // CSR build (per call)
    hipMemsetAsync(deg, 0, sizeof(int) * (size_t)(2 * N), stream);  // deg + cursor
    count_deg_kernel<<<cdiv(E, 256), 256, 0, stream>>>(dst, deg, E);
    scan_kernel<<<1, 1024, 0, stream>>>(deg, rowptr, N);
    fill_csr_kernel<<<cdiv(E, 256), 256, 0, stream>>>(src, dst, rowptr, cursor, csrc, E);

    const int nodeBlocks = cdiv(N, 4);

    // ---- layer 1 (2 -> 128, relu) ----
    z1_kernel<<<cdiv(N * 128, 256), 256, 0, stream>>>(feat, W1, z, N);
    elr128_kernel<<<nodeBlocks, 256, 0, stream>>>(z, al1, ar1, el, er, N);
    agg_kernel<true, 16, 128><<<cdiv(N, 16), 256, 0, stream>>>(z, el, er, rowptr, csrc,
                                                               b1, hbuf, N);

    // ---- layer 2 (128 -> 128, relu) ----
    gemm_tile_kernel<<<dim3(cdiv(N, 128), 2), 256, 0, stream>>>(hbuf, W2, z, N, 128);
    elr128_kernel<<<nodeBlocks, 256, 0, stream>>>(z, al2, ar2, el, er, N);
    agg_kernel<true, 16, 128><<<cdiv(N, 16), 256, 0, stream>>>(z, el, er, rowptr, csrc,
                                                               b2, hbuf, N);

    // ---- layer 3 (128 -> 256, no relu) ----
    gemm_tile_kernel<<<dim3(cdiv(N, 128), 4), 256, 0, stream>>>(hbuf, W3, z, N, 256);
    elr256_kernel<<<nodeBlocks, 256, 0, stream>>>(z, al3, ar3, el, er, N);
    agg_kernel<false, 32, 256><<<cdiv(N, 8), 256, 0, stream>>>(z, el, er, rowptr, csrc,
                                                               b3, (float*)d_out, N);
}

// Round 9
// 462.880 us; speedup vs baseline: 1.8849x; 1.2087x over previous
//
#include <hip/hip_runtime.h>
#include <math.h>

// GAT 3-layer inference on MI355X.
// R8: halve the random-gather traffic — fp16 shadow copy zh of each layer's
// z (written in GEMM epilogue / z1), gathered by agg instead of f32 z.
// Logits (el/er), GEMMs, accumulation and outputs remain f32.

#define NEG_BIG (-1e38f)

typedef _Float16 h8 __attribute__((ext_vector_type(8)));
typedef _Float16 h4 __attribute__((ext_vector_type(4)));

static inline int cdiv(int a, int b) { return (a + b - 1) / b; }

__device__ __forceinline__ float lrelu(float x) { return (x >= 0.f) ? x : 0.2f * x; }

// ---------------- CSR build ----------------

__global__ void count_deg_kernel(const int* __restrict__ dst, int* __restrict__ deg, int E) {
    int i = blockIdx.x * blockDim.x + threadIdx.x;
    if (i < E) atomicAdd(&deg[dst[i]], 1);
}

// single-block exclusive scan over N (~50000) elements
__global__ void scan_kernel(const int* __restrict__ deg, int* __restrict__ rowptr, int n) {
    __shared__ int sums[1024];
    int t = threadIdx.x;
    int chunk = (n + 1023) >> 10;
    int s0 = t * chunk;
    int s1 = min(s0 + chunk, n);
    if (s1 < s0) s1 = s0;
    int tot = 0;
    for (int i = s0; i < s1; ++i) tot += deg[i];
    sums[t] = tot;
    __syncthreads();
    for (int off = 1; off < 1024; off <<= 1) {
        int val = (t >= off) ? sums[t - off] : 0;
        __syncthreads();
        sums[t] += val;
        __syncthreads();
    }
    int excl = sums[t] - tot;
    for (int i = s0; i < s1; ++i) { rowptr[i] = excl; excl += deg[i]; }
    if (t == 1023) rowptr[n] = sums[1023];
}

// store the SRC VALUE in CSR order (no eidx indirection)
__global__ void fill_csr_kernel(const int* __restrict__ src, const int* __restrict__ dst,
                                const int* __restrict__ rowptr,
                                int* __restrict__ cursor, int* __restrict__ csrc, int E) {
    int i = blockIdx.x * blockDim.x + threadIdx.x;
    if (i < E) {
        int d = dst[i];
        int pos = atomicAdd(&cursor[d], 1);
        csrc[rowptr[d] + pos] = src[i];
    }
}

// ---------------- layer 1 projection (Fin=2) ----------------

__global__ void z1_kernel(const float* __restrict__ feat, const float* __restrict__ W1,
                          float* __restrict__ z, _Float16* __restrict__ zh, int N) {
    int t = blockIdx.x * blockDim.x + threadIdx.x;
    int n = t >> 7;
    if (n >= N) return;
    int j = t & 127;
    float f0 = feat[(size_t)n * 2];
    float f1 = feat[(size_t)n * 2 + 1];
    float v = fmaf(f0, W1[j], f1 * W1[128 + j]);
    z[t] = v;
    zh[t] = (_Float16)v;
}

// ---------------- GEMM: A[N,128] @ W[128,HDout] -> Z[N,HDout] + fp16 copy ----------------
// (R6 structure: 128x64 tile, 8x4 micro-tile, K chunked at 64,
// A transposed in LDS pad 132; epilogue additionally stores ZH = (fp16)Z.)

__global__ __launch_bounds__(256) void gemm_tile_kernel(
        const float* __restrict__ A, const float* __restrict__ W,
        float* __restrict__ Z, _Float16* __restrict__ ZH, int N, int HDout) {
    __shared__ __align__(16) float AT[64][132];
    __shared__ __align__(16) float WS[64][64];
    int n0 = blockIdx.x * 128;
    int c0 = blockIdx.y * 64;
    int t = threadIdx.x;
    int tr = t >> 4;
    int tc = t & 15;

    float acc[8][4] = {};

    for (int kc = 0; kc < 128; kc += 64) {
        {
            int kk = (t & 15) * 4;
            int rb = t >> 4;
            #pragma unroll
            for (int it = 0; it < 8; ++it) {
                int r = rb + 16 * it;
                int n = n0 + r;
                float4 a = (n < N) ? *(const float4*)&A[(size_t)n * 128 + kc + kk]
                                   : make_float4(0.f, 0.f, 0.f, 0.f);
                AT[kk + 0][r] = a.x;
                AT[kk + 1][r] = a.y;
                AT[kk + 2][r] = a.z;
                AT[kk + 3][r] = a.w;
            }
        }
        {
            int cc = (t & 15) * 4;
            int kb = t >> 4;
            #pragma unroll
            for (int it = 0; it < 4; ++it) {
                int k = kb + 16 * it;
                *(float4*)&WS[k][cc] =
                    *(const float4*)&W[(size_t)(kc + k) * HDout + c0 + cc];
            }
        }
        __syncthreads();

        #pragma unroll 4
        for (int k = 0; k < 64; ++k) {
            float4 a0 = *(const float4*)&AT[k][tr * 8];
            float4 a1 = *(const float4*)&AT[k][tr * 8 + 4];
            float4 wv = *(const float4*)&WS[k][tc * 4];
            acc[0][0] = fmaf(a0.x, wv.x, acc[0][0]); acc[0][1] = fmaf(a0.x, wv.y, acc[0][1]);
            acc[0][2] = fmaf(a0.x, wv.z, acc[0][2]); acc[0][3] = fmaf(a0.x, wv.w, acc[0][3]);
            acc[1][0] = fmaf(a0.y, wv.x, acc[1][0]); acc[1][1] = fmaf(a0.y, wv.y, acc[1][1]);
            acc[1][2] = fmaf(a0.y, wv.z, acc[1][2]); acc[1][3] = fmaf(a0.y, wv.w, acc[1][3]);
            acc[2][0] = fmaf(a0.z, wv.x, acc[2][0]); acc[2][1] = fmaf(a0.z, wv.y, acc[2][1]);
            acc[2][2] = fmaf(a0.z, wv.z, acc[2][2]); acc[2][3] = fmaf(a0.z, wv.w, acc[2][3]);
            acc[3][0] = fmaf(a0.w, wv.x, acc[3][0]); acc[3][1] = fmaf(a0.w, wv.y, acc[3][1]);
            acc[3][2] = fmaf(a0.w, wv.z, acc[3][2]); acc[3][3] = fmaf(a0.w, wv.w, acc[3][3]);
            acc[4][0] = fmaf(a1.x, wv.x, acc[4][0]); acc[4][1] = fmaf(a1.x, wv.y, acc[4][1]);
            acc[4][2] = fmaf(a1.x, wv.z, acc[4][2]); acc[4][3] = fmaf(a1.x, wv.w, acc[4][3]);
            acc[5][0] = fmaf(a1.y, wv.x, acc[5][0]); acc[5][1] = fmaf(a1.y, wv.y, acc[5][1]);
            acc[5][2] = fmaf(a1.y, wv.z, acc[5][2]); acc[5][3] = fmaf(a1.y, wv.w, acc[5][3]);
            acc[6][0] = fmaf(a1.z, wv.x, acc[6][0]); acc[6][1] = fmaf(a1.z, wv.y, acc[6][1]);
            acc[6][2] = fmaf(a1.z, wv.z, acc[6][2]); acc[6][3] = fmaf(a1.z, wv.w, acc[6][3]);
            acc[7][0] = fmaf(a1.w, wv.x, acc[7][0]); acc[7][1] = fmaf(a1.w, wv.y, acc[7][1]);
            acc[7][2] = fmaf(a1.w, wv.z, acc[7][2]); acc[7][3] = fmaf(a1.w, wv.w, acc[7][3]);
        }
        __syncthreads();
    }

    #pragma unroll
    for (int i = 0; i < 8; ++i) {
        int n = n0 + tr * 8 + i;
        if (n < N) {
            *(float4*)&Z[(size_t)n * HDout + c0 + tc * 4] =
                make_float4(acc[i][0], acc[i][1], acc[i][2], acc[i][3]);
            h4 hz = { (_Float16)acc[i][0], (_Float16)acc[i][1],
                      (_Float16)acc[i][2], (_Float16)acc[i][3] };
            *(h4*)&ZH[(size_t)n * HDout + c0 + tc * 4] = hz;
        }
    }
}

// ---------------- el/er: per-node attention logits (from f32 z) ----------------

__global__ void elr128_kernel(const float* __restrict__ z, const float* __restrict__ al,
                              const float* __restrict__ ar, float* __restrict__ el,
                              float* __restrict__ er, int N) {
    int l = threadIdx.x & 63;
    int v = blockIdx.x * 4 + (threadIdx.x >> 6);
    if (v >= N) return;
    const float* zr = z + (size_t)v * 128;
    float z0 = zr[l], z1 = zr[l + 64];
    float pl0 = z0 * al[l], pl1 = z1 * al[l + 64];
    float pr0 = z0 * ar[l], pr1 = z1 * ar[l + 64];
    #pragma unroll
    for (int off = 1; off < 32; off <<= 1) {
        pl0 += __shfl_xor(pl0, off);
        pl1 += __shfl_xor(pl1, off);
        pr0 += __shfl_xor(pr0, off);
        pr1 += __shfl_xor(pr1, off);
    }
    if ((l & 31) == 0) {
        int g = l >> 5;  // 0 or 1
        el[(size_t)v * 4 + g] = pl0;
        el[(size_t)v * 4 + 2 + g] = pl1;
        er[(size_t)v * 4 + g] = pr0;
        er[(size_t)v * 4 + 2 + g] = pr1;
    }
}

__global__ void elr256_kernel(const float* __restrict__ z, const float* __restrict__ al,
                              const float* __restrict__ ar, float* __restrict__ el,
                              float* __restrict__ er, int N) {
    int l = threadIdx.x & 63;
    int v = blockIdx.x * 4 + (threadIdx.x >> 6);
    if (v >= N) return;
    const float* zr = z + (size_t)v * 256;
    float pl[4], pr[4];
    #pragma unroll
    for (int j = 0; j < 4; ++j) {
        int c = l + 64 * j;
        float zc = zr[c];
        pl[j] = zc * al[c];
        pr[j] = zc * ar[c];
    }
    #pragma unroll
    for (int off = 1; off < 64; off <<= 1) {
        #pragma unroll
        for (int j = 0; j < 4; ++j) {
            pl[j] += __shfl_xor(pl[j], off);
            pr[j] += __shfl_xor(pr[j], off);
        }
    }
    if (l == 0) {
        #pragma unroll
        for (int j = 0; j < 4; ++j) {
            el[(size_t)v * 4 + j] = pl[j];
            er[(size_t)v * 4 + j] = pr[j];
        }
    }
}

// ---------------- fused edge-softmax + aggregate (one GROUP per node) ----------------
// R7 structure (GRP lanes/node, NV nodes/wave, 8 ch/lane), but the z gather
// now reads the fp16 shadow zh: ONE 16B load per lane per edge (was 2x16B),
// converted to f32 for accumulation. Logits stay f32.

template <bool RELU, int GRP, int HD>
__global__ __launch_bounds__(256) void agg_kernel(
        const _Float16* __restrict__ zh, const float* __restrict__ el,
        const float* __restrict__ er, const int* __restrict__ rowptr,
        const int* __restrict__ csrc, const float* __restrict__ bias,
        float* __restrict__ out, int N) {
    constexpr int NV = 64 / GRP;    // nodes per wave
    constexpr int CH = HD / GRP;    // channels per lane (= 8)
    constexpr int HGRP = GRP / 4;   // lanes per head
    static_assert(CH == 8, "config assumes 8 channels per lane");
    __shared__ float exs[4][NV][4][GRP + 1];
    __shared__ int   svs[4][NV][GRP + 1];
    const int l = threadIdx.x & 63;
    const int w = threadIdx.x >> 6;
    const int g = l / GRP;          // node slot within wave
    const int lg = l & (GRP - 1);   // lane within group
    const int v = blockIdx.x * (4 * NV) + w * NV + g;
    if (v >= N) return;             // whole group exits together (v group-uniform)
    const int r0 = rowptr[v], r1 = rowptr[v + 1];
    const int c0 = lg * CH;
    const int h = lg / HGRP;
    float4 b0 = *(const float4*)(bias + c0);
    float4 b1 = *(const float4*)(bias + c0 + 4);
    float4 o0, o1;

    if (r0 == r1) {
        o0 = b0; o1 = b1;  // empty segment: segment_sum = 0, out = bias
    } else {
        float4 er4 = *(const float4*)(er + (size_t)v * 4);

        // ---- pass 1: per-head max; keep chunk-0 logits in registers ----
        float m0 = NEG_BIG, m1 = NEG_BIG, m2 = NEG_BIG, m3 = NEG_BIG;
        int sv0 = 0;
        float4 e40 = make_float4(NEG_BIG, NEG_BIG, NEG_BIG, NEG_BIG);
        for (int base = r0; base < r1; base += GRP) {
            int i = base + lg;
            float ex_ = NEG_BIG, ey_ = NEG_BIG, ez_ = NEG_BIG, ew_ = NEG_BIG;
            int sv = 0;
            if (i < r1) {
                sv = csrc[i];
                float4 ev = *(const float4*)(el + (size_t)sv * 4);
                ex_ = lrelu(ev.x + er4.x);
                ey_ = lrelu(ev.y + er4.y);
                ez_ = lrelu(ev.z + er4.z);
                ew_ = lrelu(ev.w + er4.w);
            }
            if (base == r0) { sv0 = sv; e40 = make_float4(ex_, ey_, ez_, ew_); }
            m0 = fmaxf(m0, ex_); m1 = fmaxf(m1, ey_);
            m2 = fmaxf(m2, ez_); m3 = fmaxf(m3, ew_);
        }
        #pragma unroll
        for (int off = 1; off < GRP; off <<= 1) {
            m0 = fmaxf(m0, __shfl_xor(m0, off));
            m1 = fmaxf(m1, __shfl_xor(m1, off));
            m2 = fmaxf(m2, __shfl_xor(m2, off));
            m3 = fmaxf(m3, __shfl_xor(m3, off));
        }

        // ---- pass 2: stage {sv, ex} per chunk, pure-gather inner loop ----
        float s0 = 0.f, s1 = 0.f, s2 = 0.f, s3 = 0.f;
        float4 a0 = make_float4(0.f, 0.f, 0.f, 0.f);
        float4 a1 = make_float4(0.f, 0.f, 0.f, 0.f);

        for (int base = r0; base < r1; base += GRP) {
            int i = base + lg;
            int sv; float4 e4;
            if (base == r0) {
                sv = sv0; e4 = e40;  // reused from pass 1 (covers deg<=GRP fully)
            } else if (i < r1) {
                sv = csrc[i];
                float4 ev = *(const float4*)(el + (size_t)sv * 4);
                e4 = make_float4(lrelu(ev.x + er4.x), lrelu(ev.y + er4.y),
                                 lrelu(ev.z + er4.z), lrelu(ev.w + er4.w));
            } else {
                sv = 0; e4 = make_float4(NEG_BIG, NEG_BIG, NEG_BIG, NEG_BIG);
            }
            bool valid = (i < r1);
            float exv0 = valid ? __expf(e4.x - m0) : 0.f;
            float exv1 = valid ? __expf(e4.y - m1) : 0.f;
            float exv2 = valid ? __expf(e4.z - m2) : 0.f;
            float exv3 = valid ? __expf(e4.w - m3) : 0.f;
            s0 += exv0; s1 += exv1; s2 += exv2; s3 += exv3;
            svs[w][g][lg] = sv;
            exs[w][g][0][lg] = exv0; exs[w][g][1][lg] = exv1;
            exs[w][g][2][lg] = exv2; exs[w][g][3][lg] = exv3;
            // same-wave producer/consumer: compiler-inserted lgkmcnt waits order this
            int cnt = min(GRP, r1 - base);
            #pragma unroll 4
            for (int k = 0; k < cnt; ++k) {
                int svk = svs[w][g][k];        // broadcast ds_read within group
                float exk = exs[w][g][h][k];   // broadcast ds_read (bank-spread)
                h8 zz = *(const h8*)(zh + (size_t)svk * HD + c0);  // ONE 16B load
                a0.x = fmaf((float)zz[0], exk, a0.x);
                a0.y = fmaf((float)zz[1], exk, a0.y);
                a0.z = fmaf((float)zz[2], exk, a0.z);
                a0.w = fmaf((float)zz[3], exk, a0.w);
                a1.x = fmaf((float)zz[4], exk, a1.x);
                a1.y = fmaf((float)zz[5], exk, a1.y);
                a1.z = fmaf((float)zz[6], exk, a1.z);
                a1.w = fmaf((float)zz[7], exk, a1.w);
            }
        }
        // group-reduce denominators, pick this lane's head
        #pragma unroll
        for (int off = 1; off < GRP; off <<= 1) {
            s0 += __shfl_xor(s0, off);
            s1 += __shfl_xor(s1, off);
            s2 += __shfl_xor(s2, off);
            s3 += __shfl_xor(s3, off);
        }
        float s = (h == 0) ? s0 : (h == 1) ? s1 : (h == 2) ? s2 : s3;
        float inv = 1.f / s;  // s >= 1 (max edge contributes exp(0)=1)
        o0 = make_float4(fmaf(a0.x, inv, b0.x), fmaf(a0.y, inv, b0.y),
                         fmaf(a0.z, inv, b0.z), fmaf(a0.w, inv, b0.w));
        o1 = make_float4(fmaf(a1.x, inv, b1.x), fmaf(a1.y, inv, b1.y),
                         fmaf(a1.z, inv, b1.z), fmaf(a1.w, inv, b1.w));
    }
    if (RELU) {
        o0.x = fmaxf(o0.x, 0.f); o0.y = fmaxf(o0.y, 0.f);
        o0.z = fmaxf(o0.z, 0.f); o0.w = fmaxf(o0.w, 0.f);
        o1.x = fmaxf(o1.x, 0.f); o1.y = fmaxf(o1.y, 0.f);
        o1.z = fmaxf(o1.z, 0.f); o1.w = fmaxf(o1.w, 0.f);
    }
    float* op = out + (size_t)v * HD + c0;
    *(float4*)op = o0;
    *(float4*)(op + 4) = o1;
}

// ---------------- launch ----------------

extern "C" void kernel_launch(void* const* d_in, const int* in_sizes, int n_in,
                              void* d_out, int out_size, void* d_ws, size_t ws_size,
                              hipStream_t stream) {
    const float* feat = (const float*)d_in[0];
    const int* src = (const int*)d_in[1];
    const int* dst = (const int*)d_in[2];
    const float* W1 = (const float*)d_in[3];
    const float* al1 = (const float*)d_in[4];
    const float* ar1 = (const float*)d_in[5];
    const float* b1 = (const float*)d_in[6];
    const float* W2 = (const float*)d_in[7];
    const float* al2 = (const float*)d_in[8];
    const float* ar2 = (const float*)d_in[9];
    const float* b2 = (const float*)d_in[10];
    const float* W3 = (const float*)d_in[11];
    const float* al3 = (const float*)d_in[12];
    const float* ar3 = (const float*)d_in[13];
    const float* b3 = (const float*)d_in[14];
    const int N = in_sizes[0] / 2;   // feat is [N,2]
    const int E = in_sizes[1];

    // workspace layout
    float* z = (float*)d_ws;                        // [N,256] f32
    float* hbuf = z + (size_t)N * 256;              // [N,128] f32
    float* el = hbuf + (size_t)N * 128;             // [N,4]
    float* er = el + (size_t)N * 4;                 // [N,4]
    _Float16* zh = (_Float16*)(er + (size_t)N * 4); // [N,256] fp16 shadow (16B-aligned)
    int* csrc = (int*)(zh + (size_t)N * 256);       // [E] src values in CSR order
    int* deg = csrc + E;                            // [N]
    int* cursor = deg + N;                          // [N]
    int* rowptr = cursor + N;                       // [N+1]

    // CSR build (per call)
    hipMemsetAsync(deg, 0, sizeof(int) * (size_t)(2 * N), stream);  // deg + cursor
    count_deg_kernel<<<cdiv(E, 256), 256, 0, stream>>>(dst, deg, E);
    scan_kernel<<<1, 1024, 0, stream>>>(deg, rowptr, N);
    fill_csr_kernel<<<cdiv(E, 256), 256, 0, stream>>>(src, dst, rowptr, cursor, csrc, E);

    const int nodeBlocks = cdiv(N, 4);

    // ---- layer 1 (2 -> 128, relu) ----
    z1_kernel<<<cdiv(N * 128, 256), 256, 0, stream>>>(feat, W1, z, zh, N);
    elr128_kernel<<<nodeBlocks, 256, 0, stream>>>(z, al1, ar1, el, er, N);
    agg_kernel<true, 16, 128><<<cdiv(N, 16), 256, 0, stream>>>(zh, el, er, rowptr, csrc,
                                                               b1, hbuf, N);

    // ---- layer 2 (128 -> 128, relu) ----
    gemm_tile_kernel<<<dim3(cdiv(N, 128), 2), 256, 0, stream>>>(hbuf, W2, z, zh, N, 128);
    elr128_kernel<<<nodeBlocks, 256, 0, stream>>>(z, al2, ar2, el, er, N);
    agg_kernel<true, 16, 128><<<cdiv(N, 16), 256, 0, stream>>>(zh, el, er, rowptr, csrc,
                                                               b2, hbuf, N);

    // ---- layer 3 (128 -> 256, no relu) ----
    gemm_tile_kernel<<<dim3(cdiv(N, 128), 4), 256, 0, stream>>>(hbuf, W3, z, zh, N, 256);
    elr256_kernel<<<nodeBlocks, 256, 0, stream>>>(z, al3, ar3, el, er, N);
    agg_kernel<false, 32, 256><<<cdiv(N, 8), 256, 0, stream>>>(zh, el, er, rowptr, csrc,
                                                               b3, (float*)d_out, N);
}

// Round 10
// 394.032 us; speedup vs baseline: 2.2142x; 1.1747x over previous
//
#include <hip/hip_runtime.h>
#include <math.h>

// GAT 3-layer inference on MI355X.
// R9: replace the 78µs single-block scan with a hierarchical 3-kernel scan
// (coalesced, shfl_up wave scans). Everything else unchanged from R8
// (fp16 shadow gather, group-per-node agg, transposed-LDS GEMM).

#define NEG_BIG (-1e38f)

typedef _Float16 h8 __attribute__((ext_vector_type(8)));
typedef _Float16 h4 __attribute__((ext_vector_type(4)));

static inline int cdiv(int a, int b) { return (a + b - 1) / b; }

__device__ __forceinline__ float lrelu(float x) { return (x >= 0.f) ? x : 0.2f * x; }

// ---------------- CSR build ----------------

__global__ void count_deg_kernel(const int* __restrict__ dst, int* __restrict__ deg, int E) {
    int i = blockIdx.x * blockDim.x + threadIdx.x;
    if (i < E) atomicAdd(&deg[dst[i]], 1);
}

// hierarchical exclusive scan, phase 1: per-block (256 elems) scan + block sum
__global__ __launch_bounds__(256) void scan1_kernel(const int* __restrict__ deg,
                                                    int* __restrict__ rowptr,
                                                    int* __restrict__ bsum, int n) {
    __shared__ int wsum[4];
    int t = threadIdx.x;
    int l = t & 63, wv = t >> 6;
    int i = blockIdx.x * 256 + t;
    int v = (i < n) ? deg[i] : 0;
    int x = v;
    #pragma unroll
    for (int off = 1; off < 64; off <<= 1) {
        int y = __shfl_up(x, off);
        if (l >= off) x += y;
    }
    if (l == 63) wsum[wv] = x;
    __syncthreads();
    int wo = 0;
    #pragma unroll
    for (int j = 0; j < 4; ++j)
        if (j < wv) wo += wsum[j];
    if (i < n) rowptr[i] = wo + x - v;     // block-local exclusive
    if (t == 255) bsum[blockIdx.x] = wo + x;  // block total
}

// phase 2: single block scans the block sums (nb <= 256)
__global__ __launch_bounds__(256) void scan2_kernel(const int* __restrict__ bsum,
                                                    int* __restrict__ boff, int nb) {
    __shared__ int wsum[4];
    int t = threadIdx.x;
    int l = t & 63, wv = t >> 6;
    int v = (t < nb) ? bsum[t] : 0;
    int x = v;
    #pragma unroll
    for (int off = 1; off < 64; off <<= 1) {
        int y = __shfl_up(x, off);
        if (l >= off) x += y;
    }
    if (l == 63) wsum[wv] = x;
    __syncthreads();
    int wo = 0;
    #pragma unroll
    for (int j = 0; j < 4; ++j)
        if (j < wv) wo += wsum[j];
    if (t < nb) boff[t] = wo + x - v;      // exclusive over blocks
}

// phase 3: add block offsets; rowptr[n] = E (all dst in range => total = E)
__global__ __launch_bounds__(256) void scan3_kernel(int* __restrict__ rowptr,
                                                    const int* __restrict__ boff,
                                                    int n, int E) {
    int i = blockIdx.x * 256 + threadIdx.x;
    if (i < n) rowptr[i] += boff[blockIdx.x];
    if (i == 0) rowptr[n] = E;
}

// store the SRC VALUE in CSR order (no eidx indirection)
__global__ void fill_csr_kernel(const int* __restrict__ src, const int* __restrict__ dst,
                                const int* __restrict__ rowptr,
                                int* __restrict__ cursor, int* __restrict__ csrc, int E) {
    int i = blockIdx.x * blockDim.x + threadIdx.x;
    if (i < E) {
        int d = dst[i];
        int pos = atomicAdd(&cursor[d], 1);
        csrc[rowptr[d] + pos] = src[i];
    }
}

// ---------------- layer 1 projection (Fin=2) ----------------

__global__ void z1_kernel(const float* __restrict__ feat, const float* __restrict__ W1,
                          float* __restrict__ z, _Float16* __restrict__ zh, int N) {
    int t = blockIdx.x * blockDim.x + threadIdx.x;
    int n = t >> 7;
    if (n >= N) return;
    int j = t & 127;
    float f0 = feat[(size_t)n * 2];
    float f1 = feat[(size_t)n * 2 + 1];
    float v = fmaf(f0, W1[j], f1 * W1[128 + j]);
    z[t] = v;
    zh[t] = (_Float16)v;
}

// ---------------- GEMM: A[N,128] @ W[128,HDout] -> Z[N,HDout] + fp16 copy ----------------

__global__ __launch_bounds__(256) void gemm_tile_kernel(
        const float* __restrict__ A, const float* __restrict__ W,
        float* __restrict__ Z, _Float16* __restrict__ ZH, int N, int HDout) {
    __shared__ __align__(16) float AT[64][132];
    __shared__ __align__(16) float WS[64][64];
    int n0 = blockIdx.x * 128;
    int c0 = blockIdx.y * 64;
    int t = threadIdx.x;
    int tr = t >> 4;
    int tc = t & 15;

    float acc[8][4] = {};

    for (int kc = 0; kc < 128; kc += 64) {
        {
            int kk = (t & 15) * 4;
            int rb = t >> 4;
            #pragma unroll
            for (int it = 0; it < 8; ++it) {
                int r = rb + 16 * it;
                int n = n0 + r;
                float4 a = (n < N) ? *(const float4*)&A[(size_t)n * 128 + kc + kk]
                                   : make_float4(0.f, 0.f, 0.f, 0.f);
                AT[kk + 0][r] = a.x;
                AT[kk + 1][r] = a.y;
                AT[kk + 2][r] = a.z;
                AT[kk + 3][r] = a.w;
            }
        }
        {
            int cc = (t & 15) * 4;
            int kb = t >> 4;
            #pragma unroll
            for (int it = 0; it < 4; ++it) {
                int k = kb + 16 * it;
                *(float4*)&WS[k][cc] =
                    *(const float4*)&W[(size_t)(kc + k) * HDout + c0 + cc];
            }
        }
        __syncthreads();

        #pragma unroll 4
        for (int k = 0; k < 64; ++k) {
            float4 a0 = *(const float4*)&AT[k][tr * 8];
            float4 a1 = *(const float4*)&AT[k][tr * 8 + 4];
            float4 wv = *(const float4*)&WS[k][tc * 4];
            acc[0][0] = fmaf(a0.x, wv.x, acc[0][0]); acc[0][1] = fmaf(a0.x, wv.y, acc[0][1]);
            acc[0][2] = fmaf(a0.x, wv.z, acc[0][2]); acc[0][3] = fmaf(a0.x, wv.w, acc[0][3]);
            acc[1][0] = fmaf(a0.y, wv.x, acc[1][0]); acc[1][1] = fmaf(a0.y, wv.y, acc[1][1]);
            acc[1][2] = fmaf(a0.y, wv.z, acc[1][2]); acc[1][3] = fmaf(a0.y, wv.w, acc[1][3]);
            acc[2][0] = fmaf(a0.z, wv.x, acc[2][0]); acc[2][1] = fmaf(a0.z, wv.y, acc[2][1]);
            acc[2][2] = fmaf(a0.z, wv.z, acc[2][2]); acc[2][3] = fmaf(a0.z, wv.w, acc[2][3]);
            acc[3][0] = fmaf(a0.w, wv.x, acc[3][0]); acc[3][1] = fmaf(a0.w, wv.y, acc[3][1]);
            acc[3][2] = fmaf(a0.w, wv.z, acc[3][2]); acc[3][3] = fmaf(a0.w, wv.w, acc[3][3]);
            acc[4][0] = fmaf(a1.x, wv.x, acc[4][0]); acc[4][1] = fmaf(a1.x, wv.y, acc[4][1]);
            acc[4][2] = fmaf(a1.x, wv.z, acc[4][2]); acc[4][3] = fmaf(a1.x, wv.w, acc[4][3]);
            acc[5][0] = fmaf(a1.y, wv.x, acc[5][0]); acc[5][1] = fmaf(a1.y, wv.y, acc[5][1]);
            acc[5][2] = fmaf(a1.y, wv.z, acc[5][2]); acc[5][3] = fmaf(a1.y, wv.w, acc[5][3]);
            acc[6][0] = fmaf(a1.z, wv.x, acc[6][0]); acc[6][1] = fmaf(a1.z, wv.y, acc[6][1]);
            acc[6][2] = fmaf(a1.z, wv.z, acc[6][2]); acc[6][3] = fmaf(a1.z, wv.w, acc[6][3]);
            acc[7][0] = fmaf(a1.w, wv.x, acc[7][0]); acc[7][1] = fmaf(a1.w, wv.y, acc[7][1]);
            acc[7][2] = fmaf(a1.w, wv.z, acc[7][2]); acc[7][3] = fmaf(a1.w, wv.w, acc[7][3]);
        }
        __syncthreads();
    }

    #pragma unroll
    for (int i = 0; i < 8; ++i) {
        int n = n0 + tr * 8 + i;
        if (n < N) {
            *(float4*)&Z[(size_t)n * HDout + c0 + tc * 4] =
                make_float4(acc[i][0], acc[i][1], acc[i][2], acc[i][3]);
            h4 hz = { (_Float16)acc[i][0], (_Float16)acc[i][1],
                      (_Float16)acc[i][2], (_Float16)acc[i][3] };
            *(h4*)&ZH[(size_t)n * HDout + c0 + tc * 4] = hz;
        }
    }
}

// ---------------- el/er: per-node attention logits (from f32 z) ----------------

__global__ void elr128_kernel(const float* __restrict__ z, const float* __restrict__ al,
                              const float* __restrict__ ar, float* __restrict__ el,
                              float* __restrict__ er, int N) {
    int l = threadIdx.x & 63;
    int v = blockIdx.x * 4 + (threadIdx.x >> 6);
    if (v >= N) return;
    const float* zr = z + (size_t)v * 128;
    float z0 = zr[l], z1 = zr[l + 64];
    float pl0 = z0 * al[l], pl1 = z1 * al[l + 64];
    float pr0 = z0 * ar[l], pr1 = z1 * ar[l + 64];
    #pragma unroll
    for (int off = 1; off < 32; off <<= 1) {
        pl0 += __shfl_xor(pl0, off);
        pl1 += __shfl_xor(pl1, off);
        pr0 += __shfl_xor(pr0, off);
        pr1 += __shfl_xor(pr1, off);
    }
    if ((l & 31) == 0) {
        int g = l >> 5;  // 0 or 1
        el[(size_t)v * 4 + g] = pl0;
        el[(size_t)v * 4 + 2 + g] = pl1;
        er[(size_t)v * 4 + g] = pr0;
        er[(size_t)v * 4 + 2 + g] = pr1;
    }
}

__global__ void elr256_kernel(const float* __restrict__ z, const float* __restrict__ al,
                              const float* __restrict__ ar, float* __restrict__ el,
                              float* __restrict__ er, int N) {
    int l = threadIdx.x & 63;
    int v = blockIdx.x * 4 + (threadIdx.x >> 6);
    if (v >= N) return;
    const float* zr = z + (size_t)v * 256;
    float pl[4], pr[4];
    #pragma unroll
    for (int j = 0; j < 4; ++j) {
        int c = l + 64 * j;
        float zc = zr[c];
        pl[j] = zc * al[c];
        pr[j] = zc * ar[c];
    }
    #pragma unroll
    for (int off = 1; off < 64; off <<= 1) {
        #pragma unroll
        for (int j = 0; j < 4; ++j) {
            pl[j] += __shfl_xor(pl[j], off);
            pr[j] += __shfl_xor(pr[j], off);
        }
    }
    if (l == 0) {
        #pragma unroll
        for (int j = 0; j < 4; ++j) {
            el[(size_t)v * 4 + j] = pl[j];
            er[(size_t)v * 4 + j] = pr[j];
        }
    }
}

// ---------------- fused edge-softmax + aggregate (one GROUP per node) ----------------
// GRP lanes per node (16 for HD=128, 32 for HD=256); NV = 64/GRP nodes per
// wave. 8 channels/lane; z gather reads the fp16 shadow zh: ONE 16B load per
// lane per edge. Logits stay f32.

template <bool RELU, int GRP, int HD>
__global__ __launch_bounds__(256) void agg_kernel(
        const _Float16* __restrict__ zh, const float* __restrict__ el,
        const float* __restrict__ er, const int* __restrict__ rowptr,
        const int* __restrict__ csrc, const float* __restrict__ bias,
        float* __restrict__ out, int N) {
    constexpr int NV = 64 / GRP;    // nodes per wave
    constexpr int CH = HD / GRP;    // channels per lane (= 8)
    constexpr int HGRP = GRP / 4;   // lanes per head
    static_assert(CH == 8, "config assumes 8 channels per lane");
    __shared__ float exs[4][NV][4][GRP + 1];
    __shared__ int   svs[4][NV][GRP + 1];
    const int l = threadIdx.x & 63;
    const int w = threadIdx.x >> 6;
    const int g = l / GRP;          // node slot within wave
    const int lg = l & (GRP - 1);   // lane within group
    const int v = blockIdx.x * (4 * NV) + w * NV + g;
    if (v >= N) return;             // whole group exits together (v group-uniform)
    const int r0 = rowptr[v], r1 = rowptr[v + 1];
    const int c0 = lg * CH;
    const int h = lg / HGRP;
    float4 b0 = *(const float4*)(bias + c0);
    float4 b1 = *(const float4*)(bias + c0 + 4);
    float4 o0, o1;

    if (r0 == r1) {
        o0 = b0; o1 = b1;  // empty segment: segment_sum = 0, out = bias
    } else {
        float4 er4 = *(const float4*)(er + (size_t)v * 4);

        // ---- pass 1: per-head max; keep chunk-0 logits in registers ----
        float m0 = NEG_BIG, m1 = NEG_BIG, m2 = NEG_BIG, m3 = NEG_BIG;
        int sv0 = 0;
        float4 e40 = make_float4(NEG_BIG, NEG_BIG, NEG_BIG, NEG_BIG);
        for (int base = r0; base < r1; base += GRP) {
            int i = base + lg;
            float ex_ = NEG_BIG, ey_ = NEG_BIG, ez_ = NEG_BIG, ew_ = NEG_BIG;
            int sv = 0;
            if (i < r1) {
                sv = csrc[i];
                float4 ev = *(const float4*)(el + (size_t)sv * 4);
                ex_ = lrelu(ev.x + er4.x);
                ey_ = lrelu(ev.y + er4.y);
                ez_ = lrelu(ev.z + er4.z);
                ew_ = lrelu(ev.w + er4.w);
            }
            if (base == r0) { sv0 = sv; e40 = make_float4(ex_, ey_, ez_, ew_); }
            m0 = fmaxf(m0, ex_); m1 = fmaxf(m1, ey_);
            m2 = fmaxf(m2, ez_); m3 = fmaxf(m3, ew_);
        }
        #pragma unroll
        for (int off = 1; off < GRP; off <<= 1) {
            m0 = fmaxf(m0, __shfl_xor(m0, off));
            m1 = fmaxf(m1, __shfl_xor(m1, off));
            m2 = fmaxf(m2, __shfl_xor(m2, off));
            m3 = fmaxf(m3, __shfl_xor(m3, off));
        }

        // ---- pass 2: stage {sv, ex} per chunk, pure-gather inner loop ----
        float s0 = 0.f, s1 = 0.f, s2 = 0.f, s3 = 0.f;
        float4 a0 = make_float4(0.f, 0.f, 0.f, 0.f);
        float4 a1 = make_float4(0.f, 0.f, 0.f, 0.f);

        for (int base = r0; base < r1; base += GRP) {
            int i = base + lg;
            int sv; float4 e4;
            if (base == r0) {
                sv = sv0; e4 = e40;  // reused from pass 1 (covers deg<=GRP fully)
            } else if (i < r1) {
                sv = csrc[i];
                float4 ev = *(const float4*)(el + (size_t)sv * 4);
                e4 = make_float4(lrelu(ev.x + er4.x), lrelu(ev.y + er4.y),
                                 lrelu(ev.z + er4.z), lrelu(ev.w + er4.w));
            } else {
                sv = 0; e4 = make_float4(NEG_BIG, NEG_BIG, NEG_BIG, NEG_BIG);
            }
            bool valid = (i < r1);
            float exv0 = valid ? __expf(e4.x - m0) : 0.f;
            float exv1 = valid ? __expf(e4.y - m1) : 0.f;
            float exv2 = valid ? __expf(e4.z - m2) : 0.f;
            float exv3 = valid ? __expf(e4.w - m3) : 0.f;
            s0 += exv0; s1 += exv1; s2 += exv2; s3 += exv3;
            svs[w][g][lg] = sv;
            exs[w][g][0][lg] = exv0; exs[w][g][1][lg] = exv1;
            exs[w][g][2][lg] = exv2; exs[w][g][3][lg] = exv3;
            // same-wave producer/consumer: compiler-inserted lgkmcnt waits order this
            int cnt = min(GRP, r1 - base);
            #pragma unroll 4
            for (int k = 0; k < cnt; ++k) {
                int svk = svs[w][g][k];        // broadcast ds_read within group
                float exk = exs[w][g][h][k];   // broadcast ds_read (bank-spread)
                h8 zz = *(const h8*)(zh + (size_t)svk * HD + c0);  // ONE 16B load
                a0.x = fmaf((float)zz[0], exk, a0.x);
                a0.y = fmaf((float)zz[1], exk, a0.y);
                a0.z = fmaf((float)zz[2], exk, a0.z);
                a0.w = fmaf((float)zz[3], exk, a0.w);
                a1.x = fmaf((float)zz[4], exk, a1.x);
                a1.y = fmaf((float)zz[5], exk, a1.y);
                a1.z = fmaf((float)zz[6], exk, a1.z);
                a1.w = fmaf((float)zz[7], exk, a1.w);
            }
        }
        // group-reduce denominators, pick this lane's head
        #pragma unroll
        for (int off = 1; off < GRP; off <<= 1) {
            s0 += __shfl_xor(s0, off);
            s1 += __shfl_xor(s1, off);
            s2 += __shfl_xor(s2, off);
            s3 += __shfl_xor(s3, off);
        }
        float s = (h == 0) ? s0 : (h == 1) ? s1 : (h == 2) ? s2 : s3;
        float inv = 1.f / s;  // s >= 1 (max edge contributes exp(0)=1)
        o0 = make_float4(fmaf(a0.x, inv, b0.x), fmaf(a0.y, inv, b0.y),
                         fmaf(a0.z, inv, b0.z), fmaf(a0.w, inv, b0.w));
        o1 = make_float4(fmaf(a1.x, inv, b1.x), fmaf(a1.y, inv, b1.y),
                         fmaf(a1.z, inv, b1.z), fmaf(a1.w, inv, b1.w));
    }
    if (RELU) {
        o0.x = fmaxf(o0.x, 0.f); o0.y = fmaxf(o0.y, 0.f);
        o0.z = fmaxf(o0.z, 0.f); o0.w = fmaxf(o0.w, 0.f);
        o1.x = fmaxf(o1.x, 0.f); o1.y = fmaxf(o1.y, 0.f);
        o1.z = fmaxf(o1.z, 0.f); o1.w = fmaxf(o1.w, 0.f);
    }
    float* op = out + (size_t)v * HD + c0;
    *(float4*)op = o0;
    *(float4*)(op + 4) = o1;
}

// ---------------- launch ----------------

extern "C" void kernel_launch(void* const* d_in, const int* in_sizes, int n_in,
                              void* d_out, int out_size, void* d_ws, size_t ws_size,
                              hipStream_t stream) {
    const float* feat = (const float*)d_in[0];
    const int* src = (const int*)d_in[1];
    const int* dst = (const int*)d_in[2];
    const float* W1 = (const float*)d_in[3];
    const float* al1 = (const float*)d_in[4];
    const float* ar1 = (const float*)d_in[5];
    const float* b1 = (const float*)d_in[6];
    const float* W2 = (const float*)d_in[7];
    const float* al2 = (const float*)d_in[8];
    const float* ar2 = (const float*)d_in[9];
    const float* b2 = (const float*)d_in[10];
    const float* W3 = (const float*)d_in[11];
    const float* al3 = (const float*)d_in[12];
    const float* ar3 = (const float*)d_in[13];
    const float* b3 = (const float*)d_in[14];
    const int N = in_sizes[0] / 2;   // feat is [N,2]
    const int E = in_sizes[1];

    // workspace layout
    float* z = (float*)d_ws;                        // [N,256] f32
    float* hbuf = z + (size_t)N * 256;              // [N,128] f32
    float* el = hbuf + (size_t)N * 128;             // [N,4]
    float* er = el + (size_t)N * 4;                 // [N,4]
    _Float16* zh = (_Float16*)(er + (size_t)N * 4); // [N,256] fp16 shadow (16B-aligned)
    int* csrc = (int*)(zh + (size_t)N * 256);       // [E] src values in CSR order
    int* deg = csrc + E;                            // [N]
    int* cursor = deg + N;                          // [N]
    int* rowptr = cursor + N;                       // [N+1]
    int* bsum = rowptr + (N + 1);                   // [nb]
    int* boff = bsum + 256;                         // [nb]

    const int nb = cdiv(N, 256);  // scan blocks (196 <= 256)

    // CSR build (per call)
    hipMemsetAsync(deg, 0, sizeof(int) * (size_t)(2 * N), stream);  // deg + cursor
    count_deg_kernel<<<cdiv(E, 256), 256, 0, stream>>>(dst, deg, E);
    scan1_kernel<<<nb, 256, 0, stream>>>(deg, rowptr, bsum, N);
    scan2_kernel<<<1, 256, 0, stream>>>(bsum, boff, nb);
    scan3_kernel<<<nb, 256, 0, stream>>>(rowptr, boff, N, E);
    fill_csr_kernel<<<cdiv(E, 256), 256, 0, stream>>>(src, dst, rowptr, cursor, csrc, E);

    const int nodeBlocks = cdiv(N, 4);

    // ---- layer 1 (2 -> 128, relu) ----
    z1_kernel<<<cdiv(N * 128, 256), 256, 0, stream>>>(feat, W1, z, zh, N);
    elr128_kernel<<<nodeBlocks, 256, 0, stream>>>(z, al1, ar1, el, er, N);
    agg_kernel<true, 16, 128><<<cdiv(N, 16), 256, 0, stream>>>(zh, el, er, rowptr, csrc,
                                                               b1, hbuf, N);

    // ---- layer 2 (128 -> 128, relu) ----
    gemm_tile_kernel<<<dim3(cdiv(N, 128), 2), 256, 0, stream>>>(hbuf, W2, z, zh, N, 128);
    elr128_kernel<<<nodeBlocks, 256, 0, stream>>>(z, al2, ar2, el, er, N);
    agg_kernel<true, 16, 128><<<cdiv(N, 16), 256, 0, stream>>>(zh, el, er, rowptr, csrc,
                                                               b2, hbuf, N);

    // ---- layer 3 (128 -> 256, no relu) ----
    gemm_tile_kernel<<<dim3(cdiv(N, 128), 4), 256, 0, stream>>>(hbuf, W3, z, zh, N, 256);
    elr256_kernel<<<nodeBlocks, 256, 0, stream>>>(z, al3, ar3, el, er, N);
    agg_kernel<false, 32, 256><<<cdiv(N, 8), 256, 0, stream>>>(zh, el, er, rowptr, csrc,
                                                               b3, (float*)d_out, N);
}

// Round 11
// 354.360 us; speedup vs baseline: 2.4621x; 1.1120x over previous
//
#include <hip/hip_runtime.h>
#include <math.h>

// GAT 3-layer inference on MI355X.
// R10: eliminate the f32 z array. GEMM epilogue computes el/er in-register
// (per-row segmented shfl reduction — every y-block covers complete heads,
// so no atomics) and writes only the fp16 shadow zh. Layer-1 z1 fused the
// same way. Kills elr kernels + 100MB reads + 100MB writes.

#define NEG_BIG (-1e38f)

typedef _Float16 h8 __attribute__((ext_vector_type(8)));
typedef _Float16 h4 __attribute__((ext_vector_type(4)));

static inline int cdiv(int a, int b) { return (a + b - 1) / b; }

__device__ __forceinline__ float lrelu(float x) { return (x >= 0.f) ? x : 0.2f * x; }

// ---------------- CSR build ----------------

__global__ void count_deg_kernel(const int* __restrict__ dst, int* __restrict__ deg, int E) {
    int i = blockIdx.x * blockDim.x + threadIdx.x;
    if (i < E) atomicAdd(&deg[dst[i]], 1);
}

// hierarchical exclusive scan, phase 1: per-block (256 elems) scan + block sum
__global__ __launch_bounds__(256) void scan1_kernel(const int* __restrict__ deg,
                                                    int* __restrict__ rowptr,
                                                    int* __restrict__ bsum, int n) {
    __shared__ int wsum[4];
    int t = threadIdx.x;
    int l = t & 63, wv = t >> 6;
    int i = blockIdx.x * 256 + t;
    int v = (i < n) ? deg[i] : 0;
    int x = v;
    #pragma unroll
    for (int off = 1; off < 64; off <<= 1) {
        int y = __shfl_up(x, off);
        if (l >= off) x += y;
    }
    if (l == 63) wsum[wv] = x;
    __syncthreads();
    int wo = 0;
    #pragma unroll
    for (int j = 0; j < 4; ++j)
        if (j < wv) wo += wsum[j];
    if (i < n) rowptr[i] = wo + x - v;     // block-local exclusive
    if (t == 255) bsum[blockIdx.x] = wo + x;  // block total
}

// phase 2: single block scans the block sums (nb <= 256)
__global__ __launch_bounds__(256) void scan2_kernel(const int* __restrict__ bsum,
                                                    int* __restrict__ boff, int nb) {
    __shared__ int wsum[4];
    int t = threadIdx.x;
    int l = t & 63, wv = t >> 6;
    int v = (t < nb) ? bsum[t] : 0;
    int x = v;
    #pragma unroll
    for (int off = 1; off < 64; off <<= 1) {
        int y = __shfl_up(x, off);
        if (l >= off) x += y;
    }
    if (l == 63) wsum[wv] = x;
    __syncthreads();
    int wo = 0;
    #pragma unroll
    for (int j = 0; j < 4; ++j)
        if (j < wv) wo += wsum[j];
    if (t < nb) boff[t] = wo + x - v;      // exclusive over blocks
}

// phase 3: add block offsets; rowptr[n] = E (all dst in range => total = E)
__global__ __launch_bounds__(256) void scan3_kernel(int* __restrict__ rowptr,
                                                    const int* __restrict__ boff,
                                                    int n, int E) {
    int i = blockIdx.x * 256 + threadIdx.x;
    if (i < n) rowptr[i] += boff[blockIdx.x];
    if (i == 0) rowptr[n] = E;
}

// store the SRC VALUE in CSR order (no eidx indirection)
__global__ void fill_csr_kernel(const int* __restrict__ src, const int* __restrict__ dst,
                                const int* __restrict__ rowptr,
                                int* __restrict__ cursor, int* __restrict__ csrc, int E) {
    int i = blockIdx.x * blockDim.x + threadIdx.x;
    if (i < E) {
        int d = dst[i];
        int pos = atomicAdd(&cursor[d], 1);
        csrc[rowptr[d] + pos] = src[i];
    }
}

// ---------------- layer 1: projection (Fin=2) + fused el/er ----------------
// One node per 64-lane wave; lane l owns cols l and l+64. Writes zh (fp16)
// and el/er directly — no f32 z.

__global__ void z1_kernel(const float* __restrict__ feat, const float* __restrict__ W1,
                          const float* __restrict__ al, const float* __restrict__ ar,
                          _Float16* __restrict__ zh, float* __restrict__ el,
                          float* __restrict__ er, int N) {
    int l = threadIdx.x & 63;
    int v = blockIdx.x * 4 + (threadIdx.x >> 6);
    if (v >= N) return;
    float f0 = feat[(size_t)v * 2];
    float f1 = feat[(size_t)v * 2 + 1];
    float z0 = fmaf(f0, W1[l], f1 * W1[128 + l]);
    float z1v = fmaf(f0, W1[l + 64], f1 * W1[128 + l + 64]);
    zh[(size_t)v * 128 + l] = (_Float16)z0;
    zh[(size_t)v * 128 + l + 64] = (_Float16)z1v;
    float pl0 = z0 * al[l], pl1 = z1v * al[l + 64];
    float pr0 = z0 * ar[l], pr1 = z1v * ar[l + 64];
    #pragma unroll
    for (int off = 1; off < 32; off <<= 1) {
        pl0 += __shfl_xor(pl0, off);
        pl1 += __shfl_xor(pl1, off);
        pr0 += __shfl_xor(pr0, off);
        pr1 += __shfl_xor(pr1, off);
    }
    if ((l & 31) == 0) {
        int g = l >> 5;  // 0 or 1
        el[(size_t)v * 4 + g] = pl0;
        el[(size_t)v * 4 + 2 + g] = pl1;
        er[(size_t)v * 4 + g] = pr0;
        er[(size_t)v * 4 + 2 + g] = pr1;
    }
}

// ---------------- GEMM: A[N,128] @ W[128,HDout] -> ZH(fp16) + el/er ----------------
// R6 core (128x64 tile, 8x4 micro-tile, K=64 chunks, transposed-A LDS).
// Epilogue: writes fp16 zh only, plus per-head el/er dots. Each y-block
// covers COMPLETE heads (HDout=128: heads 2y,2y+1; HDout=256: head y), so a
// segmented 16-lane shfl reduction per row yields final values — no atomics.

template <int HDOUT>
__global__ __launch_bounds__(256) void gemm_tile_kernel(
        const float* __restrict__ A, const float* __restrict__ W,
        const float* __restrict__ al, const float* __restrict__ ar,
        _Float16* __restrict__ ZH, float* __restrict__ el, float* __restrict__ er,
        int N) {
    __shared__ __align__(16) float AT[64][132];
    __shared__ __align__(16) float WS[64][64];
    int n0 = blockIdx.x * 128;
    int c0 = blockIdx.y * 64;
    int t = threadIdx.x;
    int tr = t >> 4;
    int tc = t & 15;

    float acc[8][4] = {};

    for (int kc = 0; kc < 128; kc += 64) {
        {
            int kk = (t & 15) * 4;
            int rb = t >> 4;
            #pragma unroll
            for (int it = 0; it < 8; ++it) {
                int r = rb + 16 * it;
                int n = n0 + r;
                float4 a = (n < N) ? *(const float4*)&A[(size_t)n * 128 + kc + kk]
                                   : make_float4(0.f, 0.f, 0.f, 0.f);
                AT[kk + 0][r] = a.x;
                AT[kk + 1][r] = a.y;
                AT[kk + 2][r] = a.z;
                AT[kk + 3][r] = a.w;
            }
        }
        {
            int cc = (t & 15) * 4;
            int kb = t >> 4;
            #pragma unroll
            for (int it = 0; it < 4; ++it) {
                int k = kb + 16 * it;
                *(float4*)&WS[k][cc] =
                    *(const float4*)&W[(size_t)(kc + k) * HDOUT + c0 + cc];
            }
        }
        __syncthreads();

        #pragma unroll 4
        for (int k = 0; k < 64; ++k) {
            float4 a0 = *(const float4*)&AT[k][tr * 8];
            float4 a1 = *(const float4*)&AT[k][tr * 8 + 4];
            float4 wv = *(const float4*)&WS[k][tc * 4];
            acc[0][0] = fmaf(a0.x, wv.x, acc[0][0]); acc[0][1] = fmaf(a0.x, wv.y, acc[0][1]);
            acc[0][2] = fmaf(a0.x, wv.z, acc[0][2]); acc[0][3] = fmaf(a0.x, wv.w, acc[0][3]);
            acc[1][0] = fmaf(a0.y, wv.x, acc[1][0]); acc[1][1] = fmaf(a0.y, wv.y, acc[1][1]);
            acc[1][2] = fmaf(a0.y, wv.z, acc[1][2]); acc[1][3] = fmaf(a0.y, wv.w, acc[1][3]);
            acc[2][0] = fmaf(a0.z, wv.x, acc[2][0]); acc[2][1] = fmaf(a0.z, wv.y, acc[2][1]);
            acc[2][2] = fmaf(a0.z, wv.z, acc[2][2]); acc[2][3] = fmaf(a0.z, wv.w, acc[2][3]);
            acc[3][0] = fmaf(a0.w, wv.x, acc[3][0]); acc[3][1] = fmaf(a0.w, wv.y, acc[3][1]);
            acc[3][2] = fmaf(a0.w, wv.z, acc[3][2]); acc[3][3] = fmaf(a0.w, wv.w, acc[3][3]);
            acc[4][0] = fmaf(a1.x, wv.x, acc[4][0]); acc[4][1] = fmaf(a1.x, wv.y, acc[4][1]);
            acc[4][2] = fmaf(a1.x, wv.z, acc[4][2]); acc[4][3] = fmaf(a1.x, wv.w, acc[4][3]);
            acc[5][0] = fmaf(a1.y, wv.x, acc[5][0]); acc[5][1] = fmaf(a1.y, wv.y, acc[5][1]);
            acc[5][2] = fmaf(a1.y, wv.z, acc[5][2]); acc[5][3] = fmaf(a1.y, wv.w, acc[5][3]);
            acc[6][0] = fmaf(a1.z, wv.x, acc[6][0]); acc[6][1] = fmaf(a1.z, wv.y, acc[6][1]);
            acc[6][2] = fmaf(a1.z, wv.z, acc[6][2]); acc[6][3] = fmaf(a1.z, wv.w, acc[6][3]);
            acc[7][0] = fmaf(a1.w, wv.x, acc[7][0]); acc[7][1] = fmaf(a1.w, wv.y, acc[7][1]);
            acc[7][2] = fmaf(a1.w, wv.z, acc[7][2]); acc[7][3] = fmaf(a1.w, wv.w, acc[7][3]);
        }
        __syncthreads();
    }

    // per-thread al/ar slice (4 cols)
    float4 alv = *(const float4*)&al[c0 + tc * 4];
    float4 arv = *(const float4*)&ar[c0 + tc * 4];

    #pragma unroll
    for (int i = 0; i < 8; ++i) {
        int n = n0 + tr * 8 + i;
        bool ok = (n < N);
        if (ok) {
            h8 hz = { (_Float16)acc[i][0], (_Float16)acc[i][1],
                      (_Float16)acc[i][2], (_Float16)acc[i][3],
                      (_Float16)0.f, (_Float16)0.f, (_Float16)0.f, (_Float16)0.f };
            // store only the low 4 halves (8B)
            h4 hz4 = { hz[0], hz[1], hz[2], hz[3] };
            *(h4*)&ZH[(size_t)n * HDOUT + c0 + tc * 4] = hz4;
        }
        // el/er partial dots (computed unconditionally; only written if ok)
        float pe = acc[i][0] * alv.x + acc[i][1] * alv.y +
                   acc[i][2] * alv.z + acc[i][3] * alv.w;
        float pr = acc[i][0] * arv.x + acc[i][1] * arv.y +
                   acc[i][2] * arv.z + acc[i][3] * arv.w;
        if (HDOUT == 128) {
            // 64 cols = heads 2y (tc 0-7) and 2y+1 (tc 8-15): 8-lane reduce
            #pragma unroll
            for (int off = 1; off < 8; off <<= 1) {
                pe += __shfl_xor(pe, off);
                pr += __shfl_xor(pr, off);
            }
            if (ok && (tc & 7) == 0) {
                int h = 2 * blockIdx.y + (tc >> 3);
                el[(size_t)n * 4 + h] = pe;
                er[(size_t)n * 4 + h] = pr;
            }
        } else {
            // 64 cols = exactly head y: 16-lane reduce
            #pragma unroll
            for (int off = 1; off < 16; off <<= 1) {
                pe += __shfl_xor(pe, off);
                pr += __shfl_xor(pr, off);
            }
            if (ok && tc == 0) {
                int h = blockIdx.y;
                el[(size_t)n * 4 + h] = pe;
                er[(size_t)n * 4 + h] = pr;
            }
        }
    }
}

// ---------------- fused edge-softmax + aggregate (one GROUP per node) ----------------
// GRP lanes per node (16 for HD=128, 32 for HD=256); NV = 64/GRP nodes per
// wave. 8 channels/lane; z gather reads the fp16 shadow zh: ONE 16B load per
// lane per edge. Logits f32.

template <bool RELU, int GRP, int HD>
__global__ __launch_bounds__(256) void agg_kernel(
        const _Float16* __restrict__ zh, const float* __restrict__ el,
        const float* __restrict__ er, const int* __restrict__ rowptr,
        const int* __restrict__ csrc, const float* __restrict__ bias,
        float* __restrict__ out, int N) {
    constexpr int NV = 64 / GRP;    // nodes per wave
    constexpr int CH = HD / GRP;    // channels per lane (= 8)
    constexpr int HGRP = GRP / 4;   // lanes per head
    static_assert(CH == 8, "config assumes 8 channels per lane");
    __shared__ float exs[4][NV][4][GRP + 1];
    __shared__ int   svs[4][NV][GRP + 1];
    const int l = threadIdx.x & 63;
    const int w = threadIdx.x >> 6;
    const int g = l / GRP;          // node slot within wave
    const int lg = l & (GRP - 1);   // lane within group
    const int v = blockIdx.x * (4 * NV) + w * NV + g;
    if (v >= N) return;             // whole group exits together (v group-uniform)
    const int r0 = rowptr[v], r1 = rowptr[v + 1];
    const int c0 = lg * CH;
    const int h = lg / HGRP;
    float4 b0 = *(const float4*)(bias + c0);
    float4 b1 = *(const float4*)(bias + c0 + 4);
    float4 o0, o1;

    if (r0 == r1) {
        o0 = b0; o1 = b1;  // empty segment: segment_sum = 0, out = bias
    } else {
        float4 er4 = *(const float4*)(er + (size_t)v * 4);

        // ---- pass 1: per-head max; keep chunk-0 logits in registers ----
        float m0 = NEG_BIG, m1 = NEG_BIG, m2 = NEG_BIG, m3 = NEG_BIG;
        int sv0 = 0;
        float4 e40 = make_float4(NEG_BIG, NEG_BIG, NEG_BIG, NEG_BIG);
        for (int base = r0; base < r1; base += GRP) {
            int i = base + lg;
            float ex_ = NEG_BIG, ey_ = NEG_BIG, ez_ = NEG_BIG, ew_ = NEG_BIG;
            int sv = 0;
            if (i < r1) {
                sv = csrc[i];
                float4 ev = *(const float4*)(el + (size_t)sv * 4);
                ex_ = lrelu(ev.x + er4.x);
                ey_ = lrelu(ev.y + er4.y);
                ez_ = lrelu(ev.z + er4.z);
                ew_ = lrelu(ev.w + er4.w);
            }
            if (base == r0) { sv0 = sv; e40 = make_float4(ex_, ey_, ez_, ew_); }
            m0 = fmaxf(m0, ex_); m1 = fmaxf(m1, ey_);
            m2 = fmaxf(m2, ez_); m3 = fmaxf(m3, ew_);
        }
        #pragma unroll
        for (int off = 1; off < GRP; off <<= 1) {
            m0 = fmaxf(m0, __shfl_xor(m0, off));
            m1 = fmaxf(m1, __shfl_xor(m1, off));
            m2 = fmaxf(m2, __shfl_xor(m2, off));
            m3 = fmaxf(m3, __shfl_xor(m3, off));
        }

        // ---- pass 2: stage {sv, ex} per chunk, pure-gather inner loop ----
        float s0 = 0.f, s1 = 0.f, s2 = 0.f, s3 = 0.f;
        float4 a0 = make_float4(0.f, 0.f, 0.f, 0.f);
        float4 a1 = make_float4(0.f, 0.f, 0.f, 0.f);

        for (int base = r0; base < r1; base += GRP) {
            int i = base + lg;
            int sv; float4 e4;
            if (base == r0) {
                sv = sv0; e4 = e40;  // reused from pass 1 (covers deg<=GRP fully)
            } else if (i < r1) {
                sv = csrc[i];
                float4 ev = *(const float4*)(el + (size_t)sv * 4);
                e4 = make_float4(lrelu(ev.x + er4.x), lrelu(ev.y + er4.y),
                                 lrelu(ev.z + er4.z), lrelu(ev.w + er4.w));
            } else {
                sv = 0; e4 = make_float4(NEG_BIG, NEG_BIG, NEG_BIG, NEG_BIG);
            }
            bool valid = (i < r1);
            float exv0 = valid ? __expf(e4.x - m0) : 0.f;
            float exv1 = valid ? __expf(e4.y - m1) : 0.f;
            float exv2 = valid ? __expf(e4.z - m2) : 0.f;
            float exv3 = valid ? __expf(e4.w - m3) : 0.f;
            s0 += exv0; s1 += exv1; s2 += exv2; s3 += exv3;
            svs[w][g][lg] = sv;
            exs[w][g][0][lg] = exv0; exs[w][g][1][lg] = exv1;
            exs[w][g][2][lg] = exv2; exs[w][g][3][lg] = exv3;
            // same-wave producer/consumer: compiler-inserted lgkmcnt waits order this
            int cnt = min(GRP, r1 - base);
            #pragma unroll 4
            for (int k = 0; k < cnt; ++k) {
                int svk = svs[w][g][k];        // broadcast ds_read within group
                float exk = exs[w][g][h][k];   // broadcast ds_read (bank-spread)
                h8 zz = *(const h8*)(zh + (size_t)svk * HD + c0);  // ONE 16B load
                a0.x = fmaf((float)zz[0], exk, a0.x);
                a0.y = fmaf((float)zz[1], exk, a0.y);
                a0.z = fmaf((float)zz[2], exk, a0.z);
                a0.w = fmaf((float)zz[3], exk, a0.w);
                a1.x = fmaf((float)zz[4], exk, a1.x);
                a1.y = fmaf((float)zz[5], exk, a1.y);
                a1.z = fmaf((float)zz[6], exk, a1.z);
                a1.w = fmaf((float)zz[7], exk, a1.w);
            }
        }
        // group-reduce denominators, pick this lane's head
        #pragma unroll
        for (int off = 1; off < GRP; off <<= 1) {
            s0 += __shfl_xor(s0, off);
            s1 += __shfl_xor(s1, off);
            s2 += __shfl_xor(s2, off);
            s3 += __shfl_xor(s3, off);
        }
        float s = (h == 0) ? s0 : (h == 1) ? s1 : (h == 2) ? s2 : s3;
        float inv = 1.f / s;  // s >= 1 (max edge contributes exp(0)=1)
        o0 = make_float4(fmaf(a0.x, inv, b0.x), fmaf(a0.y, inv, b0.y),
                         fmaf(a0.z, inv, b0.z), fmaf(a0.w, inv, b0.w));
        o1 = make_float4(fmaf(a1.x, inv, b1.x), fmaf(a1.y, inv, b1.y),
                         fmaf(a1.z, inv, b1.z), fmaf(a1.w, inv, b1.w));
    }
    if (RELU) {
        o0.x = fmaxf(o0.x, 0.f); o0.y = fmaxf(o0.y, 0.f);
        o0.z = fmaxf(o0.z, 0.f); o0.w = fmaxf(o0.w, 0.f);
        o1.x = fmaxf(o1.x, 0.f); o1.y = fmaxf(o1.y, 0.f);
        o1.z = fmaxf(o1.z, 0.f); o1.w = fmaxf(o1.w, 0.f);
    }
    float* op = out + (size_t)v * HD + c0;
    *(float4*)op = o0;
    *(float4*)(op + 4) = o1;
}

// ---------------- launch ----------------

extern "C" void kernel_launch(void* const* d_in, const int* in_sizes, int n_in,
                              void* d_out, int out_size, void* d_ws, size_t ws_size,
                              hipStream_t stream) {
    const float* feat = (const float*)d_in[0];
    const int* src = (const int*)d_in[1];
    const int* dst = (const int*)d_in[2];
    const float* W1 = (const float*)d_in[3];
    const float* al1 = (const float*)d_in[4];
    const float* ar1 = (const float*)d_in[5];
    const float* b1 = (const float*)d_in[6];
    const float* W2 = (const float*)d_in[7];
    const float* al2 = (const float*)d_in[8];
    const float* ar2 = (const float*)d_in[9];
    const float* b2 = (const float*)d_in[10];
    const float* W3 = (const float*)d_in[11];
    const float* al3 = (const float*)d_in[12];
    const float* ar3 = (const float*)d_in[13];
    const float* b3 = (const float*)d_in[14];
    const int N = in_sizes[0] / 2;   // feat is [N,2]
    const int E = in_sizes[1];

    // workspace layout (f32 z eliminated)
    float* hbuf = (float*)d_ws;                      // [N,128] f32 (agg out, gemm in)
    float* el = hbuf + (size_t)N * 128;              // [N,4]
    float* er = el + (size_t)N * 4;                  // [N,4]
    _Float16* zh = (_Float16*)(er + (size_t)N * 4);  // [N,256] fp16 shadow (16B-aligned)
    int* csrc = (int*)(zh + (size_t)N * 256);        // [E] src values in CSR order
    int* deg = csrc + E;                             // [N]
    int* cursor = deg + N;                           // [N]
    int* rowptr = cursor + N;                        // [N+1]
    int* bsum = rowptr + (N + 1);                    // [nb]
    int* boff = bsum + 256;                          // [nb]

    const int nb = cdiv(N, 256);  // scan blocks (196 <= 256)

    // CSR build (per call)
    hipMemsetAsync(deg, 0, sizeof(int) * (size_t)(2 * N), stream);  // deg + cursor
    count_deg_kernel<<<cdiv(E, 256), 256, 0, stream>>>(dst, deg, E);
    scan1_kernel<<<nb, 256, 0, stream>>>(deg, rowptr, bsum, N);
    scan2_kernel<<<1, 256, 0, stream>>>(bsum, boff, nb);
    scan3_kernel<<<nb, 256, 0, stream>>>(rowptr, boff, N, E);
    fill_csr_kernel<<<cdiv(E, 256), 256, 0, stream>>>(src, dst, rowptr, cursor, csrc, E);

    const int nodeBlocks = cdiv(N, 4);

    // ---- layer 1 (2 -> 128, relu) ----
    z1_kernel<<<nodeBlocks, 256, 0, stream>>>(feat, W1, al1, ar1, zh, el, er, N);
    agg_kernel<true, 16, 128><<<cdiv(N, 16), 256, 0, stream>>>(zh, el, er, rowptr, csrc,
                                                               b1, hbuf, N);

    // ---- layer 2 (128 -> 128, relu) ----
    gemm_tile_kernel<128><<<dim3(cdiv(N, 128), 2), 256, 0, stream>>>(
        hbuf, W2, al2, ar2, zh, el, er, N);
    agg_kernel<true, 16, 128><<<cdiv(N, 16), 256, 0, stream>>>(zh, el, er, rowptr, csrc,
                                                               b2, hbuf, N);

    // ---- layer 3 (128 -> 256, no relu) ----
    gemm_tile_kernel<256><<<dim3(cdiv(N, 128), 4), 256, 0, stream>>>(
        hbuf, W3, al3, ar3, zh, el, er, N);
    agg_kernel<false, 32, 256><<<cdiv(N, 8), 256, 0, stream>>>(zh, el, er, rowptr, csrc,
                                                               b3, (float*)d_out, N);
}

// Round 12
// 353.566 us; speedup vs baseline: 2.4676x; 1.0022x over previous
//
#include <hip/hip_runtime.h>
#include <math.h>

// GAT 3-layer inference on MI355X.
// R11: (1) agg pass-2 unroll 4->8 (16 outstanding gathers diagnostic for
// MLP- vs fabric-bound); (2) fp16 inter-layer activations: agg writes fp16
// hbuf, GEMM stages fp16 A -> f32 LDS (halves agg WRITE + gemm A FETCH).

#define NEG_BIG (-1e38f)

typedef _Float16 h8 __attribute__((ext_vector_type(8)));
typedef _Float16 h4 __attribute__((ext_vector_type(4)));

static inline int cdiv(int a, int b) { return (a + b - 1) / b; }

__device__ __forceinline__ float lrelu(float x) { return (x >= 0.f) ? x : 0.2f * x; }

// ---------------- CSR build ----------------

__global__ void count_deg_kernel(const int* __restrict__ dst, int* __restrict__ deg, int E) {
    int i = blockIdx.x * blockDim.x + threadIdx.x;
    if (i < E) atomicAdd(&deg[dst[i]], 1);
}

// hierarchical exclusive scan, phase 1: per-block (256 elems) scan + block sum
__global__ __launch_bounds__(256) void scan1_kernel(const int* __restrict__ deg,
                                                    int* __restrict__ rowptr,
                                                    int* __restrict__ bsum, int n) {
    __shared__ int wsum[4];
    int t = threadIdx.x;
    int l = t & 63, wv = t >> 6;
    int i = blockIdx.x * 256 + t;
    int v = (i < n) ? deg[i] : 0;
    int x = v;
    #pragma unroll
    for (int off = 1; off < 64; off <<= 1) {
        int y = __shfl_up(x, off);
        if (l >= off) x += y;
    }
    if (l == 63) wsum[wv] = x;
    __syncthreads();
    int wo = 0;
    #pragma unroll
    for (int j = 0; j < 4; ++j)
        if (j < wv) wo += wsum[j];
    if (i < n) rowptr[i] = wo + x - v;     // block-local exclusive
    if (t == 255) bsum[blockIdx.x] = wo + x;  // block total
}

// phase 2: single block scans the block sums (nb <= 256)
__global__ __launch_bounds__(256) void scan2_kernel(const int* __restrict__ bsum,
                                                    int* __restrict__ boff, int nb) {
    __shared__ int wsum[4];
    int t = threadIdx.x;
    int l = t & 63, wv = t >> 6;
    int v = (t < nb) ? bsum[t] : 0;
    int x = v;
    #pragma unroll
    for (int off = 1; off < 64; off <<= 1) {
        int y = __shfl_up(x, off);
        if (l >= off) x += y;
    }
    if (l == 63) wsum[wv] = x;
    __syncthreads();
    int wo = 0;
    #pragma unroll
    for (int j = 0; j < 4; ++j)
        if (j < wv) wo += wsum[j];
    if (t < nb) boff[t] = wo + x - v;      // exclusive over blocks
}

// phase 3: add block offsets; rowptr[n] = E (all dst in range => total = E)
__global__ __launch_bounds__(256) void scan3_kernel(int* __restrict__ rowptr,
                                                    const int* __restrict__ boff,
                                                    int n, int E) {
    int i = blockIdx.x * 256 + threadIdx.x;
    if (i < n) rowptr[i] += boff[blockIdx.x];
    if (i == 0) rowptr[n] = E;
}

// store the SRC VALUE in CSR order (no eidx indirection)
__global__ void fill_csr_kernel(const int* __restrict__ src, const int* __restrict__ dst,
                                const int* __restrict__ rowptr,
                                int* __restrict__ cursor, int* __restrict__ csrc, int E) {
    int i = blockIdx.x * blockDim.x + threadIdx.x;
    if (i < E) {
        int d = dst[i];
        int pos = atomicAdd(&cursor[d], 1);
        csrc[rowptr[d] + pos] = src[i];
    }
}

// ---------------- layer 1: projection (Fin=2) + fused el/er ----------------

__global__ void z1_kernel(const float* __restrict__ feat, const float* __restrict__ W1,
                          const float* __restrict__ al, const float* __restrict__ ar,
                          _Float16* __restrict__ zh, float* __restrict__ el,
                          float* __restrict__ er, int N) {
    int l = threadIdx.x & 63;
    int v = blockIdx.x * 4 + (threadIdx.x >> 6);
    if (v >= N) return;
    float f0 = feat[(size_t)v * 2];
    float f1 = feat[(size_t)v * 2 + 1];
    float z0 = fmaf(f0, W1[l], f1 * W1[128 + l]);
    float z1v = fmaf(f0, W1[l + 64], f1 * W1[128 + l + 64]);
    zh[(size_t)v * 128 + l] = (_Float16)z0;
    zh[(size_t)v * 128 + l + 64] = (_Float16)z1v;
    float pl0 = z0 * al[l], pl1 = z1v * al[l + 64];
    float pr0 = z0 * ar[l], pr1 = z1v * ar[l + 64];
    #pragma unroll
    for (int off = 1; off < 32; off <<= 1) {
        pl0 += __shfl_xor(pl0, off);
        pl1 += __shfl_xor(pl1, off);
        pr0 += __shfl_xor(pr0, off);
        pr1 += __shfl_xor(pr1, off);
    }
    if ((l & 31) == 0) {
        int g = l >> 5;  // 0 or 1
        el[(size_t)v * 4 + g] = pl0;
        el[(size_t)v * 4 + 2 + g] = pl1;
        er[(size_t)v * 4 + g] = pr0;
        er[(size_t)v * 4 + 2 + g] = pr1;
    }
}

// ---------------- GEMM: A(fp16)[N,128] @ W(f32)[128,HDout] -> ZH(fp16) + el/er ----------------
// R6 core; A staged from fp16 (h8 loads) into f32 transposed LDS tile.
// Epilogue: fp16 zh + per-head el/er via segmented shfl reduction.

template <int HDOUT>
__global__ __launch_bounds__(256) void gemm_tile_kernel(
        const _Float16* __restrict__ A, const float* __restrict__ W,
        const float* __restrict__ al, const float* __restrict__ ar,
        _Float16* __restrict__ ZH, float* __restrict__ el, float* __restrict__ er,
        int N) {
    __shared__ __align__(16) float AT[64][132];
    __shared__ __align__(16) float WS[64][64];
    int n0 = blockIdx.x * 128;
    int c0 = blockIdx.y * 64;
    int t = threadIdx.x;
    int tr = t >> 4;
    int tc = t & 15;

    float acc[8][4] = {};

    for (int kc = 0; kc < 128; kc += 64) {
        // ---- stage A chunk (fp16 -> f32, transposed) ----
        {
            int kk = (t & 7) * 8;       // k within chunk, 8 halves (16B aligned)
            int rb = t >> 3;            // 0..31, rows rb + 32*it
            #pragma unroll
            for (int it = 0; it < 4; ++it) {
                int r = rb + 32 * it;
                int n = n0 + r;
                h8 a;
                #pragma unroll
                for (int j = 0; j < 8; ++j) a[j] = (_Float16)0.f;
                if (n < N) a = *(const h8*)&A[(size_t)n * 128 + kc + kk];
                #pragma unroll
                for (int j = 0; j < 8; ++j) AT[kk + j][r] = (float)a[j];
            }
        }
        // ---- stage W chunk ----
        {
            int cc = (t & 15) * 4;
            int kb = t >> 4;
            #pragma unroll
            for (int it = 0; it < 4; ++it) {
                int k = kb + 16 * it;
                *(float4*)&WS[k][cc] =
                    *(const float4*)&W[(size_t)(kc + k) * HDOUT + c0 + cc];
            }
        }
        __syncthreads();

        #pragma unroll 4
        for (int k = 0; k < 64; ++k) {
            float4 a0 = *(const float4*)&AT[k][tr * 8];
            float4 a1 = *(const float4*)&AT[k][tr * 8 + 4];
            float4 wv = *(const float4*)&WS[k][tc * 4];
            acc[0][0] = fmaf(a0.x, wv.x, acc[0][0]); acc[0][1] = fmaf(a0.x, wv.y, acc[0][1]);
            acc[0][2] = fmaf(a0.x, wv.z, acc[0][2]); acc[0][3] = fmaf(a0.x, wv.w, acc[0][3]);
            acc[1][0] = fmaf(a0.y, wv.x, acc[1][0]); acc[1][1] = fmaf(a0.y, wv.y, acc[1][1]);
            acc[1][2] = fmaf(a0.y, wv.z, acc[1][2]); acc[1][3] = fmaf(a0.y, wv.w, acc[1][3]);
            acc[2][0] = fmaf(a0.z, wv.x, acc[2][0]); acc[2][1] = fmaf(a0.z, wv.y, acc[2][1]);
            acc[2][2] = fmaf(a0.z, wv.z, acc[2][2]); acc[2][3] = fmaf(a0.z, wv.w, acc[2][3]);
            acc[3][0] = fmaf(a0.w, wv.x, acc[3][0]); acc[3][1] = fmaf(a0.w, wv.y, acc[3][1]);
            acc[3][2] = fmaf(a0.w, wv.z, acc[3][2]); acc[3][3] = fmaf(a0.w, wv.w, acc[3][3]);
            acc[4][0] = fmaf(a1.x, wv.x, acc[4][0]); acc[4][1] = fmaf(a1.x, wv.y, acc[4][1]);
            acc[4][2] = fmaf(a1.x, wv.z, acc[4][2]); acc[4][3] = fmaf(a1.x, wv.w, acc[4][3]);
            acc[5][0] = fmaf(a1.y, wv.x, acc[5][0]); acc[5][1] = fmaf(a1.y, wv.y, acc[5][1]);
            acc[5][2] = fmaf(a1.y, wv.z, acc[5][2]); acc[5][3] = fmaf(a1.y, wv.w, acc[5][3]);
            acc[6][0] = fmaf(a1.z, wv.x, acc[6][0]); acc[6][1] = fmaf(a1.z, wv.y, acc[6][1]);
            acc[6][2] = fmaf(a1.z, wv.z, acc[6][2]); acc[6][3] = fmaf(a1.z, wv.w, acc[6][3]);
            acc[7][0] = fmaf(a1.w, wv.x, acc[7][0]); acc[7][1] = fmaf(a1.w, wv.y, acc[7][1]);
            acc[7][2] = fmaf(a1.w, wv.z, acc[7][2]); acc[7][3] = fmaf(a1.w, wv.w, acc[7][3]);
        }
        __syncthreads();
    }

    // per-thread al/ar slice (4 cols)
    float4 alv = *(const float4*)&al[c0 + tc * 4];
    float4 arv = *(const float4*)&ar[c0 + tc * 4];

    #pragma unroll
    for (int i = 0; i < 8; ++i) {
        int n = n0 + tr * 8 + i;
        bool ok = (n < N);
        if (ok) {
            h4 hz4 = { (_Float16)acc[i][0], (_Float16)acc[i][1],
                       (_Float16)acc[i][2], (_Float16)acc[i][3] };
            *(h4*)&ZH[(size_t)n * HDOUT + c0 + tc * 4] = hz4;
        }
        float pe = acc[i][0] * alv.x + acc[i][1] * alv.y +
                   acc[i][2] * alv.z + acc[i][3] * alv.w;
        float pr = acc[i][0] * arv.x + acc[i][1] * arv.y +
                   acc[i][2] * arv.z + acc[i][3] * arv.w;
        if (HDOUT == 128) {
            #pragma unroll
            for (int off = 1; off < 8; off <<= 1) {
                pe += __shfl_xor(pe, off);
                pr += __shfl_xor(pr, off);
            }
            if (ok && (tc & 7) == 0) {
                int h = 2 * blockIdx.y + (tc >> 3);
                el[(size_t)n * 4 + h] = pe;
                er[(size_t)n * 4 + h] = pr;
            }
        } else {
            #pragma unroll
            for (int off = 1; off < 16; off <<= 1) {
                pe += __shfl_xor(pe, off);
                pr += __shfl_xor(pr, off);
            }
            if (ok && tc == 0) {
                int h = blockIdx.y;
                el[(size_t)n * 4 + h] = pe;
                er[(size_t)n * 4 + h] = pr;
            }
        }
    }
}

// ---------------- fused edge-softmax + aggregate (one GROUP per node) ----------------
// GRP lanes per node; NV = 64/GRP nodes per wave; 8 channels/lane; zh fp16
// gather (one 16B load/lane/edge, unroll 8 -> 8 wave-gathers in flight).
// OUTT = _Float16 (inter-layer) or float (final output).

template <bool RELU, int GRP, int HD, typename OUTT>
__global__ __launch_bounds__(256) void agg_kernel(
        const _Float16* __restrict__ zh, const float* __restrict__ el,
        const float* __restrict__ er, const int* __restrict__ rowptr,
        const int* __restrict__ csrc, const float* __restrict__ bias,
        OUTT* __restrict__ out, int N) {
    constexpr int NV = 64 / GRP;    // nodes per wave
    constexpr int CH = HD / GRP;    // channels per lane (= 8)
    constexpr int HGRP = GRP / 4;   // lanes per head
    static_assert(CH == 8, "config assumes 8 channels per lane");
    __shared__ float exs[4][NV][4][GRP + 1];
    __shared__ int   svs[4][NV][GRP + 1];
    const int l = threadIdx.x & 63;
    const int w = threadIdx.x >> 6;
    const int g = l / GRP;          // node slot within wave
    const int lg = l & (GRP - 1);   // lane within group
    const int v = blockIdx.x * (4 * NV) + w * NV + g;
    if (v >= N) return;             // whole group exits together (v group-uniform)
    const int r0 = rowptr[v], r1 = rowptr[v + 1];
    const int c0 = lg * CH;
    const int h = lg / HGRP;
    float4 b0 = *(const float4*)(bias + c0);
    float4 b1 = *(const float4*)(bias + c0 + 4);
    float4 o0, o1;

    if (r0 == r1) {
        o0 = b0; o1 = b1;  // empty segment: segment_sum = 0, out = bias
    } else {
        float4 er4 = *(const float4*)(er + (size_t)v * 4);

        // ---- pass 1: per-head max; keep chunk-0 logits in registers ----
        float m0 = NEG_BIG, m1 = NEG_BIG, m2 = NEG_BIG, m3 = NEG_BIG;
        int sv0 = 0;
        float4 e40 = make_float4(NEG_BIG, NEG_BIG, NEG_BIG, NEG_BIG);
        for (int base = r0; base < r1; base += GRP) {
            int i = base + lg;
            float ex_ = NEG_BIG, ey_ = NEG_BIG, ez_ = NEG_BIG, ew_ = NEG_BIG;
            int sv = 0;
            if (i < r1) {
                sv = csrc[i];
                float4 ev = *(const float4*)(el + (size_t)sv * 4);
                ex_ = lrelu(ev.x + er4.x);
                ey_ = lrelu(ev.y + er4.y);
                ez_ = lrelu(ev.z + er4.z);
                ew_ = lrelu(ev.w + er4.w);
            }
            if (base == r0) { sv0 = sv; e40 = make_float4(ex_, ey_, ez_, ew_); }
            m0 = fmaxf(m0, ex_); m1 = fmaxf(m1, ey_);
            m2 = fmaxf(m2, ez_); m3 = fmaxf(m3, ew_);
        }
        #pragma unroll
        for (int off = 1; off < GRP; off <<= 1) {
            m0 = fmaxf(m0, __shfl_xor(m0, off));
            m1 = fmaxf(m1, __shfl_xor(m1, off));
            m2 = fmaxf(m2, __shfl_xor(m2, off));
            m3 = fmaxf(m3, __shfl_xor(m3, off));
        }

        // ---- pass 2: stage {sv, ex} per chunk, pure-gather inner loop ----
        float s0 = 0.f, s1 = 0.f, s2 = 0.f, s3 = 0.f;
        float4 a0 = make_float4(0.f, 0.f, 0.f, 0.f);
        float4 a1 = make_float4(0.f, 0.f, 0.f, 0.f);

        for (int base = r0; base < r1; base += GRP) {
            int i = base + lg;
            int sv; float4 e4;
            if (base == r0) {
                sv = sv0; e4 = e40;  // reused from pass 1 (covers deg<=GRP fully)
            } else if (i < r1) {
                sv = csrc[i];
                float4 ev = *(const float4*)(el + (size_t)sv * 4);
                e4 = make_float4(lrelu(ev.x + er4.x), lrelu(ev.y + er4.y),
                                 lrelu(ev.z + er4.z), lrelu(ev.w + er4.w));
            } else {
                sv = 0; e4 = make_float4(NEG_BIG, NEG_BIG, NEG_BIG, NEG_BIG);
            }
            bool valid = (i < r1);
            float exv0 = valid ? __expf(e4.x - m0) : 0.f;
            float exv1 = valid ? __expf(e4.y - m1) : 0.f;
            float exv2 = valid ? __expf(e4.z - m2) : 0.f;
            float exv3 = valid ? __expf(e4.w - m3) : 0.f;
            s0 += exv0; s1 += exv1; s2 += exv2; s3 += exv3;
            svs[w][g][lg] = sv;
            exs[w][g][0][lg] = exv0; exs[w][g][1][lg] = exv1;
            exs[w][g][2][lg] = exv2; exs[w][g][3][lg] = exv3;
            // same-wave producer/consumer: compiler-inserted lgkmcnt waits order this
            int cnt = min(GRP, r1 - base);
            #pragma unroll 8
            for (int k = 0; k < cnt; ++k) {
                int svk = svs[w][g][k];        // broadcast ds_read within group
                float exk = exs[w][g][h][k];   // broadcast ds_read (bank-spread)
                h8 zz = *(const h8*)(zh + (size_t)svk * HD + c0);  // ONE 16B load
                a0.x = fmaf((float)zz[0], exk, a0.x);
                a0.y = fmaf((float)zz[1], exk, a0.y);
                a0.z = fmaf((float)zz[2], exk, a0.z);
                a0.w = fmaf((float)zz[3], exk, a0.w);
                a1.x = fmaf((float)zz[4], exk, a1.x);
                a1.y = fmaf((float)zz[5], exk, a1.y);
                a1.z = fmaf((float)zz[6], exk, a1.z);
                a1.w = fmaf((float)zz[7], exk, a1.w);
            }
        }
        // group-reduce denominators, pick this lane's head
        #pragma unroll
        for (int off = 1; off < GRP; off <<= 1) {
            s0 += __shfl_xor(s0, off);
            s1 += __shfl_xor(s1, off);
            s2 += __shfl_xor(s2, off);
            s3 += __shfl_xor(s3, off);
        }
        float s = (h == 0) ? s0 : (h == 1) ? s1 : (h == 2) ? s2 : s3;
        float inv = 1.f / s;  // s >= 1 (max edge contributes exp(0)=1)
        o0 = make_float4(fmaf(a0.x, inv, b0.x), fmaf(a0.y, inv, b0.y),
                         fmaf(a0.z, inv, b0.z), fmaf(a0.w, inv, b0.w));
        o1 = make_float4(fmaf(a1.x, inv, b1.x), fmaf(a1.y, inv, b1.y),
                         fmaf(a1.z, inv, b1.z), fmaf(a1.w, inv, b1.w));
    }
    if (RELU) {
        o0.x = fmaxf(o0.x, 0.f); o0.y = fmaxf(o0.y, 0.f);
        o0.z = fmaxf(o0.z, 0.f); o0.w = fmaxf(o0.w, 0.f);
        o1.x = fmaxf(o1.x, 0.f); o1.y = fmaxf(o1.y, 0.f);
        o1.z = fmaxf(o1.z, 0.f); o1.w = fmaxf(o1.w, 0.f);
    }
    if constexpr (sizeof(OUTT) == 2) {
        h8 ho;
        ho[0] = (_Float16)o0.x; ho[1] = (_Float16)o0.y;
        ho[2] = (_Float16)o0.z; ho[3] = (_Float16)o0.w;
        ho[4] = (_Float16)o1.x; ho[5] = (_Float16)o1.y;
        ho[6] = (_Float16)o1.z; ho[7] = (_Float16)o1.w;
        *(h8*)((_Float16*)out + (size_t)v * HD + c0) = ho;
    } else {
        float* op = (float*)out + (size_t)v * HD + c0;
        *(float4*)op = o0;
        *(float4*)(op + 4) = o1;
    }
}

// ---------------- launch ----------------

extern "C" void kernel_launch(void* const* d_in, const int* in_sizes, int n_in,
                              void* d_out, int out_size, void* d_ws, size_t ws_size,
                              hipStream_t stream) {
    const float* feat = (const float*)d_in[0];
    const int* src = (const int*)d_in[1];
    const int* dst = (const int*)d_in[2];
    const float* W1 = (const float*)d_in[3];
    const float* al1 = (const float*)d_in[4];
    const float* ar1 = (const float*)d_in[5];
    const float* b1 = (const float*)d_in[6];
    const float* W2 = (const float*)d_in[7];
    const float* al2 = (const float*)d_in[8];
    const float* ar2 = (const float*)d_in[9];
    const float* b2 = (const float*)d_in[10];
    const float* W3 = (const float*)d_in[11];
    const float* al3 = (const float*)d_in[12];
    const float* ar3 = (const float*)d_in[13];
    const float* b3 = (const float*)d_in[14];
    const int N = in_sizes[0] / 2;   // feat is [N,2]
    const int E = in_sizes[1];

    // workspace layout
    _Float16* hbuf = (_Float16*)d_ws;                 // [N,128] fp16 (agg out, gemm in)
    float* el = (float*)(hbuf + (size_t)N * 128);     // [N,4]
    float* er = el + (size_t)N * 4;                   // [N,4]
    _Float16* zh = (_Float16*)(er + (size_t)N * 4);   // [N,256] fp16 shadow
    int* csrc = (int*)(zh + (size_t)N * 256);         // [E] src values in CSR order
    int* deg = csrc + E;                              // [N]
    int* cursor = deg + N;                            // [N]
    int* rowptr = cursor + N;                         // [N+1]
    int* bsum = rowptr + (N + 1);                     // [nb]
    int* boff = bsum + 256;                           // [nb]

    const int nb = cdiv(N, 256);  // scan blocks (196 <= 256)

    // CSR build (per call)
    hipMemsetAsync(deg, 0, sizeof(int) * (size_t)(2 * N), stream);  // deg + cursor
    count_deg_kernel<<<cdiv(E, 256), 256, 0, stream>>>(dst, deg, E);
    scan1_kernel<<<nb, 256, 0, stream>>>(deg, rowptr, bsum, N);
    scan2_kernel<<<1, 256, 0, stream>>>(bsum, boff, nb);
    scan3_kernel<<<nb, 256, 0, stream>>>(rowptr, boff, N, E);
    fill_csr_kernel<<<cdiv(E, 256), 256, 0, stream>>>(src, dst, rowptr, cursor, csrc, E);

    const int nodeBlocks = cdiv(N, 4);

    // ---- layer 1 (2 -> 128, relu) ----
    z1_kernel<<<nodeBlocks, 256, 0, stream>>>(feat, W1, al1, ar1, zh, el, er, N);
    agg_kernel<true, 16, 128, _Float16><<<cdiv(N, 16), 256, 0, stream>>>(
        zh, el, er, rowptr, csrc, b1, hbuf, N);

    // ---- layer 2 (128 -> 128, relu) ----
    gemm_tile_kernel<128><<<dim3(cdiv(N, 128), 2), 256, 0, stream>>>(
        hbuf, W2, al2, ar2, zh, el, er, N);
    agg_kernel<true, 16, 128, _Float16><<<cdiv(N, 16), 256, 0, stream>>>(
        zh, el, er, rowptr, csrc, b2, hbuf, N);

    // ---- layer 3 (128 -> 256, no relu) ----
    gemm_tile_kernel<256><<<dim3(cdiv(N, 128), 4), 256, 0, stream>>>(
        hbuf, W3, al3, ar3, zh, el, er, N);
    agg_kernel<false, 32, 256, float><<<cdiv(N, 8), 256, 0, stream>>>(
        zh, el, er, rowptr, csrc, b3, (float*)d_out, N);
}

// Round 13
// 327.434 us; speedup vs baseline: 2.6645x; 1.0798x over previous
//
#include <hip/hip_runtime.h>
#include <math.h>

// GAT 3-layer inference on MI355X.
// R12: layer 1 is rank-2 (Fin=2), so agg1 reconstructs z/el/er on the fly
// from feat[src] (8B L2-resident gather) + register-held W1 columns and
// rank-2 logit coefficients. Kills z1 kernel, layer-1 el/er arrays, and the
// 96MB layer-1 zh gather. Layers 2-3 unchanged (R11 structure).

#define NEG_BIG (-1e38f)

typedef _Float16 h8 __attribute__((ext_vector_type(8)));
typedef _Float16 h4 __attribute__((ext_vector_type(4)));

static inline int cdiv(int a, int b) { return (a + b - 1) / b; }

__device__ __forceinline__ float lrelu(float x) { return (x >= 0.f) ? x : 0.2f * x; }

// ---------------- CSR build ----------------

__global__ void count_deg_kernel(const int* __restrict__ dst, int* __restrict__ deg, int E) {
    int i = blockIdx.x * blockDim.x + threadIdx.x;
    if (i < E) atomicAdd(&deg[dst[i]], 1);
}

// hierarchical exclusive scan, phase 1: per-block (256 elems) scan + block sum
__global__ __launch_bounds__(256) void scan1_kernel(const int* __restrict__ deg,
                                                    int* __restrict__ rowptr,
                                                    int* __restrict__ bsum, int n) {
    __shared__ int wsum[4];
    int t = threadIdx.x;
    int l = t & 63, wv = t >> 6;
    int i = blockIdx.x * 256 + t;
    int v = (i < n) ? deg[i] : 0;
    int x = v;
    #pragma unroll
    for (int off = 1; off < 64; off <<= 1) {
        int y = __shfl_up(x, off);
        if (l >= off) x += y;
    }
    if (l == 63) wsum[wv] = x;
    __syncthreads();
    int wo = 0;
    #pragma unroll
    for (int j = 0; j < 4; ++j)
        if (j < wv) wo += wsum[j];
    if (i < n) rowptr[i] = wo + x - v;     // block-local exclusive
    if (t == 255) bsum[blockIdx.x] = wo + x;  // block total
}

// phase 2: single block scans the block sums (nb <= 256)
__global__ __launch_bounds__(256) void scan2_kernel(const int* __restrict__ bsum,
                                                    int* __restrict__ boff, int nb) {
    __shared__ int wsum[4];
    int t = threadIdx.x;
    int l = t & 63, wv = t >> 6;
    int v = (t < nb) ? bsum[t] : 0;
    int x = v;
    #pragma unroll
    for (int off = 1; off < 64; off <<= 1) {
        int y = __shfl_up(x, off);
        if (l >= off) x += y;
    }
    if (l == 63) wsum[wv] = x;
    __syncthreads();
    int wo = 0;
    #pragma unroll
    for (int j = 0; j < 4; ++j)
        if (j < wv) wo += wsum[j];
    if (t < nb) boff[t] = wo + x - v;      // exclusive over blocks
}

// phase 3: add block offsets; rowptr[n] = E (all dst in range => total = E)
__global__ __launch_bounds__(256) void scan3_kernel(int* __restrict__ rowptr,
                                                    const int* __restrict__ boff,
                                                    int n, int E) {
    int i = blockIdx.x * 256 + threadIdx.x;
    if (i < n) rowptr[i] += boff[blockIdx.x];
    if (i == 0) rowptr[n] = E;
}

// store the SRC VALUE in CSR order (no eidx indirection)
__global__ void fill_csr_kernel(const int* __restrict__ src, const int* __restrict__ dst,
                                const int* __restrict__ rowptr,
                                int* __restrict__ cursor, int* __restrict__ csrc, int E) {
    int i = blockIdx.x * blockDim.x + threadIdx.x;
    if (i < E) {
        int d = dst[i];
        int pos = atomicAdd(&cursor[d], 1);
        csrc[rowptr[d] + pos] = src[i];
    }
}

// ---------------- layer 1: fully-fused rank-2 GAT layer ----------------
// One 16-lane group per node, 4 nodes/wave. z1[v] = f0*W1[0,:]+f1*W1[1,:],
// el1[v] = f0*Ael[h]+f1*Bel[h] (rank-2), so per edge we load only
// feat[src] (8B, L2-resident). Lane owns channels c0=lg*8 (head h=lg>>2),
// holding W1[0][c0..+7], W1[1][c0..+7] in registers. Writes fp16 out.

__global__ __launch_bounds__(256) void agg1_kernel(
        const float* __restrict__ feat, const float* __restrict__ W1,
        const float* __restrict__ al, const float* __restrict__ ar,
        const int* __restrict__ rowptr, const int* __restrict__ csrc,
        const float* __restrict__ bias, _Float16* __restrict__ out, int N) {
    constexpr int GRP = 16, NV = 4;
    __shared__ float2 fss[4][NV][GRP + 1];
    __shared__ float  exs[4][NV][4][GRP + 1];
    const int l = threadIdx.x & 63;
    const int w = threadIdx.x >> 6;
    const int g = l >> 4;          // node slot within wave
    const int lg = l & 15;         // lane within group
    const int v = blockIdx.x * (4 * NV) + w * NV + g;

    // ---- per-wave prologue: rank-2 logit coefficients (all 64 lanes) ----
    // channel l (head l>>5) and channel l+64 (head 2+(l>>5))
    float w0l = W1[l], w0h = W1[l + 64];
    float w1l = W1[128 + l], w1h = W1[128 + l + 64];
    float all_ = al[l], alh = al[l + 64];
    float arl = ar[l], arh = ar[l + 64];
    float pa0 = w0l * all_, pa1 = w0h * alh;   // el f0-coef, heads {0|1},{2|3}
    float pb0 = w1l * all_, pb1 = w1h * alh;   // el f1-coef
    float pc0 = w0l * arl,  pc1 = w0h * arh;   // er f0-coef
    float pd0 = w1l * arl,  pd1 = w1h * arh;   // er f1-coef
    #pragma unroll
    for (int off = 1; off < 32; off <<= 1) {
        pa0 += __shfl_xor(pa0, off); pa1 += __shfl_xor(pa1, off);
        pb0 += __shfl_xor(pb0, off); pb1 += __shfl_xor(pb1, off);
        pc0 += __shfl_xor(pc0, off); pc1 += __shfl_xor(pc1, off);
        pd0 += __shfl_xor(pd0, off); pd1 += __shfl_xor(pd1, off);
    }
    // lanes 0..31 hold head {0 / 2}, lanes 32..63 hold head {1 / 3}
    float4 Ael = make_float4(__shfl(pa0, 0), __shfl(pa0, 32),
                             __shfl(pa1, 0), __shfl(pa1, 32));
    float4 Bel = make_float4(__shfl(pb0, 0), __shfl(pb0, 32),
                             __shfl(pb1, 0), __shfl(pb1, 32));
    float4 Aer = make_float4(__shfl(pc0, 0), __shfl(pc0, 32),
                             __shfl(pc1, 0), __shfl(pc1, 32));
    float4 Ber = make_float4(__shfl(pd0, 0), __shfl(pd0, 32),
                             __shfl(pd1, 0), __shfl(pd1, 32));

    if (v >= N) return;
    const int r0 = rowptr[v], r1 = rowptr[v + 1];
    const int c0 = lg * 8;
    const int h = lg >> 2;
    // W1 columns for this lane's 8 channels
    float4 w0a = *(const float4*)&W1[c0];
    float4 w0b = *(const float4*)&W1[c0 + 4];
    float4 w1a = *(const float4*)&W1[128 + c0];
    float4 w1b = *(const float4*)&W1[128 + c0 + 4];
    float4 b0 = *(const float4*)(bias + c0);
    float4 b1 = *(const float4*)(bias + c0 + 4);
    float4 o0, o1;

    if (r0 == r1) {
        o0 = b0; o1 = b1;  // empty segment: out = bias
    } else {
        float2 fv = *(const float2*)(feat + (size_t)v * 2);
        float4 er4 = make_float4(fmaf(fv.x, Aer.x, fv.y * Ber.x),
                                 fmaf(fv.x, Aer.y, fv.y * Ber.y),
                                 fmaf(fv.x, Aer.z, fv.y * Ber.z),
                                 fmaf(fv.x, Aer.w, fv.y * Ber.w));

        // ---- pass 1: per-head max; chunk-0 feat kept in registers ----
        float m0 = NEG_BIG, m1 = NEG_BIG, m2 = NEG_BIG, m3 = NEG_BIG;
        float2 fs0 = make_float2(0.f, 0.f);
        float4 e40 = make_float4(NEG_BIG, NEG_BIG, NEG_BIG, NEG_BIG);
        for (int base = r0; base < r1; base += GRP) {
            int i = base + lg;
            float ex_ = NEG_BIG, ey_ = NEG_BIG, ez_ = NEG_BIG, ew_ = NEG_BIG;
            float2 fs = make_float2(0.f, 0.f);
            if (i < r1) {
                int sv = csrc[i];
                fs = *(const float2*)(feat + (size_t)sv * 2);
                ex_ = lrelu(fmaf(fs.x, Ael.x, fs.y * Bel.x) + er4.x);
                ey_ = lrelu(fmaf(fs.x, Ael.y, fs.y * Bel.y) + er4.y);
                ez_ = lrelu(fmaf(fs.x, Ael.z, fs.y * Bel.z) + er4.z);
                ew_ = lrelu(fmaf(fs.x, Ael.w, fs.y * Bel.w) + er4.w);
            }
            if (base == r0) { fs0 = fs; e40 = make_float4(ex_, ey_, ez_, ew_); }
            m0 = fmaxf(m0, ex_); m1 = fmaxf(m1, ey_);
            m2 = fmaxf(m2, ez_); m3 = fmaxf(m3, ew_);
        }
        #pragma unroll
        for (int off = 1; off < GRP; off <<= 1) {
            m0 = fmaxf(m0, __shfl_xor(m0, off));
            m1 = fmaxf(m1, __shfl_xor(m1, off));
            m2 = fmaxf(m2, __shfl_xor(m2, off));
            m3 = fmaxf(m3, __shfl_xor(m3, off));
        }

        // ---- pass 2: stage {feat, ex}; inner loop = LDS + 18 VALU/edge ----
        float s0 = 0.f, s1 = 0.f, s2 = 0.f, s3 = 0.f;
        float4 a0 = make_float4(0.f, 0.f, 0.f, 0.f);
        float4 a1 = make_float4(0.f, 0.f, 0.f, 0.f);

        for (int base = r0; base < r1; base += GRP) {
            int i = base + lg;
            float2 fs; float4 e4;
            if (base == r0) {
                fs = fs0; e4 = e40;  // reused from pass 1 (deg<=16 fully covered)
            } else if (i < r1) {
                int sv = csrc[i];
                fs = *(const float2*)(feat + (size_t)sv * 2);
                e4 = make_float4(
                    lrelu(fmaf(fs.x, Ael.x, fs.y * Bel.x) + er4.x),
                    lrelu(fmaf(fs.x, Ael.y, fs.y * Bel.y) + er4.y),
                    lrelu(fmaf(fs.x, Ael.z, fs.y * Bel.z) + er4.z),
                    lrelu(fmaf(fs.x, Ael.w, fs.y * Bel.w) + er4.w));
            } else {
                fs = make_float2(0.f, 0.f);
                e4 = make_float4(NEG_BIG, NEG_BIG, NEG_BIG, NEG_BIG);
            }
            bool valid = (i < r1);
            float exv0 = valid ? __expf(e4.x - m0) : 0.f;
            float exv1 = valid ? __expf(e4.y - m1) : 0.f;
            float exv2 = valid ? __expf(e4.z - m2) : 0.f;
            float exv3 = valid ? __expf(e4.w - m3) : 0.f;
            s0 += exv0; s1 += exv1; s2 += exv2; s3 += exv3;
            fss[w][g][lg] = fs;
            exs[w][g][0][lg] = exv0; exs[w][g][1][lg] = exv1;
            exs[w][g][2][lg] = exv2; exs[w][g][3][lg] = exv3;
            int cnt = min(GRP, r1 - base);
            #pragma unroll 8
            for (int k = 0; k < cnt; ++k) {
                float2 fk = fss[w][g][k];      // broadcast ds_read (8B)
                float exk = exs[w][g][h][k];   // broadcast ds_read (4B)
                float u = fk.x * exk;
                float t = fk.y * exk;
                a0.x = fmaf(u, w0a.x, fmaf(t, w1a.x, a0.x));
                a0.y = fmaf(u, w0a.y, fmaf(t, w1a.y, a0.y));
                a0.z = fmaf(u, w0a.z, fmaf(t, w1a.z, a0.z));
                a0.w = fmaf(u, w0a.w, fmaf(t, w1a.w, a0.w));
                a1.x = fmaf(u, w0b.x, fmaf(t, w1b.x, a1.x));
                a1.y = fmaf(u, w0b.y, fmaf(t, w1b.y, a1.y));
                a1.z = fmaf(u, w0b.z, fmaf(t, w1b.z, a1.z));
                a1.w = fmaf(u, w0b.w, fmaf(t, w1b.w, a1.w));
            }
        }
        #pragma unroll
        for (int off = 1; off < GRP; off <<= 1) {
            s0 += __shfl_xor(s0, off);
            s1 += __shfl_xor(s1, off);
            s2 += __shfl_xor(s2, off);
            s3 += __shfl_xor(s3, off);
        }
        float s = (h == 0) ? s0 : (h == 1) ? s1 : (h == 2) ? s2 : s3;
        float inv = 1.f / s;
        o0 = make_float4(fmaf(a0.x, inv, b0.x), fmaf(a0.y, inv, b0.y),
                         fmaf(a0.z, inv, b0.z), fmaf(a0.w, inv, b0.w));
        o1 = make_float4(fmaf(a1.x, inv, b1.x), fmaf(a1.y, inv, b1.y),
                         fmaf(a1.z, inv, b1.z), fmaf(a1.w, inv, b1.w));
    }
    // relu
    o0.x = fmaxf(o0.x, 0.f); o0.y = fmaxf(o0.y, 0.f);
    o0.z = fmaxf(o0.z, 0.f); o0.w = fmaxf(o0.w, 0.f);
    o1.x = fmaxf(o1.x, 0.f); o1.y = fmaxf(o1.y, 0.f);
    o1.z = fmaxf(o1.z, 0.f); o1.w = fmaxf(o1.w, 0.f);
    h8 ho;
    ho[0] = (_Float16)o0.x; ho[1] = (_Float16)o0.y;
    ho[2] = (_Float16)o0.z; ho[3] = (_Float16)o0.w;
    ho[4] = (_Float16)o1.x; ho[5] = (_Float16)o1.y;
    ho[6] = (_Float16)o1.z; ho[7] = (_Float16)o1.w;
    *(h8*)(out + (size_t)v * 128 + c0) = ho;
}

// ---------------- GEMM: A(fp16)[N,128] @ W(f32)[128,HDout] -> ZH(fp16) + el/er ----------------

template <int HDOUT>
__global__ __launch_bounds__(256) void gemm_tile_kernel(
        const _Float16* __restrict__ A, const float* __restrict__ W,
        const float* __restrict__ al, const float* __restrict__ ar,
        _Float16* __restrict__ ZH, float* __restrict__ el, float* __restrict__ er,
        int N) {
    __shared__ __align__(16) float AT[64][132];
    __shared__ __align__(16) float WS[64][64];
    int n0 = blockIdx.x * 128;
    int c0 = blockIdx.y * 64;
    int t = threadIdx.x;
    int tr = t >> 4;
    int tc = t & 15;

    float acc[8][4] = {};

    for (int kc = 0; kc < 128; kc += 64) {
        {
            int kk = (t & 7) * 8;
            int rb = t >> 3;
            #pragma unroll
            for (int it = 0; it < 4; ++it) {
                int r = rb + 32 * it;
                int n = n0 + r;
                h8 a;
                #pragma unroll
                for (int j = 0; j < 8; ++j) a[j] = (_Float16)0.f;
                if (n < N) a = *(const h8*)&A[(size_t)n * 128 + kc + kk];
                #pragma unroll
                for (int j = 0; j < 8; ++j) AT[kk + j][r] = (float)a[j];
            }
        }
        {
            int cc = (t & 15) * 4;
            int kb = t >> 4;
            #pragma unroll
            for (int it = 0; it < 4; ++it) {
                int k = kb + 16 * it;
                *(float4*)&WS[k][cc] =
                    *(const float4*)&W[(size_t)(kc + k) * HDOUT + c0 + cc];
            }
        }
        __syncthreads();

        #pragma unroll 4
        for (int k = 0; k < 64; ++k) {
            float4 a0 = *(const float4*)&AT[k][tr * 8];
            float4 a1 = *(const float4*)&AT[k][tr * 8 + 4];
            float4 wv = *(const float4*)&WS[k][tc * 4];
            acc[0][0] = fmaf(a0.x, wv.x, acc[0][0]); acc[0][1] = fmaf(a0.x, wv.y, acc[0][1]);
            acc[0][2] = fmaf(a0.x, wv.z, acc[0][2]); acc[0][3] = fmaf(a0.x, wv.w, acc[0][3]);
            acc[1][0] = fmaf(a0.y, wv.x, acc[1][0]); acc[1][1] = fmaf(a0.y, wv.y, acc[1][1]);
            acc[1][2] = fmaf(a0.y, wv.z, acc[1][2]); acc[1][3] = fmaf(a0.y, wv.w, acc[1][3]);
            acc[2][0] = fmaf(a0.z, wv.x, acc[2][0]); acc[2][1] = fmaf(a0.z, wv.y, acc[2][1]);
            acc[2][2] = fmaf(a0.z, wv.z, acc[2][2]); acc[2][3] = fmaf(a0.z, wv.w, acc[2][3]);
            acc[3][0] = fmaf(a0.w, wv.x, acc[3][0]); acc[3][1] = fmaf(a0.w, wv.y, acc[3][1]);
            acc[3][2] = fmaf(a0.w, wv.z, acc[3][2]); acc[3][3] = fmaf(a0.w, wv.w, acc[3][3]);
            acc[4][0] = fmaf(a1.x, wv.x, acc[4][0]); acc[4][1] = fmaf(a1.x, wv.y, acc[4][1]);
            acc[4][2] = fmaf(a1.x, wv.z, acc[4][2]); acc[4][3] = fmaf(a1.x, wv.w, acc[4][3]);
            acc[5][0] = fmaf(a1.y, wv.x, acc[5][0]); acc[5][1] = fmaf(a1.y, wv.y, acc[5][1]);
            acc[5][2] = fmaf(a1.y, wv.z, acc[5][2]); acc[5][3] = fmaf(a1.y, wv.w, acc[5][3]);
            acc[6][0] = fmaf(a1.z, wv.x, acc[6][0]); acc[6][1] = fmaf(a1.z, wv.y, acc[6][1]);
            acc[6][2] = fmaf(a1.z, wv.z, acc[6][2]); acc[6][3] = fmaf(a1.z, wv.w, acc[6][3]);
            acc[7][0] = fmaf(a1.w, wv.x, acc[7][0]); acc[7][1] = fmaf(a1.w, wv.y, acc[7][1]);
            acc[7][2] = fmaf(a1.w, wv.z, acc[7][2]); acc[7][3] = fmaf(a1.w, wv.w, acc[7][3]);
        }
        __syncthreads();
    }

    float4 alv = *(const float4*)&al[c0 + tc * 4];
    float4 arv = *(const float4*)&ar[c0 + tc * 4];

    #pragma unroll
    for (int i = 0; i < 8; ++i) {
        int n = n0 + tr * 8 + i;
        bool ok = (n < N);
        if (ok) {
            h4 hz4 = { (_Float16)acc[i][0], (_Float16)acc[i][1],
                       (_Float16)acc[i][2], (_Float16)acc[i][3] };
            *(h4*)&ZH[(size_t)n * HDOUT + c0 + tc * 4] = hz4;
        }
        float pe = acc[i][0] * alv.x + acc[i][1] * alv.y +
                   acc[i][2] * alv.z + acc[i][3] * alv.w;
        float pr = acc[i][0] * arv.x + acc[i][1] * arv.y +
                   acc[i][2] * arv.z + acc[i][3] * arv.w;
        if (HDOUT == 128) {
            #pragma unroll
            for (int off = 1; off < 8; off <<= 1) {
                pe += __shfl_xor(pe, off);
                pr += __shfl_xor(pr, off);
            }
            if (ok && (tc & 7) == 0) {
                int h = 2 * blockIdx.y + (tc >> 3);
                el[(size_t)n * 4 + h] = pe;
                er[(size_t)n * 4 + h] = pr;
            }
        } else {
            #pragma unroll
            for (int off = 1; off < 16; off <<= 1) {
                pe += __shfl_xor(pe, off);
                pr += __shfl_xor(pr, off);
            }
            if (ok && tc == 0) {
                int h = blockIdx.y;
                el[(size_t)n * 4 + h] = pe;
                er[(size_t)n * 4 + h] = pr;
            }
        }
    }
}

// ---------------- fused edge-softmax + aggregate (layers 2-3) ----------------

template <bool RELU, int GRP, int HD, typename OUTT>
__global__ __launch_bounds__(256) void agg_kernel(
        const _Float16* __restrict__ zh, const float* __restrict__ el,
        const float* __restrict__ er, const int* __restrict__ rowptr,
        const int* __restrict__ csrc, const float* __restrict__ bias,
        OUTT* __restrict__ out, int N) {
    constexpr int NV = 64 / GRP;    // nodes per wave
    constexpr int CH = HD / GRP;    // channels per lane (= 8)
    constexpr int HGRP = GRP / 4;   // lanes per head
    static_assert(CH == 8, "config assumes 8 channels per lane");
    __shared__ float exs[4][NV][4][GRP + 1];
    __shared__ int   svs[4][NV][GRP + 1];
    const int l = threadIdx.x & 63;
    const int w = threadIdx.x >> 6;
    const int g = l / GRP;
    const int lg = l & (GRP - 1);
    const int v = blockIdx.x * (4 * NV) + w * NV + g;
    if (v >= N) return;
    const int r0 = rowptr[v], r1 = rowptr[v + 1];
    const int c0 = lg * CH;
    const int h = lg / HGRP;
    float4 b0 = *(const float4*)(bias + c0);
    float4 b1 = *(const float4*)(bias + c0 + 4);
    float4 o0, o1;

    if (r0 == r1) {
        o0 = b0; o1 = b1;
    } else {
        float4 er4 = *(const float4*)(er + (size_t)v * 4);

        float m0 = NEG_BIG, m1 = NEG_BIG, m2 = NEG_BIG, m3 = NEG_BIG;
        int sv0 = 0;
        float4 e40 = make_float4(NEG_BIG, NEG_BIG, NEG_BIG, NEG_BIG);
        for (int base = r0; base < r1; base += GRP) {
            int i = base + lg;
            float ex_ = NEG_BIG, ey_ = NEG_BIG, ez_ = NEG_BIG, ew_ = NEG_BIG;
            int sv = 0;
            if (i < r1) {
                sv = csrc[i];
                float4 ev = *(const float4*)(el + (size_t)sv * 4);
                ex_ = lrelu(ev.x + er4.x);
                ey_ = lrelu(ev.y + er4.y);
                ez_ = lrelu(ev.z + er4.z);
                ew_ = lrelu(ev.w + er4.w);
            }
            if (base == r0) { sv0 = sv; e40 = make_float4(ex_, ey_, ez_, ew_); }
            m0 = fmaxf(m0, ex_); m1 = fmaxf(m1, ey_);
            m2 = fmaxf(m2, ez_); m3 = fmaxf(m3, ew_);
        }
        #pragma unroll
        for (int off = 1; off < GRP; off <<= 1) {
            m0 = fmaxf(m0, __shfl_xor(m0, off));
            m1 = fmaxf(m1, __shfl_xor(m1, off));
            m2 = fmaxf(m2, __shfl_xor(m2, off));
            m3 = fmaxf(m3, __shfl_xor(m3, off));
        }

        float s0 = 0.f, s1 = 0.f, s2 = 0.f, s3 = 0.f;
        float4 a0 = make_float4(0.f, 0.f, 0.f, 0.f);
        float4 a1 = make_float4(0.f, 0.f, 0.f, 0.f);

        for (int base = r0; base < r1; base += GRP) {
            int i = base + lg;
            int sv; float4 e4;
            if (base == r0) {
                sv = sv0; e4 = e40;
            } else if (i < r1) {
                sv = csrc[i];
                float4 ev = *(const float4*)(el + (size_t)sv * 4);
                e4 = make_float4(lrelu(ev.x + er4.x), lrelu(ev.y + er4.y),
                                 lrelu(ev.z + er4.z), lrelu(ev.w + er4.w));
            } else {
                sv = 0; e4 = make_float4(NEG_BIG, NEG_BIG, NEG_BIG, NEG_BIG);
            }
            bool valid = (i < r1);
            float exv0 = valid ? __expf(e4.x - m0) : 0.f;
            float exv1 = valid ? __expf(e4.y - m1) : 0.f;
            float exv2 = valid ? __expf(e4.z - m2) : 0.f;
            float exv3 = valid ? __expf(e4.w - m3) : 0.f;
            s0 += exv0; s1 += exv1; s2 += exv2; s3 += exv3;
            svs[w][g][lg] = sv;
            exs[w][g][0][lg] = exv0; exs[w][g][1][lg] = exv1;
            exs[w][g][2][lg] = exv2; exs[w][g][3][lg] = exv3;
            int cnt = min(GRP, r1 - base);
            #pragma unroll 8
            for (int k = 0; k < cnt; ++k) {
                int svk = svs[w][g][k];
                float exk = exs[w][g][h][k];
                h8 zz = *(const h8*)(zh + (size_t)svk * HD + c0);
                a0.x = fmaf((float)zz[0], exk, a0.x);
                a0.y = fmaf((float)zz[1], exk, a0.y);
                a0.z = fmaf((float)zz[2], exk, a0.z);
                a0.w = fmaf((float)zz[3], exk, a0.w);
                a1.x = fmaf((float)zz[4], exk, a1.x);
                a1.y = fmaf((float)zz[5], exk, a1.y);
                a1.z = fmaf((float)zz[6], exk, a1.z);
                a1.w = fmaf((float)zz[7], exk, a1.w);
            }
        }
        #pragma unroll
        for (int off = 1; off < GRP; off <<= 1) {
            s0 += __shfl_xor(s0, off);
            s1 += __shfl_xor(s1, off);
            s2 += __shfl_xor(s2, off);
            s3 += __shfl_xor(s3, off);
        }
        float s = (h == 0) ? s0 : (h == 1) ? s1 : (h == 2) ? s2 : s3;
        float inv = 1.f / s;
        o0 = make_float4(fmaf(a0.x, inv, b0.x), fmaf(a0.y, inv, b0.y),
                         fmaf(a0.z, inv, b0.z), fmaf(a0.w, inv, b0.w));
        o1 = make_float4(fmaf(a1.x, inv, b1.x), fmaf(a1.y, inv, b1.y),
                         fmaf(a1.z, inv, b1.z), fmaf(a1.w, inv, b1.w));
    }
    if (RELU) {
        o0.x = fmaxf(o0.x, 0.f); o0.y = fmaxf(o0.y, 0.f);
        o0.z = fmaxf(o0.z, 0.f); o0.w = fmaxf(o0.w, 0.f);
        o1.x = fmaxf(o1.x, 0.f); o1.y = fmaxf(o1.y, 0.f);
        o1.z = fmaxf(o1.z, 0.f); o1.w = fmaxf(o1.w, 0.f);
    }
    if constexpr (sizeof(OUTT) == 2) {
        h8 ho;
        ho[0] = (_Float16)o0.x; ho[1] = (_Float16)o0.y;
        ho[2] = (_Float16)o0.z; ho[3] = (_Float16)o0.w;
        ho[4] = (_Float16)o1.x; ho[5] = (_Float16)o1.y;
        ho[6] = (_Float16)o1.z; ho[7] = (_Float16)o1.w;
        *(h8*)((_Float16*)out + (size_t)v * HD + c0) = ho;
    } else {
        float* op = (float*)out + (size_t)v * HD + c0;
        *(float4*)op = o0;
        *(float4*)(op + 4) = o1;
    }
}

// ---------------- launch ----------------

extern "C" void kernel_launch(void* const* d_in, const int* in_sizes, int n_in,
                              void* d_out, int out_size, void* d_ws, size_t ws_size,
                              hipStream_t stream) {
    const float* feat = (const float*)d_in[0];
    const int* src = (const int*)d_in[1];
    const int* dst = (const int*)d_in[2];
    const float* W1 = (const float*)d_in[3];
    const float* al1 = (const float*)d_in[4];
    const float* ar1 = (const float*)d_in[5];
    const float* b1 = (const float*)d_in[6];
    const float* W2 = (const float*)d_in[7];
    const float* al2 = (const float*)d_in[8];
    const float* ar2 = (const float*)d_in[9];
    const float* b2 = (const float*)d_in[10];
    const float* W3 = (const float*)d_in[11];
    const float* al3 = (const float*)d_in[12];
    const float* ar3 = (const float*)d_in[13];
    const float* b3 = (const float*)d_in[14];
    const int N = in_sizes[0] / 2;   // feat is [N,2]
    const int E = in_sizes[1];

    // workspace layout
    _Float16* hbuf = (_Float16*)d_ws;                 // [N,128] fp16 (agg out, gemm in)
    float* el = (float*)(hbuf + (size_t)N * 128);     // [N,4]
    float* er = el + (size_t)N * 4;                   // [N,4]
    _Float16* zh = (_Float16*)(er + (size_t)N * 4);   // [N,256] fp16 shadow
    int* csrc = (int*)(zh + (size_t)N * 256);         // [E] src values in CSR order
    int* deg = csrc + E;                              // [N]
    int* cursor = deg + N;                            // [N]
    int* rowptr = cursor + N;                         // [N+1]
    int* bsum = rowptr + (N + 1);                     // [nb]
    int* boff = bsum + 256;                           // [nb]

    const int nb = cdiv(N, 256);

    // CSR build (per call)
    hipMemsetAsync(deg, 0, sizeof(int) * (size_t)(2 * N), stream);  // deg + cursor
    count_deg_kernel<<<cdiv(E, 256), 256, 0, stream>>>(dst, deg, E);
    scan1_kernel<<<nb, 256, 0, stream>>>(deg, rowptr, bsum, N);
    scan2_kernel<<<1, 256, 0, stream>>>(bsum, boff, nb);
    scan3_kernel<<<nb, 256, 0, stream>>>(rowptr, boff, N, E);
    fill_csr_kernel<<<cdiv(E, 256), 256, 0, stream>>>(src, dst, rowptr, cursor, csrc, E);

    // ---- layer 1 (2 -> 128, relu): fully fused rank-2 layer ----
    agg1_kernel<<<cdiv(N, 16), 256, 0, stream>>>(feat, W1, al1, ar1, rowptr, csrc,
                                                 b1, hbuf, N);

    // ---- layer 2 (128 -> 128, relu) ----
    gemm_tile_kernel<128><<<dim3(cdiv(N, 128), 2), 256, 0, stream>>>(
        hbuf, W2, al2, ar2, zh, el, er, N);
    agg_kernel<true, 16, 128, _Float16><<<cdiv(N, 16), 256, 0, stream>>>(
        zh, el, er, rowptr, csrc, b2, hbuf, N);

    // ---- layer 3 (128 -> 256, no relu) ----
    gemm_tile_kernel<256><<<dim3(cdiv(N, 128), 4), 256, 0, stream>>>(
        hbuf, W3, al3, ar3, zh, el, er, N);
    agg_kernel<false, 32, 256, float><<<cdiv(N, 8), 256, 0, stream>>>(
        zh, el, er, rowptr, csrc, b3, (float*)d_out, N);
}

// Round 14
// 291.462 us; speedup vs baseline: 2.9934x; 1.1234x over previous
//
#include <hip/hip_runtime.h>
#include <math.h>

// GAT 3-layer inference on MI355X.
// R13: GEMMs moved to matrix cores (v_mfma_f32_16x16x32_f16). A is already
// fp16 (hbuf); W converted+transposed to fp16 WT once per call. No LDS:
// per-lane contiguous-8 fragment loads from row-major A and WT (m92 B^T
// idiom); el/er fused in the per-head tile loop. Everything else frozen.

#define NEG_BIG (-1e38f)

typedef _Float16 h8 __attribute__((ext_vector_type(8)));
typedef _Float16 h4 __attribute__((ext_vector_type(4)));
typedef float f32x4 __attribute__((ext_vector_type(4)));

static inline int cdiv(int a, int b) { return (a + b - 1) / b; }

__device__ __forceinline__ float lrelu(float x) { return (x >= 0.f) ? x : 0.2f * x; }

// ---------------- CSR build ----------------

__global__ void count_deg_kernel(const int* __restrict__ dst, int* __restrict__ deg, int E) {
    int i = blockIdx.x * blockDim.x + threadIdx.x;
    if (i < E) atomicAdd(&deg[dst[i]], 1);
}

__global__ __launch_bounds__(256) void scan1_kernel(const int* __restrict__ deg,
                                                    int* __restrict__ rowptr,
                                                    int* __restrict__ bsum, int n) {
    __shared__ int wsum[4];
    int t = threadIdx.x;
    int l = t & 63, wv = t >> 6;
    int i = blockIdx.x * 256 + t;
    int v = (i < n) ? deg[i] : 0;
    int x = v;
    #pragma unroll
    for (int off = 1; off < 64; off <<= 1) {
        int y = __shfl_up(x, off);
        if (l >= off) x += y;
    }
    if (l == 63) wsum[wv] = x;
    __syncthreads();
    int wo = 0;
    #pragma unroll
    for (int j = 0; j < 4; ++j)
        if (j < wv) wo += wsum[j];
    if (i < n) rowptr[i] = wo + x - v;
    if (t == 255) bsum[blockIdx.x] = wo + x;
}

__global__ __launch_bounds__(256) void scan2_kernel(const int* __restrict__ bsum,
                                                    int* __restrict__ boff, int nb) {
    __shared__ int wsum[4];
    int t = threadIdx.x;
    int l = t & 63, wv = t >> 6;
    int v = (t < nb) ? bsum[t] : 0;
    int x = v;
    #pragma unroll
    for (int off = 1; off < 64; off <<= 1) {
        int y = __shfl_up(x, off);
        if (l >= off) x += y;
    }
    if (l == 63) wsum[wv] = x;
    __syncthreads();
    int wo = 0;
    #pragma unroll
    for (int j = 0; j < 4; ++j)
        if (j < wv) wo += wsum[j];
    if (t < nb) boff[t] = wo + x - v;
}

__global__ __launch_bounds__(256) void scan3_kernel(int* __restrict__ rowptr,
                                                    const int* __restrict__ boff,
                                                    int n, int E) {
    int i = blockIdx.x * 256 + threadIdx.x;
    if (i < n) rowptr[i] += boff[blockIdx.x];
    if (i == 0) rowptr[n] = E;
}

__global__ void fill_csr_kernel(const int* __restrict__ src, const int* __restrict__ dst,
                                const int* __restrict__ rowptr,
                                int* __restrict__ cursor, int* __restrict__ csrc, int E) {
    int i = blockIdx.x * blockDim.x + threadIdx.x;
    if (i < E) {
        int d = dst[i];
        int pos = atomicAdd(&cursor[d], 1);
        csrc[rowptr[d] + pos] = src[i];
    }
}

// ---------------- W convert: WT[c][k] = (fp16) W[k][c] ----------------

template <int HDOUT>
__global__ __launch_bounds__(256) void wconv_kernel(const float* __restrict__ W,
                                                    _Float16* __restrict__ WT) {
    int idx = blockIdx.x * 256 + threadIdx.x;
    if (idx < 128 * HDOUT) {
        int k = idx / HDOUT, c = idx % HDOUT;
        WT[(size_t)c * 128 + k] = (_Float16)W[idx];
    }
}

// ---------------- layer 1: fully-fused rank-2 GAT layer (R12) ----------------

__global__ __launch_bounds__(256) void agg1_kernel(
        const float* __restrict__ feat, const float* __restrict__ W1,
        const float* __restrict__ al, const float* __restrict__ ar,
        const int* __restrict__ rowptr, const int* __restrict__ csrc,
        const float* __restrict__ bias, _Float16* __restrict__ out, int N) {
    constexpr int GRP = 16, NV = 4;
    __shared__ float2 fss[4][NV][GRP + 1];
    __shared__ float  exs[4][NV][4][GRP + 1];
    const int l = threadIdx.x & 63;
    const int w = threadIdx.x >> 6;
    const int g = l >> 4;
    const int lg = l & 15;
    const int v = blockIdx.x * (4 * NV) + w * NV + g;

    // per-wave prologue: rank-2 logit coefficients
    float w0l = W1[l], w0h = W1[l + 64];
    float w1l = W1[128 + l], w1h = W1[128 + l + 64];
    float all_ = al[l], alh = al[l + 64];
    float arl = ar[l], arh = ar[l + 64];
    float pa0 = w0l * all_, pa1 = w0h * alh;
    float pb0 = w1l * all_, pb1 = w1h * alh;
    float pc0 = w0l * arl,  pc1 = w0h * arh;
    float pd0 = w1l * arl,  pd1 = w1h * arh;
    #pragma unroll
    for (int off = 1; off < 32; off <<= 1) {
        pa0 += __shfl_xor(pa0, off); pa1 += __shfl_xor(pa1, off);
        pb0 += __shfl_xor(pb0, off); pb1 += __shfl_xor(pb1, off);
        pc0 += __shfl_xor(pc0, off); pc1 += __shfl_xor(pc1, off);
        pd0 += __shfl_xor(pd0, off); pd1 += __shfl_xor(pd1, off);
    }
    float4 Ael = make_float4(__shfl(pa0, 0), __shfl(pa0, 32),
                             __shfl(pa1, 0), __shfl(pa1, 32));
    float4 Bel = make_float4(__shfl(pb0, 0), __shfl(pb0, 32),
                             __shfl(pb1, 0), __shfl(pb1, 32));
    float4 Aer = make_float4(__shfl(pc0, 0), __shfl(pc0, 32),
                             __shfl(pc1, 0), __shfl(pc1, 32));
    float4 Ber = make_float4(__shfl(pd0, 0), __shfl(pd0, 32),
                             __shfl(pd1, 0), __shfl(pd1, 32));

    if (v >= N) return;
    const int r0 = rowptr[v], r1 = rowptr[v + 1];
    const int c0 = lg * 8;
    const int h = lg >> 2;
    float4 w0a = *(const float4*)&W1[c0];
    float4 w0b = *(const float4*)&W1[c0 + 4];
    float4 w1a = *(const float4*)&W1[128 + c0];
    float4 w1b = *(const float4*)&W1[128 + c0 + 4];
    float4 b0 = *(const float4*)(bias + c0);
    float4 b1 = *(const float4*)(bias + c0 + 4);
    float4 o0, o1;

    if (r0 == r1) {
        o0 = b0; o1 = b1;
    } else {
        float2 fv = *(const float2*)(feat + (size_t)v * 2);
        float4 er4 = make_float4(fmaf(fv.x, Aer.x, fv.y * Ber.x),
                                 fmaf(fv.x, Aer.y, fv.y * Ber.y),
                                 fmaf(fv.x, Aer.z, fv.y * Ber.z),
                                 fmaf(fv.x, Aer.w, fv.y * Ber.w));

        float m0 = NEG_BIG, m1 = NEG_BIG, m2 = NEG_BIG, m3 = NEG_BIG;
        float2 fs0 = make_float2(0.f, 0.f);
        float4 e40 = make_float4(NEG_BIG, NEG_BIG, NEG_BIG, NEG_BIG);
        for (int base = r0; base < r1; base += GRP) {
            int i = base + lg;
            float ex_ = NEG_BIG, ey_ = NEG_BIG, ez_ = NEG_BIG, ew_ = NEG_BIG;
            float2 fs = make_float2(0.f, 0.f);
            if (i < r1) {
                int sv = csrc[i];
                fs = *(const float2*)(feat + (size_t)sv * 2);
                ex_ = lrelu(fmaf(fs.x, Ael.x, fs.y * Bel.x) + er4.x);
                ey_ = lrelu(fmaf(fs.x, Ael.y, fs.y * Bel.y) + er4.y);
                ez_ = lrelu(fmaf(fs.x, Ael.z, fs.y * Bel.z) + er4.z);
                ew_ = lrelu(fmaf(fs.x, Ael.w, fs.y * Bel.w) + er4.w);
            }
            if (base == r0) { fs0 = fs; e40 = make_float4(ex_, ey_, ez_, ew_); }
            m0 = fmaxf(m0, ex_); m1 = fmaxf(m1, ey_);
            m2 = fmaxf(m2, ez_); m3 = fmaxf(m3, ew_);
        }
        #pragma unroll
        for (int off = 1; off < GRP; off <<= 1) {
            m0 = fmaxf(m0, __shfl_xor(m0, off));
            m1 = fmaxf(m1, __shfl_xor(m1, off));
            m2 = fmaxf(m2, __shfl_xor(m2, off));
            m3 = fmaxf(m3, __shfl_xor(m3, off));
        }

        float s0 = 0.f, s1 = 0.f, s2 = 0.f, s3 = 0.f;
        float4 a0 = make_float4(0.f, 0.f, 0.f, 0.f);
        float4 a1 = make_float4(0.f, 0.f, 0.f, 0.f);

        for (int base = r0; base < r1; base += GRP) {
            int i = base + lg;
            float2 fs; float4 e4;
            if (base == r0) {
                fs = fs0; e4 = e40;
            } else if (i < r1) {
                int sv = csrc[i];
                fs = *(const float2*)(feat + (size_t)sv * 2);
                e4 = make_float4(
                    lrelu(fmaf(fs.x, Ael.x, fs.y * Bel.x) + er4.x),
                    lrelu(fmaf(fs.x, Ael.y, fs.y * Bel.y) + er4.y),
                    lrelu(fmaf(fs.x, Ael.z, fs.y * Bel.z) + er4.z),
                    lrelu(fmaf(fs.x, Ael.w, fs.y * Bel.w) + er4.w));
            } else {
                fs = make_float2(0.f, 0.f);
                e4 = make_float4(NEG_BIG, NEG_BIG, NEG_BIG, NEG_BIG);
            }
            bool valid = (i < r1);
            float exv0 = valid ? __expf(e4.x - m0) : 0.f;
            float exv1 = valid ? __expf(e4.y - m1) : 0.f;
            float exv2 = valid ? __expf(e4.z - m2) : 0.f;
            float exv3 = valid ? __expf(e4.w - m3) : 0.f;
            s0 += exv0; s1 += exv1; s2 += exv2; s3 += exv3;
            fss[w][g][lg] = fs;
            exs[w][g][0][lg] = exv0; exs[w][g][1][lg] = exv1;
            exs[w][g][2][lg] = exv2; exs[w][g][3][lg] = exv3;
            int cnt = min(GRP, r1 - base);
            #pragma unroll 8
            for (int k = 0; k < cnt; ++k) {
                float2 fk = fss[w][g][k];
                float exk = exs[w][g][h][k];
                float u = fk.x * exk;
                float t = fk.y * exk;
                a0.x = fmaf(u, w0a.x, fmaf(t, w1a.x, a0.x));
                a0.y = fmaf(u, w0a.y, fmaf(t, w1a.y, a0.y));
                a0.z = fmaf(u, w0a.z, fmaf(t, w1a.z, a0.z));
                a0.w = fmaf(u, w0a.w, fmaf(t, w1a.w, a0.w));
                a1.x = fmaf(u, w0b.x, fmaf(t, w1b.x, a1.x));
                a1.y = fmaf(u, w0b.y, fmaf(t, w1b.y, a1.y));
                a1.z = fmaf(u, w0b.z, fmaf(t, w1b.z, a1.z));
                a1.w = fmaf(u, w0b.w, fmaf(t, w1b.w, a1.w));
            }
        }
        #pragma unroll
        for (int off = 1; off < GRP; off <<= 1) {
            s0 += __shfl_xor(s0, off);
            s1 += __shfl_xor(s1, off);
            s2 += __shfl_xor(s2, off);
            s3 += __shfl_xor(s3, off);
        }
        float s = (h == 0) ? s0 : (h == 1) ? s1 : (h == 2) ? s2 : s3;
        float inv = 1.f / s;
        o0 = make_float4(fmaf(a0.x, inv, b0.x), fmaf(a0.y, inv, b0.y),
                         fmaf(a0.z, inv, b0.z), fmaf(a0.w, inv, b0.w));
        o1 = make_float4(fmaf(a1.x, inv, b1.x), fmaf(a1.y, inv, b1.y),
                         fmaf(a1.z, inv, b1.z), fmaf(a1.w, inv, b1.w));
    }
    o0.x = fmaxf(o0.x, 0.f); o0.y = fmaxf(o0.y, 0.f);
    o0.z = fmaxf(o0.z, 0.f); o0.w = fmaxf(o0.w, 0.f);
    o1.x = fmaxf(o1.x, 0.f); o1.y = fmaxf(o1.y, 0.f);
    o1.z = fmaxf(o1.z, 0.f); o1.w = fmaxf(o1.w, 0.f);
    h8 ho;
    ho[0] = (_Float16)o0.x; ho[1] = (_Float16)o0.y;
    ho[2] = (_Float16)o0.z; ho[3] = (_Float16)o0.w;
    ho[4] = (_Float16)o1.x; ho[5] = (_Float16)o1.y;
    ho[6] = (_Float16)o1.z; ho[7] = (_Float16)o1.w;
    *(h8*)(out + (size_t)v * 128 + c0) = ho;
}

// ---------------- MFMA GEMM: A(fp16)[N,128] @ W -> ZH(fp16) + el/er ----------------
// One wave per 16 rows. v_mfma_f32_16x16x32_f16, K=128 in 4 steps.
// Fragments (m89/m92-verified pattern): A[m=l&15][k=(l>>4)*8+j] contiguous h8
// from row-major A; B[k][n=l&15] as contiguous h8 from WT[n][k] (B^T idiom);
// D: row=(l>>4)*4+r, col=l&15. Head h covers col tiles [h*TPH, (h+1)*TPH) so
// el/er accumulate per-head in registers, 16-lane shfl reduce, single write.

template <int HDOUT>
__global__ __launch_bounds__(256) void gemm_mfma_kernel(
        const _Float16* __restrict__ A, const _Float16* __restrict__ WT,
        const float* __restrict__ al, const float* __restrict__ ar,
        _Float16* __restrict__ ZH, float* __restrict__ el, float* __restrict__ er,
        int N) {
    constexpr int TPH = HDOUT / 64;  // 16-col tiles per head (2 or 4)
    const int l = threadIdx.x & 63;
    const int wid = blockIdx.x * 4 + (threadIdx.x >> 6);
    const int m0 = wid * 16;
    if (m0 >= N) return;
    const int lc = l & 15;
    const int kg = l >> 4;

    // A fragments for 4 k-steps (lane's own row)
    h8 afrag[4];
    {
        int m = m0 + lc;
        if (m < N) {
            const _Float16* ap = A + (size_t)m * 128 + kg * 8;
            #pragma unroll
            for (int ks = 0; ks < 4; ++ks) afrag[ks] = *(const h8*)(ap + ks * 32);
        } else {
            #pragma unroll
            for (int ks = 0; ks < 4; ++ks)
                #pragma unroll
                for (int j = 0; j < 8; ++j) afrag[ks][j] = (_Float16)0.f;
        }
    }

    #pragma unroll
    for (int h = 0; h < 4; ++h) {
        float pel[4] = {0.f, 0.f, 0.f, 0.f};
        float per_[4] = {0.f, 0.f, 0.f, 0.f};
        #pragma unroll
        for (int tt = 0; tt < TPH; ++tt) {
            int col = (h * TPH + tt) * 16 + lc;
            f32x4 acc = {0.f, 0.f, 0.f, 0.f};
            const _Float16* wp = WT + (size_t)col * 128 + kg * 8;
            #pragma unroll
            for (int ks = 0; ks < 4; ++ks) {
                h8 bfrag = *(const h8*)(wp + ks * 32);
                acc = __builtin_amdgcn_mfma_f32_16x16x32_f16(afrag[ks], bfrag, acc,
                                                             0, 0, 0);
            }
            float alc = al[col], arc = ar[col];
            #pragma unroll
            for (int r = 0; r < 4; ++r) {
                int n = m0 + kg * 4 + r;
                if (n < N) ZH[(size_t)n * HDOUT + col] = (_Float16)acc[r];
                pel[r] = fmaf(acc[r], alc, pel[r]);
                per_[r] = fmaf(acc[r], arc, per_[r]);
            }
        }
        #pragma unroll
        for (int off = 1; off < 16; off <<= 1) {
            #pragma unroll
            for (int r = 0; r < 4; ++r) {
                pel[r] += __shfl_xor(pel[r], off);
                per_[r] += __shfl_xor(per_[r], off);
            }
        }
        if (lc == 0) {
            #pragma unroll
            for (int r = 0; r < 4; ++r) {
                int n = m0 + kg * 4 + r;
                if (n < N) {
                    el[(size_t)n * 4 + h] = pel[r];
                    er[(size_t)n * 4 + h] = per_[r];
                }
            }
        }
    }
}

// ---------------- fused edge-softmax + aggregate (layers 2-3) ----------------

template <bool RELU, int GRP, int HD, typename OUTT>
__global__ __launch_bounds__(256) void agg_kernel(
        const _Float16* __restrict__ zh, const float* __restrict__ el,
        const float* __restrict__ er, const int* __restrict__ rowptr,
        const int* __restrict__ csrc, const float* __restrict__ bias,
        OUTT* __restrict__ out, int N) {
    constexpr int NV = 64 / GRP;
    constexpr int CH = HD / GRP;
    constexpr int HGRP = GRP / 4;
    static_assert(CH == 8, "config assumes 8 channels per lane");
    __shared__ float exs[4][NV][4][GRP + 1];
    __shared__ int   svs[4][NV][GRP + 1];
    const int l = threadIdx.x & 63;
    const int w = threadIdx.x >> 6;
    const int g = l / GRP;
    const int lg = l & (GRP - 1);
    const int v = blockIdx.x * (4 * NV) + w * NV + g;
    if (v >= N) return;
    const int r0 = rowptr[v], r1 = rowptr[v + 1];
    const int c0 = lg * CH;
    const int h = lg / HGRP;
    float4 b0 = *(const float4*)(bias + c0);
    float4 b1 = *(const float4*)(bias + c0 + 4);
    float4 o0, o1;

    if (r0 == r1) {
        o0 = b0; o1 = b1;
    } else {
        float4 er4 = *(const float4*)(er + (size_t)v * 4);

        float m0 = NEG_BIG, m1 = NEG_BIG, m2 = NEG_BIG, m3 = NEG_BIG;
        int sv0 = 0;
        float4 e40 = make_float4(NEG_BIG, NEG_BIG, NEG_BIG, NEG_BIG);
        for (int base = r0; base < r1; base += GRP) {
            int i = base + lg;
            float ex_ = NEG_BIG, ey_ = NEG_BIG, ez_ = NEG_BIG, ew_ = NEG_BIG;
            int sv = 0;
            if (i < r1) {
                sv = csrc[i];
                float4 ev = *(const float4*)(el + (size_t)sv * 4);
                ex_ = lrelu(ev.x + er4.x);
                ey_ = lrelu(ev.y + er4.y);
                ez_ = lrelu(ev.z + er4.z);
                ew_ = lrelu(ev.w + er4.w);
            }
            if (base == r0) { sv0 = sv; e40 = make_float4(ex_, ey_, ez_, ew_); }
            m0 = fmaxf(m0, ex_); m1 = fmaxf(m1, ey_);
            m2 = fmaxf(m2, ez_); m3 = fmaxf(m3, ew_);
        }
        #pragma unroll
        for (int off = 1; off < GRP; off <<= 1) {
            m0 = fmaxf(m0, __shfl_xor(m0, off));
            m1 = fmaxf(m1, __shfl_xor(m1, off));
            m2 = fmaxf(m2, __shfl_xor(m2, off));
            m3 = fmaxf(m3, __shfl_xor(m3, off));
        }

        float s0 = 0.f, s1 = 0.f, s2 = 0.f, s3 = 0.f;
        float4 a0 = make_float4(0.f, 0.f, 0.f, 0.f);
        float4 a1 = make_float4(0.f, 0.f, 0.f, 0.f);

        for (int base = r0; base < r1; base += GRP) {
            int i = base + lg;
            int sv; float4 e4;
            if (base == r0) {
                sv = sv0; e4 = e40;
            } else if (i < r1) {
                sv = csrc[i];
                float4 ev = *(const float4*)(el + (size_t)sv * 4);
                e4 = make_float4(lrelu(ev.x + er4.x), lrelu(ev.y + er4.y),
                                 lrelu(ev.z + er4.z), lrelu(ev.w + er4.w));
            } else {
                sv = 0; e4 = make_float4(NEG_BIG, NEG_BIG, NEG_BIG, NEG_BIG);
            }
            bool valid = (i < r1);
            float exv0 = valid ? __expf(e4.x - m0) : 0.f;
            float exv1 = valid ? __expf(e4.y - m1) : 0.f;
            float exv2 = valid ? __expf(e4.z - m2) : 0.f;
            float exv3 = valid ? __expf(e4.w - m3) : 0.f;
            s0 += exv0; s1 += exv1; s2 += exv2; s3 += exv3;
            svs[w][g][lg] = sv;
            exs[w][g][0][lg] = exv0; exs[w][g][1][lg] = exv1;
            exs[w][g][2][lg] = exv2; exs[w][g][3][lg] = exv3;
            int cnt = min(GRP, r1 - base);
            #pragma unroll 8
            for (int k = 0; k < cnt; ++k) {
                int svk = svs[w][g][k];
                float exk = exs[w][g][h][k];
                h8 zz = *(const h8*)(zh + (size_t)svk * HD + c0);
                a0.x = fmaf((float)zz[0], exk, a0.x);
                a0.y = fmaf((float)zz[1], exk, a0.y);
                a0.z = fmaf((float)zz[2], exk, a0.z);
                a0.w = fmaf((float)zz[3], exk, a0.w);
                a1.x = fmaf((float)zz[4], exk, a1.x);
                a1.y = fmaf((float)zz[5], exk, a1.y);
                a1.z = fmaf((float)zz[6], exk, a1.z);
                a1.w = fmaf((float)zz[7], exk, a1.w);
            }
        }
        #pragma unroll
        for (int off = 1; off < GRP; off <<= 1) {
            s0 += __shfl_xor(s0, off);
            s1 += __shfl_xor(s1, off);
            s2 += __shfl_xor(s2, off);
            s3 += __shfl_xor(s3, off);
        }
        float s = (h == 0) ? s0 : (h == 1) ? s1 : (h == 2) ? s2 : s3;
        float inv = 1.f / s;
        o0 = make_float4(fmaf(a0.x, inv, b0.x), fmaf(a0.y, inv, b0.y),
                         fmaf(a0.z, inv, b0.z), fmaf(a0.w, inv, b0.w));
        o1 = make_float4(fmaf(a1.x, inv, b1.x), fmaf(a1.y, inv, b1.y),
                         fmaf(a1.z, inv, b1.z), fmaf(a1.w, inv, b1.w));
    }
    if (RELU) {
        o0.x = fmaxf(o0.x, 0.f); o0.y = fmaxf(o0.y, 0.f);
        o0.z = fmaxf(o0.z, 0.f); o0.w = fmaxf(o0.w, 0.f);
        o1.x = fmaxf(o1.x, 0.f); o1.y = fmaxf(o1.y, 0.f);
        o1.z = fmaxf(o1.z, 0.f); o1.w = fmaxf(o1.w, 0.f);
    }
    if constexpr (sizeof(OUTT) == 2) {
        h8 ho;
        ho[0] = (_Float16)o0.x; ho[1] = (_Float16)o0.y;
        ho[2] = (_Float16)o0.z; ho[3] = (_Float16)o0.w;
        ho[4] = (_Float16)o1.x; ho[5] = (_Float16)o1.y;
        ho[6] = (_Float16)o1.z; ho[7] = (_Float16)o1.w;
        *(h8*)((_Float16*)out + (size_t)v * HD + c0) = ho;
    } else {
        float* op = (float*)out + (size_t)v * HD + c0;
        *(float4*)op = o0;
        *(float4*)(op + 4) = o1;
    }
}

// ---------------- launch ----------------

extern "C" void kernel_launch(void* const* d_in, const int* in_sizes, int n_in,
                              void* d_out, int out_size, void* d_ws, size_t ws_size,
                              hipStream_t stream) {
    const float* feat = (const float*)d_in[0];
    const int* src = (const int*)d_in[1];
    const int* dst = (const int*)d_in[2];
    const float* W1 = (const float*)d_in[3];
    const float* al1 = (const float*)d_in[4];
    const float* ar1 = (const float*)d_in[5];
    const float* b1 = (const float*)d_in[6];
    const float* W2 = (const float*)d_in[7];
    const float* al2 = (const float*)d_in[8];
    const float* ar2 = (const float*)d_in[9];
    const float* b2 = (const float*)d_in[10];
    const float* W3 = (const float*)d_in[11];
    const float* al3 = (const float*)d_in[12];
    const float* ar3 = (const float*)d_in[13];
    const float* b3 = (const float*)d_in[14];
    const int N = in_sizes[0] / 2;   // feat is [N,2]
    const int E = in_sizes[1];

    // workspace layout (16B alignment maintained through zh/WT)
    _Float16* hbuf = (_Float16*)d_ws;                 // [N,128] fp16
    float* el = (float*)(hbuf + (size_t)N * 128);     // [N,4]
    float* er = el + (size_t)N * 4;                   // [N,4]
    _Float16* zh = (_Float16*)(er + (size_t)N * 4);   // [N,256] fp16 shadow
    _Float16* WT2 = zh + (size_t)N * 256;             // [128,128] fp16 (W2^T)
    _Float16* WT3 = WT2 + 128 * 128;                  // [256,128] fp16 (W3^T)
    int* csrc = (int*)(WT3 + 256 * 128);              // [E]
    int* deg = csrc + E;                              // [N]
    int* cursor = deg + N;                            // [N]
    int* rowptr = cursor + N;                         // [N+1]
    int* bsum = rowptr + (N + 1);                     // [nb]
    int* boff = bsum + 256;                           // [nb]

    const int nb = cdiv(N, 256);

    // CSR build + weight converts (independent, front-loaded)
    hipMemsetAsync(deg, 0, sizeof(int) * (size_t)(2 * N), stream);  // deg + cursor
    wconv_kernel<128><<<cdiv(128 * 128, 256), 256, 0, stream>>>(W2, WT2);
    wconv_kernel<256><<<cdiv(128 * 256, 256), 256, 0, stream>>>(W3, WT3);
    count_deg_kernel<<<cdiv(E, 256), 256, 0, stream>>>(dst, deg, E);
    scan1_kernel<<<nb, 256, 0, stream>>>(deg, rowptr, bsum, N);
    scan2_kernel<<<1, 256, 0, stream>>>(bsum, boff, nb);
    scan3_kernel<<<nb, 256, 0, stream>>>(rowptr, boff, N, E);
    fill_csr_kernel<<<cdiv(E, 256), 256, 0, stream>>>(src, dst, rowptr, cursor, csrc, E);

    // ---- layer 1 (2 -> 128, relu): fully fused rank-2 layer ----
    agg1_kernel<<<cdiv(N, 16), 256, 0, stream>>>(feat, W1, al1, ar1, rowptr, csrc,
                                                 b1, hbuf, N);

    // ---- layer 2 (128 -> 128, relu) ----
    gemm_mfma_kernel<128><<<cdiv(N, 64), 256, 0, stream>>>(
        hbuf, WT2, al2, ar2, zh, el, er, N);
    agg_kernel<true, 16, 128, _Float16><<<cdiv(N, 16), 256, 0, stream>>>(
        zh, el, er, rowptr, csrc, b2, hbuf, N);

    // ---- layer 3 (128 -> 256, no relu) ----
    gemm_mfma_kernel<256><<<cdiv(N, 64), 256, 0, stream>>>(
        hbuf, WT3, al3, ar3, zh, el, er, N);
    agg_kernel<false, 32, 256, float><<<cdiv(N, 8), 256, 0, stream>>>(
        zh, el, er, rowptr, csrc, b3, (float*)d_out, N);
}

// Round 15
// 290.458 us; speedup vs baseline: 3.0037x; 1.0035x over previous
//
#include <hip/hip_runtime.h>
#include <math.h>

// GAT 3-layer inference on MI355X.
// R14: housekeeping — gemm ZH writes coalesced via same-wave LDS staging
// (h8 stores, was scalar 2B); count/fill vectorized 4 edges/thread;
// scan2 folded into scan3; wconv fused to one launch. Aggs frozen
// (at L2-miss-path roofline per R13 L3-replay evidence).

#define NEG_BIG (-1e38f)

typedef _Float16 h8 __attribute__((ext_vector_type(8)));
typedef _Float16 h4 __attribute__((ext_vector_type(4)));
typedef float f32x4 __attribute__((ext_vector_type(4)));

static inline int cdiv(int a, int b) { return (a + b - 1) / b; }

__device__ __forceinline__ float lrelu(float x) { return (x >= 0.f) ? x : 0.2f * x; }

// ---------------- CSR build ----------------

__global__ void count_deg_kernel(const int* __restrict__ dst, int* __restrict__ deg, int E) {
    int i = (blockIdx.x * blockDim.x + threadIdx.x) * 4;
    if (i + 3 < E) {
        int4 d = *(const int4*)(dst + i);
        atomicAdd(&deg[d.x], 1);
        atomicAdd(&deg[d.y], 1);
        atomicAdd(&deg[d.z], 1);
        atomicAdd(&deg[d.w], 1);
    } else {
        for (int j = i; j < E; ++j) atomicAdd(&deg[dst[j]], 1);
    }
}

// scan phase 1: per-block (256 elems) exclusive scan + block sum
__global__ __launch_bounds__(256) void scan1_kernel(const int* __restrict__ deg,
                                                    int* __restrict__ rowptr,
                                                    int* __restrict__ bsum, int n) {
    __shared__ int wsum[4];
    int t = threadIdx.x;
    int l = t & 63, wv = t >> 6;
    int i = blockIdx.x * 256 + t;
    int v = (i < n) ? deg[i] : 0;
    int x = v;
    #pragma unroll
    for (int off = 1; off < 64; off <<= 1) {
        int y = __shfl_up(x, off);
        if (l >= off) x += y;
    }
    if (l == 63) wsum[wv] = x;
    __syncthreads();
    int wo = 0;
    #pragma unroll
    for (int j = 0; j < 4; ++j)
        if (j < wv) wo += wsum[j];
    if (i < n) rowptr[i] = wo + x - v;
    if (t == 255) bsum[blockIdx.x] = wo + x;
}

// scan phase 2 (fused old scan2+scan3): each block computes its own
// boff = sum(bsum[0..blockIdx)) in-block (nb <= 256), adds it, sets rowptr[n].
__global__ __launch_bounds__(256) void scan3_kernel(int* __restrict__ rowptr,
                                                    const int* __restrict__ bsum,
                                                    int n, int E, int nb) {
    __shared__ int wsum[4];
    int t = threadIdx.x;
    int l = t & 63, wv = t >> 6;
    int bi = blockIdx.x;
    int v = (t < bi) ? bsum[t] : 0;   // t < bi < nb <= 256
    #pragma unroll
    for (int off = 1; off < 64; off <<= 1) v += __shfl_xor(v, off);
    if (l == 0) wsum[wv] = v;
    __syncthreads();
    int off = wsum[0] + wsum[1] + wsum[2] + wsum[3];
    int i = bi * 256 + t;
    if (i < n) rowptr[i] += off;
    if (i == 0) rowptr[n] = E;
}

// store the SRC VALUE in CSR order (no eidx indirection), 4 edges/thread
__global__ void fill_csr_kernel(const int* __restrict__ src, const int* __restrict__ dst,
                                const int* __restrict__ rowptr,
                                int* __restrict__ cursor, int* __restrict__ csrc, int E) {
    int i = (blockIdx.x * blockDim.x + threadIdx.x) * 4;
    if (i + 3 < E) {
        int4 d = *(const int4*)(dst + i);
        int4 s = *(const int4*)(src + i);
        int p;
        p = atomicAdd(&cursor[d.x], 1); csrc[rowptr[d.x] + p] = s.x;
        p = atomicAdd(&cursor[d.y], 1); csrc[rowptr[d.y] + p] = s.y;
        p = atomicAdd(&cursor[d.z], 1); csrc[rowptr[d.z] + p] = s.z;
        p = atomicAdd(&cursor[d.w], 1); csrc[rowptr[d.w] + p] = s.w;
    } else {
        for (int j = i; j < E; ++j) {
            int dd = dst[j];
            int p = atomicAdd(&cursor[dd], 1);
            csrc[rowptr[dd] + p] = src[j];
        }
    }
}

// ---------------- W convert (both weights, one launch) ----------------
// WT2[c][k] = (fp16) W2[k][c]  (128x128); WT3[c][k] = (fp16) W3[k][c] (128x256)

__global__ __launch_bounds__(256) void wconv_kernel(const float* __restrict__ W2,
                                                    const float* __restrict__ W3,
                                                    _Float16* __restrict__ WT2,
                                                    _Float16* __restrict__ WT3) {
    int idx = blockIdx.x * 256 + threadIdx.x;
    if (idx < 128 * 128) {
        int k = idx >> 7, c = idx & 127;
        WT2[(size_t)c * 128 + k] = (_Float16)W2[idx];
    } else if (idx < 128 * 128 + 128 * 256) {
        int j = idx - 128 * 128;
        int k = j >> 8, c = j & 255;
        WT3[(size_t)c * 128 + k] = (_Float16)W3[j];
    }
}

// ---------------- layer 1: fully-fused rank-2 GAT layer (R12) ----------------

__global__ __launch_bounds__(256) void agg1_kernel(
        const float* __restrict__ feat, const float* __restrict__ W1,
        const float* __restrict__ al, const float* __restrict__ ar,
        const int* __restrict__ rowptr, const int* __restrict__ csrc,
        const float* __restrict__ bias, _Float16* __restrict__ out, int N) {
    constexpr int GRP = 16, NV = 4;
    __shared__ float2 fss[4][NV][GRP + 1];
    __shared__ float  exs[4][NV][4][GRP + 1];
    const int l = threadIdx.x & 63;
    const int w = threadIdx.x >> 6;
    const int g = l >> 4;
    const int lg = l & 15;
    const int v = blockIdx.x * (4 * NV) + w * NV + g;

    // per-wave prologue: rank-2 logit coefficients
    float w0l = W1[l], w0h = W1[l + 64];
    float w1l = W1[128 + l], w1h = W1[128 + l + 64];
    float all_ = al[l], alh = al[l + 64];
    float arl = ar[l], arh = ar[l + 64];
    float pa0 = w0l * all_, pa1 = w0h * alh;
    float pb0 = w1l * all_, pb1 = w1h * alh;
    float pc0 = w0l * arl,  pc1 = w0h * arh;
    float pd0 = w1l * arl,  pd1 = w1h * arh;
    #pragma unroll
    for (int off = 1; off < 32; off <<= 1) {
        pa0 += __shfl_xor(pa0, off); pa1 += __shfl_xor(pa1, off);
        pb0 += __shfl_xor(pb0, off); pb1 += __shfl_xor(pb1, off);
        pc0 += __shfl_xor(pc0, off); pc1 += __shfl_xor(pc1, off);
        pd0 += __shfl_xor(pd0, off); pd1 += __shfl_xor(pd1, off);
    }
    float4 Ael = make_float4(__shfl(pa0, 0), __shfl(pa0, 32),
                             __shfl(pa1, 0), __shfl(pa1, 32));
    float4 Bel = make_float4(__shfl(pb0, 0), __shfl(pb0, 32),
                             __shfl(pb1, 0), __shfl(pb1, 32));
    float4 Aer = make_float4(__shfl(pc0, 0), __shfl(pc0, 32),
                             __shfl(pc1, 0), __shfl(pc1, 32));
    float4 Ber = make_float4(__shfl(pd0, 0), __shfl(pd0, 32),
                             __shfl(pd1, 0), __shfl(pd1, 32));

    if (v >= N) return;
    const int r0 = rowptr[v], r1 = rowptr[v + 1];
    const int c0 = lg * 8;
    const int h = lg >> 2;
    float4 w0a = *(const float4*)&W1[c0];
    float4 w0b = *(const float4*)&W1[c0 + 4];
    float4 w1a = *(const float4*)&W1[128 + c0];
    float4 w1b = *(const float4*)&W1[128 + c0 + 4];
    float4 b0 = *(const float4*)(bias + c0);
    float4 b1 = *(const float4*)(bias + c0 + 4);
    float4 o0, o1;

    if (r0 == r1) {
        o0 = b0; o1 = b1;
    } else {
        float2 fv = *(const float2*)(feat + (size_t)v * 2);
        float4 er4 = make_float4(fmaf(fv.x, Aer.x, fv.y * Ber.x),
                                 fmaf(fv.x, Aer.y, fv.y * Ber.y),
                                 fmaf(fv.x, Aer.z, fv.y * Ber.z),
                                 fmaf(fv.x, Aer.w, fv.y * Ber.w));

        float m0 = NEG_BIG, m1 = NEG_BIG, m2 = NEG_BIG, m3 = NEG_BIG;
        float2 fs0 = make_float2(0.f, 0.f);
        float4 e40 = make_float4(NEG_BIG, NEG_BIG, NEG_BIG, NEG_BIG);
        for (int base = r0; base < r1; base += GRP) {
            int i = base + lg;
            float ex_ = NEG_BIG, ey_ = NEG_BIG, ez_ = NEG_BIG, ew_ = NEG_BIG;
            float2 fs = make_float2(0.f, 0.f);
            if (i < r1) {
                int sv = csrc[i];
                fs = *(const float2*)(feat + (size_t)sv * 2);
                ex_ = lrelu(fmaf(fs.x, Ael.x, fs.y * Bel.x) + er4.x);
                ey_ = lrelu(fmaf(fs.x, Ael.y, fs.y * Bel.y) + er4.y);
                ez_ = lrelu(fmaf(fs.x, Ael.z, fs.y * Bel.z) + er4.z);
                ew_ = lrelu(fmaf(fs.x, Ael.w, fs.y * Bel.w) + er4.w);
            }
            if (base == r0) { fs0 = fs; e40 = make_float4(ex_, ey_, ez_, ew_); }
            m0 = fmaxf(m0, ex_); m1 = fmaxf(m1, ey_);
            m2 = fmaxf(m2, ez_); m3 = fmaxf(m3, ew_);
        }
        #pragma unroll
        for (int off = 1; off < GRP; off <<= 1) {
            m0 = fmaxf(m0, __shfl_xor(m0, off));
            m1 = fmaxf(m1, __shfl_xor(m1, off));
            m2 = fmaxf(m2, __shfl_xor(m2, off));
            m3 = fmaxf(m3, __shfl_xor(m3, off));
        }

        float s0 = 0.f, s1 = 0.f, s2 = 0.f, s3 = 0.f;
        float4 a0 = make_float4(0.f, 0.f, 0.f, 0.f);
        float4 a1 = make_float4(0.f, 0.f, 0.f, 0.f);

        for (int base = r0; base < r1; base += GRP) {
            int i = base + lg;
            float2 fs; float4 e4;
            if (base == r0) {
                fs = fs0; e4 = e40;
            } else if (i < r1) {
                int sv = csrc[i];
                fs = *(const float2*)(feat + (size_t)sv * 2);
                e4 = make_float4(
                    lrelu(fmaf(fs.x, Ael.x, fs.y * Bel.x) + er4.x),
                    lrelu(fmaf(fs.x, Ael.y, fs.y * Bel.y) + er4.y),
                    lrelu(fmaf(fs.x, Ael.z, fs.y * Bel.z) + er4.z),
                    lrelu(fmaf(fs.x, Ael.w, fs.y * Bel.w) + er4.w));
            } else {
                fs = make_float2(0.f, 0.f);
                e4 = make_float4(NEG_BIG, NEG_BIG, NEG_BIG, NEG_BIG);
            }
            bool valid = (i < r1);
            float exv0 = valid ? __expf(e4.x - m0) : 0.f;
            float exv1 = valid ? __expf(e4.y - m1) : 0.f;
            float exv2 = valid ? __expf(e4.z - m2) : 0.f;
            float exv3 = valid ? __expf(e4.w - m3) : 0.f;
            s0 += exv0; s1 += exv1; s2 += exv2; s3 += exv3;
            fss[w][g][lg] = fs;
            exs[w][g][0][lg] = exv0; exs[w][g][1][lg] = exv1;
            exs[w][g][2][lg] = exv2; exs[w][g][3][lg] = exv3;
            int cnt = min(GRP, r1 - base);
            #pragma unroll 8
            for (int k = 0; k < cnt; ++k) {
                float2 fk = fss[w][g][k];
                float exk = exs[w][g][h][k];
                float u = fk.x * exk;
                float t = fk.y * exk;
                a0.x = fmaf(u, w0a.x, fmaf(t, w1a.x, a0.x));
                a0.y = fmaf(u, w0a.y, fmaf(t, w1a.y, a0.y));
                a0.z = fmaf(u, w0a.z, fmaf(t, w1a.z, a0.z));
                a0.w = fmaf(u, w0a.w, fmaf(t, w1a.w, a0.w));
                a1.x = fmaf(u, w0b.x, fmaf(t, w1b.x, a1.x));
                a1.y = fmaf(u, w0b.y, fmaf(t, w1b.y, a1.y));
                a1.z = fmaf(u, w0b.z, fmaf(t, w1b.z, a1.z));
                a1.w = fmaf(u, w0b.w, fmaf(t, w1b.w, a1.w));
            }
        }
        #pragma unroll
        for (int off = 1; off < GRP; off <<= 1) {
            s0 += __shfl_xor(s0, off);
            s1 += __shfl_xor(s1, off);
            s2 += __shfl_xor(s2, off);
            s3 += __shfl_xor(s3, off);
        }
        float s = (h == 0) ? s0 : (h == 1) ? s1 : (h == 2) ? s2 : s3;
        float inv = 1.f / s;
        o0 = make_float4(fmaf(a0.x, inv, b0.x), fmaf(a0.y, inv, b0.y),
                         fmaf(a0.z, inv, b0.z), fmaf(a0.w, inv, b0.w));
        o1 = make_float4(fmaf(a1.x, inv, b1.x), fmaf(a1.y, inv, b1.y),
                         fmaf(a1.z, inv, b1.z), fmaf(a1.w, inv, b1.w));
    }
    o0.x = fmaxf(o0.x, 0.f); o0.y = fmaxf(o0.y, 0.f);
    o0.z = fmaxf(o0.z, 0.f); o0.w = fmaxf(o0.w, 0.f);
    o1.x = fmaxf(o1.x, 0.f); o1.y = fmaxf(o1.y, 0.f);
    o1.z = fmaxf(o1.z, 0.f); o1.w = fmaxf(o1.w, 0.f);
    h8 ho;
    ho[0] = (_Float16)o0.x; ho[1] = (_Float16)o0.y;
    ho[2] = (_Float16)o0.z; ho[3] = (_Float16)o0.w;
    ho[4] = (_Float16)o1.x; ho[5] = (_Float16)o1.y;
    ho[6] = (_Float16)o1.z; ho[7] = (_Float16)o1.w;
    *(h8*)(out + (size_t)v * 128 + c0) = ho;
}

// ---------------- MFMA GEMM: A(fp16)[N,128] @ W -> ZH(fp16) + el/er ----------------
// One wave per 16 rows. v_mfma_f32_16x16x32_f16, K=128 in 4 steps. The 16xHDOUT
// output tile is staged in LDS (same-wave, no barrier) and written back as
// contiguous h8 (coalesced 1KB/instr) instead of scalar 2B stores.

template <int HDOUT>
__global__ __launch_bounds__(256) void gemm_mfma_kernel(
        const _Float16* __restrict__ A, const _Float16* __restrict__ WT,
        const float* __restrict__ al, const float* __restrict__ ar,
        _Float16* __restrict__ ZH, float* __restrict__ el, float* __restrict__ er,
        int N) {
    constexpr int TPH = HDOUT / 64;  // 16-col tiles per head (2 or 4)
    __shared__ _Float16 zst[4][16][HDOUT];
    const int l = threadIdx.x & 63;
    const int w = threadIdx.x >> 6;
    const int wid = blockIdx.x * 4 + w;
    const int m0 = wid * 16;
    if (m0 >= N) return;
    const int lc = l & 15;
    const int kg = l >> 4;

    // A fragments for 4 k-steps (lane's own row)
    h8 afrag[4];
    {
        int m = m0 + lc;
        if (m < N) {
            const _Float16* ap = A + (size_t)m * 128 + kg * 8;
            #pragma unroll
            for (int ks = 0; ks < 4; ++ks) afrag[ks] = *(const h8*)(ap + ks * 32);
        } else {
            #pragma unroll
            for (int ks = 0; ks < 4; ++ks)
                #pragma unroll
                for (int j = 0; j < 8; ++j) afrag[ks][j] = (_Float16)0.f;
        }
    }

    #pragma unroll
    for (int h = 0; h < 4; ++h) {
        float pel[4] = {0.f, 0.f, 0.f, 0.f};
        float per_[4] = {0.f, 0.f, 0.f, 0.f};
        #pragma unroll
        for (int tt = 0; tt < TPH; ++tt) {
            int col = (h * TPH + tt) * 16 + lc;
            f32x4 acc = {0.f, 0.f, 0.f, 0.f};
            const _Float16* wp = WT + (size_t)col * 128 + kg * 8;
            #pragma unroll
            for (int ks = 0; ks < 4; ++ks) {
                h8 bfrag = *(const h8*)(wp + ks * 32);
                acc = __builtin_amdgcn_mfma_f32_16x16x32_f16(afrag[ks], bfrag, acc,
                                                             0, 0, 0);
            }
            float alc = al[col], arc = ar[col];
            #pragma unroll
            for (int r = 0; r < 4; ++r) {
                zst[w][kg * 4 + r][col] = (_Float16)acc[r];
                pel[r] = fmaf(acc[r], alc, pel[r]);
                per_[r] = fmaf(acc[r], arc, per_[r]);
            }
        }
        #pragma unroll
        for (int off = 1; off < 16; off <<= 1) {
            #pragma unroll
            for (int r = 0; r < 4; ++r) {
                pel[r] += __shfl_xor(pel[r], off);
                per_[r] += __shfl_xor(per_[r], off);
            }
        }
        if (lc == 0) {
            #pragma unroll
            for (int r = 0; r < 4; ++r) {
                int n = m0 + kg * 4 + r;
                if (n < N) {
                    el[(size_t)n * 4 + h] = pel[r];
                    er[(size_t)n * 4 + h] = per_[r];
                }
            }
        }
    }

    // coalesced ZH write-back (same-wave LDS: hardware lgkmcnt ordering)
    #pragma unroll
    for (int it = 0; it < HDOUT / 32; ++it) {
        int idx = (it * 64 + l) * 8;       // element offset within 16 x HDOUT tile
        int r = idx / HDOUT;
        int c = idx % HDOUT;
        int n = m0 + r;
        if (n < N)
            *(h8*)&ZH[(size_t)n * HDOUT + c] = *(const h8*)&zst[w][r][c];
    }
}

// ---------------- fused edge-softmax + aggregate (layers 2-3) ----------------

template <bool RELU, int GRP, int HD, typename OUTT>
__global__ __launch_bounds__(256) void agg_kernel(
        const _Float16* __restrict__ zh, const float* __restrict__ el,
        const float* __restrict__ er, const int* __restrict__ rowptr,
        const int* __restrict__ csrc, const float* __restrict__ bias,
        OUTT* __restrict__ out, int N) {
    constexpr int NV = 64 / GRP;
    constexpr int CH = HD / GRP;
    constexpr int HGRP = GRP / 4;
    static_assert(CH == 8, "config assumes 8 channels per lane");
    __shared__ float exs[4][NV][4][GRP + 1];
    __shared__ int   svs[4][NV][GRP + 1];
    const int l = threadIdx.x & 63;
    const int w = threadIdx.x >> 6;
    const int g = l / GRP;
    const int lg = l & (GRP - 1);
    const int v = blockIdx.x * (4 * NV) + w * NV + g;
    if (v >= N) return;
    const int r0 = rowptr[v], r1 = rowptr[v + 1];
    const int c0 = lg * CH;
    const int h = lg / HGRP;
    float4 b0 = *(const float4*)(bias + c0);
    float4 b1 = *(const float4*)(bias + c0 + 4);
    float4 o0, o1;

    if (r0 == r1) {
        o0 = b0; o1 = b1;
    } else {
        float4 er4 = *(const float4*)(er + (size_t)v * 4);

        float m0 = NEG_BIG, m1 = NEG_BIG, m2 = NEG_BIG, m3 = NEG_BIG;
        int sv0 = 0;
        float4 e40 = make_float4(NEG_BIG, NEG_BIG, NEG_BIG, NEG_BIG);
        for (int base = r0; base < r1; base += GRP) {
            int i = base + lg;
            float ex_ = NEG_BIG, ey_ = NEG_BIG, ez_ = NEG_BIG, ew_ = NEG_BIG;
            int sv = 0;
            if (i < r1) {
                sv = csrc[i];
                float4 ev = *(const float4*)(el + (size_t)sv * 4);
                ex_ = lrelu(ev.x + er4.x);
                ey_ = lrelu(ev.y + er4.y);
                ez_ = lrelu(ev.z + er4.z);
                ew_ = lrelu(ev.w + er4.w);
            }
            if (base == r0) { sv0 = sv; e40 = make_float4(ex_, ey_, ez_, ew_); }
            m0 = fmaxf(m0, ex_); m1 = fmaxf(m1, ey_);
            m2 = fmaxf(m2, ez_); m3 = fmaxf(m3, ew_);
        }
        #pragma unroll
        for (int off = 1; off < GRP; off <<= 1) {
            m0 = fmaxf(m0, __shfl_xor(m0, off));
            m1 = fmaxf(m1, __shfl_xor(m1, off));
            m2 = fmaxf(m2, __shfl_xor(m2, off));
            m3 = fmaxf(m3, __shfl_xor(m3, off));
        }

        float s0 = 0.f, s1 = 0.f, s2 = 0.f, s3 = 0.f;
        float4 a0 = make_float4(0.f, 0.f, 0.f, 0.f);
        float4 a1 = make_float4(0.f, 0.f, 0.f, 0.f);

        for (int base = r0; base < r1; base += GRP) {
            int i = base + lg;
            int sv; float4 e4;
            if (base == r0) {
                sv = sv0; e4 = e40;
            } else if (i < r1) {
                sv = csrc[i];
                float4 ev = *(const float4*)(el + (size_t)sv * 4);
                e4 = make_float4(lrelu(ev.x + er4.x), lrelu(ev.y + er4.y),
                                 lrelu(ev.z + er4.z), lrelu(ev.w + er4.w));
            } else {
                sv = 0; e4 = make_float4(NEG_BIG, NEG_BIG, NEG_BIG, NEG_BIG);
            }
            bool valid = (i < r1);
            float exv0 = valid ? __expf(e4.x - m0) : 0.f;
            float exv1 = valid ? __expf(e4.y - m1) : 0.f;
            float exv2 = valid ? __expf(e4.z - m2) : 0.f;
            float exv3 = valid ? __expf(e4.w - m3) : 0.f;
            s0 += exv0; s1 += exv1; s2 += exv2; s3 += exv3;
            svs[w][g][lg] = sv;
            exs[w][g][0][lg] = exv0; exs[w][g][1][lg] = exv1;
            exs[w][g][2][lg] = exv2; exs[w][g][3][lg] = exv3;
            int cnt = min(GRP, r1 - base);
            #pragma unroll 8
            for (int k = 0; k < cnt; ++k) {
                int svk = svs[w][g][k];
                float exk = exs[w][g][h][k];
                h8 zz = *(const h8*)(zh + (size_t)svk * HD + c0);
                a0.x = fmaf((float)zz[0], exk, a0.x);
                a0.y = fmaf((float)zz[1], exk, a0.y);
                a0.z = fmaf((float)zz[2], exk, a0.z);
                a0.w = fmaf((float)zz[3], exk, a0.w);
                a1.x = fmaf((float)zz[4], exk, a1.x);
                a1.y = fmaf((float)zz[5], exk, a1.y);
                a1.z = fmaf((float)zz[6], exk, a1.z);
                a1.w = fmaf((float)zz[7], exk, a1.w);
            }
        }
        #pragma unroll
        for (int off = 1; off < GRP; off <<= 1) {
            s0 += __shfl_xor(s0, off);
            s1 += __shfl_xor(s1, off);
            s2 += __shfl_xor(s2, off);
            s3 += __shfl_xor(s3, off);
        }
        float s = (h == 0) ? s0 : (h == 1) ? s1 : (h == 2) ? s2 : s3;
        float inv = 1.f / s;
        o0 = make_float4(fmaf(a0.x, inv, b0.x), fmaf(a0.y, inv, b0.y),
                         fmaf(a0.z, inv, b0.z), fmaf(a0.w, inv, b0.w));
        o1 = make_float4(fmaf(a1.x, inv, b1.x), fmaf(a1.y, inv, b1.y),
                         fmaf(a1.z, inv, b1.z), fmaf(a1.w, inv, b1.w));
    }
    if (RELU) {
        o0.x = fmaxf(o0.x, 0.f); o0.y = fmaxf(o0.y, 0.f);
        o0.z = fmaxf(o0.z, 0.f); o0.w = fmaxf(o0.w, 0.f);
        o1.x = fmaxf(o1.x, 0.f); o1.y = fmaxf(o1.y, 0.f);
        o1.z = fmaxf(o1.z, 0.f); o1.w = fmaxf(o1.w, 0.f);
    }
    if constexpr (sizeof(OUTT) == 2) {
        h8 ho;
        ho[0] = (_Float16)o0.x; ho[1] = (_Float16)o0.y;
        ho[2] = (_Float16)o0.z; ho[3] = (_Float16)o0.w;
        ho[4] = (_Float16)o1.x; ho[5] = (_Float16)o1.y;
        ho[6] = (_Float16)o1.z; ho[7] = (_Float16)o1.w;
        *(h8*)((_Float16*)out + (size_t)v * HD + c0) = ho;
    } else {
        float* op = (float*)out + (size_t)v * HD + c0;
        *(float4*)op = o0;
        *(float4*)(op + 4) = o1;
    }
}

// ---------------- launch ----------------

extern "C" void kernel_launch(void* const* d_in, const int* in_sizes, int n_in,
                              void* d_out, int out_size, void* d_ws, size_t ws_size,
                              hipStream_t stream) {
    const float* feat = (const float*)d_in[0];
    const int* src = (const int*)d_in[1];
    const int* dst = (const int*)d_in[2];
    const float* W1 = (const float*)d_in[3];
    const float* al1 = (const float*)d_in[4];
    const float* ar1 = (const float*)d_in[5];
    const float* b1 = (const float*)d_in[6];
    const float* W2 = (const float*)d_in[7];
    const float* al2 = (const float*)d_in[8];
    const float* ar2 = (const float*)d_in[9];
    const float* b2 = (const float*)d_in[10];
    const float* W3 = (const float*)d_in[11];
    const float* al3 = (const float*)d_in[12];
    const float* ar3 = (const float*)d_in[13];
    const float* b3 = (const float*)d_in[14];
    const int N = in_sizes[0] / 2;   // feat is [N,2]
    const int E = in_sizes[1];

    // workspace layout (16B alignment maintained through zh/WT)
    _Float16* hbuf = (_Float16*)d_ws;                 // [N,128] fp16
    float* el = (float*)(hbuf + (size_t)N * 128);     // [N,4]
    float* er = el + (size_t)N * 4;                   // [N,4]
    _Float16* zh = (_Float16*)(er + (size_t)N * 4);   // [N,256] fp16 shadow
    _Float16* WT2 = zh + (size_t)N * 256;             // [128,128] fp16 (W2^T)
    _Float16* WT3 = WT2 + 128 * 128;                  // [256,128] fp16 (W3^T)
    int* csrc = (int*)(WT3 + 256 * 128);              // [E]
    int* deg = csrc + E;                              // [N]
    int* cursor = deg + N;                            // [N]
    int* rowptr = cursor + N;                         // [N+1]
    int* bsum = rowptr + (N + 1);                     // [nb]

    const int nb = cdiv(N, 256);  // 196 <= 256

    // CSR build + weight convert (front-loaded, independent)
    hipMemsetAsync(deg, 0, sizeof(int) * (size_t)(2 * N), stream);  // deg + cursor
    wconv_kernel<<<cdiv(128 * 128 + 128 * 256, 256), 256, 0, stream>>>(W2, W3, WT2, WT3);
    count_deg_kernel<<<cdiv(E, 1024), 256, 0, stream>>>(dst, deg, E);
    scan1_kernel<<<nb, 256, 0, stream>>>(deg, rowptr, bsum, N);
    scan3_kernel<<<nb, 256, 0, stream>>>(rowptr, bsum, N, E, nb);
    fill_csr_kernel<<<cdiv(E, 1024), 256, 0, stream>>>(src, dst, rowptr, cursor, csrc, E);

    // ---- layer 1 (2 -> 128, relu): fully fused rank-2 layer ----
    agg1_kernel<<<cdiv(N, 16), 256, 0, stream>>>(feat, W1, al1, ar1, rowptr, csrc,
                                                 b1, hbuf, N);

    // ---- layer 2 (128 -> 128, relu) ----
    gemm_mfma_kernel<128><<<cdiv(N, 64), 256, 0, stream>>>(
        hbuf, WT2, al2, ar2, zh, el, er, N);
    agg_kernel<true, 16, 128, _Float16><<<cdiv(N, 16), 256, 0, stream>>>(
        zh, el, er, rowptr, csrc, b2, hbuf, N);

    // ---- layer 3 (128 -> 256, no relu) ----
    gemm_mfma_kernel<256><<<cdiv(N, 64), 256, 0, stream>>>(
        hbuf, WT3, al3, ar3, zh, el, er, N);
    agg_kernel<false, 32, 256, float><<<cdiv(N, 8), 256, 0, stream>>>(
        zh, el, er, rowptr, csrc, b3, (float*)d_out, N);
}